// Round 1
// baseline (5693.000 us; speedup 1.0000x reference)
//
#include <hip/hip_runtime.h>
#include <math.h>

#define LREL 0.01f

__device__ __forceinline__ float lrelu(float x) { return x > 0.f ? x : LREL * x; }

// ---------------- conv 4x4 stride2 pad1 + leaky relu ----------------
template<int CIN, int COUT>
__global__ void __launch_bounds__(256) conv4x4s2_lrelu_k(
    const float* __restrict__ in, const float* __restrict__ w,
    const float* __restrict__ bias, float* __restrict__ out,
    int N, int IH, int IW, int OH, int OW)
{
    int idx = blockIdx.x * 256 + threadIdx.x;
    int total = N * COUT * OH * OW;
    if (idx >= total) return;
    int ox = idx % OW;
    int oy = (idx / OW) % OH;
    int co = (idx / (OW * OH)) % COUT;
    int n  = idx / (OW * OH * COUT);
    float acc = bias[co];
    int iy0 = oy * 2 - 1;
    int ix0 = ox * 2 - 1;
    for (int ci = 0; ci < CIN; ++ci) {
        const float* ip = in + (size_t)(n * CIN + ci) * IH * IW;
        const float* wp = w + ((co * CIN + ci) << 4);
        #pragma unroll
        for (int ky = 0; ky < 4; ++ky) {
            int iy = iy0 + ky;
            if (iy < 0 || iy >= IH) continue;
            #pragma unroll
            for (int kx = 0; kx < 4; ++kx) {
                int ix = ix0 + kx;
                if (ix < 0 || ix >= IW) continue;
                acc = fmaf(ip[iy * IW + ix], wp[(ky << 2) + kx], acc);
            }
        }
    }
    out[idx] = lrelu(acc);
}

// ---------------- conv 3x3 pad1 (same size), optional bias/activation ----------------
template<int C, int ACT>  // ACT: 0=none, 1=lrelu
__global__ void __launch_bounds__(256) conv3x3p1_k(
    const float* __restrict__ in, const float* __restrict__ w,
    const float* __restrict__ bias, float* __restrict__ out,
    int N, int H, int W)
{
    int idx = blockIdx.x * 256 + threadIdx.x;
    int total = N * C * H * W;
    if (idx >= total) return;
    int ox = idx % W;
    int oy = (idx / W) % H;
    int co = (idx / (W * H)) % C;
    int n  = idx / (W * H * C);
    float acc = bias ? bias[co] : 0.f;
    for (int ci = 0; ci < C; ++ci) {
        const float* ip = in + (size_t)(n * C + ci) * H * W;
        const float* wp = w + (co * C + ci) * 9;
        #pragma unroll
        for (int ky = 0; ky < 3; ++ky) {
            int iy = oy + ky - 1;
            if (iy < 0 || iy >= H) continue;
            #pragma unroll
            for (int kx = 0; kx < 3; ++kx) {
                int ix = ox + kx - 1;
                if (ix < 0 || ix >= W) continue;
                acc = fmaf(ip[iy * W + ix], wp[ky * 3 + kx], acc);
            }
        }
    }
    out[idx] = ACT ? lrelu(acc) : acc;
}

// ---------------- conv 1x1, optional bias/activation ----------------
template<int CIN, int COUT, int ACT>  // ACT: 0=none, 1=lrelu
__global__ void __launch_bounds__(256) conv1x1_k(
    const float* __restrict__ in, const float* __restrict__ w,
    const float* __restrict__ bias, float* __restrict__ out,
    int N, int HW)
{
    int idx = blockIdx.x * 256 + threadIdx.x;
    int total = N * COUT * HW;
    if (idx >= total) return;
    int p  = idx % HW;
    int co = (idx / HW) % COUT;
    int n  = idx / (HW * COUT);
    float acc = bias ? bias[co] : 0.f;
    const float* ip = in + (size_t)n * CIN * HW + p;
    const float* wp = w + co * CIN;
    #pragma unroll 8
    for (int ci = 0; ci < CIN; ++ci)
        acc = fmaf(ip[(size_t)ci * HW], wp[ci], acc);
    out[idx] = ACT ? lrelu(acc) : acc;
}

// ---------------- BN batch-stats partials (deterministic, no atomics) ----------------
// grid = C * NSLICE blocks; writes part[(2c)*NSLICE + s] = sum, part[(2c+1)*NSLICE + s] = sumsq
__global__ void __launch_bounds__(256) bn_stats_k(
    const float* __restrict__ in, float* __restrict__ part,
    int N, int C, int HW, int nslice)
{
    int c = blockIdx.x / nslice;
    int s = blockIdx.x % nslice;
    int nper = N / nslice;
    float sum = 0.f, ss = 0.f;
    for (int n = s * nper; n < (s + 1) * nper; ++n) {
        const float* ip = in + (size_t)(n * C + c) * HW;
        for (int i = threadIdx.x; i < HW; i += 256) {
            float v = ip[i];
            sum += v;
            ss = fmaf(v, v, ss);
        }
    }
    __shared__ float s1[256], s2[256];
    s1[threadIdx.x] = sum; s2[threadIdx.x] = ss;
    __syncthreads();
    for (int st = 128; st > 0; st >>= 1) {
        if (threadIdx.x < st) {
            s1[threadIdx.x] += s1[threadIdx.x + st];
            s2[threadIdx.x] += s2[threadIdx.x + st];
        }
        __syncthreads();
    }
    if (threadIdx.x == 0) {
        part[(2 * c) * nslice + s]     = s1[0];
        part[(2 * c + 1) * nslice + s] = s2[0];
    }
}

// finalize: fin[2c] = mean, fin[2c+1] = rstd
__global__ void bn_fin_k(const float* __restrict__ part, float* __restrict__ fin,
                         int C, int nslice, float invM)
{
    int c = threadIdx.x;
    if (c >= C) return;
    float sum = 0.f, ss = 0.f;
    for (int s = 0; s < nslice; ++s) {
        sum += part[(2 * c) * nslice + s];
        ss  += part[(2 * c + 1) * nslice + s];
    }
    float mean = sum * invM;
    float var  = ss * invM - mean * mean;
    fin[2 * c]     = mean;
    fin[2 * c + 1] = rsqrtf(var + 1e-5f);
}

// ---------------- BN apply + activation (+ optional residual) ----------------
template<int MODE>  // 0: relu(bn(x)) ; 1: lrelu(res + bn(x))
__global__ void __launch_bounds__(256) bn_apply_k(
    const float* __restrict__ in, const float* __restrict__ fin,
    const float* __restrict__ g, const float* __restrict__ beta,
    const float* __restrict__ res, float* __restrict__ out,
    int N, int C, int HW)
{
    int idx = blockIdx.x * 256 + threadIdx.x;
    int total = N * C * HW;
    if (idx >= total) return;
    int c = (idx / HW) % C;
    float mean = fin[2 * c];
    float rstd = fin[2 * c + 1];
    float y = (in[idx] - mean) * rstd * g[c] + beta[c];
    if (MODE == 0) {
        out[idx] = fmaxf(y, 0.f);
    } else {
        float t = res[idx] + y;
        out[idx] = lrelu(t);
    }
}

// ---------------- VQ: per-thread pixel, full 512-code scan (D=64, K=512) ----------------
__global__ void __launch_bounds__(256) vq_k(
    const float* __restrict__ z, const float* __restrict__ emb,
    float* __restrict__ qf, float* __restrict__ out_q, float* __restrict__ out_e,
    float* __restrict__ partials, int N, int HW)
{
    int m = blockIdx.x * 256 + threadIdx.x;   // m in [0, N*HW)
    int n = m / HW, p = m % HW;
    size_t base = (size_t)n * 64 * HW + p;
    float zr[64];
    #pragma unroll
    for (int d = 0; d < 64; ++d) zr[d] = z[base + (size_t)d * HW];
    #pragma unroll
    for (int d = 0; d < 64; ++d) out_e[base + (size_t)d * HW] = zr[d];

    float best = 3.4e38f;
    int bi = 0;
    for (int k = 0; k < 512; ++k) {
        const float4* e4 = (const float4*)(emb + (k << 6));
        float s = 0.f;
        #pragma unroll
        for (int j = 0; j < 16; ++j) {
            float4 e = e4[j];
            float d0 = zr[4 * j]     - e.x;
            float d1 = zr[4 * j + 1] - e.y;
            float d2 = zr[4 * j + 2] - e.z;
            float d3 = zr[4 * j + 3] - e.w;
            s = fmaf(d0, d0, s); s = fmaf(d1, d1, s);
            s = fmaf(d2, d2, s); s = fmaf(d3, d3, s);
        }
        if (s < best) { best = s; bi = k; }  // ascending k => first-min tie-break (jnp.argmin)
    }

    float lsum = 0.f;
    const float* eb = emb + (bi << 6);
    #pragma unroll
    for (int d = 0; d < 64; ++d) {
        float q = eb[d];
        qf[base + (size_t)d * HW]    = q;
        out_q[base + (size_t)d * HW] = q;
        float df = q - zr[d];
        lsum = fmaf(df, df, lsum);
    }
    __shared__ float sh[256];
    sh[threadIdx.x] = lsum;
    __syncthreads();
    for (int st = 128; st > 0; st >>= 1) {
        if (threadIdx.x < st) sh[threadIdx.x] += sh[threadIdx.x + st];
        __syncthreads();
    }
    if (threadIdx.x == 0) partials[blockIdx.x] = sh[0];
}

__global__ void vq_fin_k(const float* __restrict__ partials, float* __restrict__ out)
{
    __shared__ float sh[256];
    sh[threadIdx.x] = partials[threadIdx.x];
    __syncthreads();
    for (int st = 128; st > 0; st >>= 1) {
        if (threadIdx.x < st) sh[threadIdx.x] += sh[threadIdx.x + st];
        __syncthreads();
    }
    if (threadIdx.x == 0) out[0] = sh[0] * (0.25f / (65536.f * 64.f));
}

// ---------------- deconv (ConvTranspose2d) 4x4 stride2 pad1 ----------------
// out[n,co,oy,ox] = b[co] + sum_ci sum_{ky,kx: oy=2*iy-1+ky} in[n,ci,iy,ix] * w[ci,co,ky,kx]
template<int CIN, int COUT, int ACT>  // ACT: 1=lrelu, 2=tanh
__global__ void __launch_bounds__(256) deconv4x4s2_k(
    const float* __restrict__ in, const float* __restrict__ w,
    const float* __restrict__ bias, float* __restrict__ out,
    int N, int IH, int IW, int OH, int OW)
{
    int idx = blockIdx.x * 256 + threadIdx.x;
    int total = N * COUT * OH * OW;
    if (idx >= total) return;
    int ox = idx % OW;
    int oy = (idx / OW) % OH;
    int co = (idx / (OW * OH)) % COUT;
    int n  = idx / (OW * OH * COUT);
    float acc = bias[co];
    int ky0 = (oy + 1) & 1;
    int kx0 = (ox + 1) & 1;
    #pragma unroll
    for (int ty = 0; ty < 2; ++ty) {
        int ky = ky0 + 2 * ty;
        int iy = (oy + 1 - ky) >> 1;
        if (iy < 0 || iy >= IH) continue;
        #pragma unroll
        for (int tx = 0; tx < 2; ++tx) {
            int kx = kx0 + 2 * tx;
            int ix = (ox + 1 - kx) >> 1;
            if (ix < 0 || ix >= IW) continue;
            for (int ci = 0; ci < CIN; ++ci) {
                acc = fmaf(in[((size_t)(n * CIN + ci) * IH + iy) * IW + ix],
                           w[((ci * COUT + co) << 4) + (ky << 2) + kx], acc);
            }
        }
    }
    out[idx] = (ACT == 1) ? lrelu(acc) : tanhf(acc);
}

extern "C" void kernel_launch(void* const* d_in, const int* in_sizes, int n_in,
                              void* d_out, int out_size, void* d_ws, size_t ws_size,
                              hipStream_t stream)
{
    const float* x    = (const float*)d_in[0];
    const float* e1w  = (const float*)d_in[1];
    const float* e1b  = (const float*)d_in[2];
    const float* e2w  = (const float*)d_in[3];
    const float* e2b  = (const float*)d_in[4];
    const float* e3w  = (const float*)d_in[5];
    const float* e3b  = (const float*)d_in[6];
    const float* er1w = (const float*)d_in[7];
    const float* er1g = (const float*)d_in[8];
    const float* er1b = (const float*)d_in[9];
    const float* er2w = (const float*)d_in[10];
    const float* er2g = (const float*)d_in[11];
    const float* er2b = (const float*)d_in[12];
    const float* e4w  = (const float*)d_in[13];
    const float* e4b  = (const float*)d_in[14];
    const float* emb  = (const float*)d_in[15];
    const float* d1w  = (const float*)d_in[16];
    const float* d1b  = (const float*)d_in[17];
    const float* dr1w = (const float*)d_in[18];
    const float* dr1g = (const float*)d_in[19];
    const float* dr1b = (const float*)d_in[20];
    const float* dr2w = (const float*)d_in[21];
    const float* dr2g = (const float*)d_in[22];
    const float* dr2b = (const float*)d_in[23];
    const float* dt1w = (const float*)d_in[24];
    const float* dt1b = (const float*)d_in[25];
    const float* dt2w = (const float*)d_in[26];
    const float* dt2b = (const float*)d_in[27];

    float* out = (float*)d_out;
    float* ws  = (float*)d_ws;

    const int N = 64;
    const int HW32 = 32 * 32;  // 1024
    const int NSLICE = 16;

    // workspace layout (floats)
    float* B0 = ws;                  // 8,388,608  (64x32x64x64)
    float* B1 = ws + 8388608;        // 4,194,304  (64x64x32x32)
    float* B2 = B1 + 4194304;
    float* B3 = B2 + 4194304;
    float* B4 = B3 + 4194304;
    float* bn_part = B4 + 4194304;   // 2048 floats (2*64*16)
    float* bn_fin  = bn_part + 2048; // 128 floats
    float* vq_part = bn_fin + 128;   // 256 floats

    float* out_recon = out;                 // 3,145,728
    float* out_q     = out + 3145728;       // 4,194,304
    float* out_e     = out + 7340032;       // 4,194,304
    float* out_loss  = out + 11534336;      // 1

    const float invM = 1.f / 65536.f;       // N*H*W = 64*32*32

    // ---------------- encoder ----------------
    conv4x4s2_lrelu_k<3, 32><<<(N * 32 * 64 * 64) / 256, 256, 0, stream>>>(
        x, e1w, e1b, B0, N, 128, 128, 64, 64);
    conv4x4s2_lrelu_k<32, 64><<<(N * 64 * 32 * 32) / 256, 256, 0, stream>>>(
        B0, e2w, e2b, B1, N, 64, 64, 32, 32);
    conv3x3p1_k<64, 1><<<16384, 256, 0, stream>>>(B1, e3w, e3b, B2, N, 32, 32);

    // encoder resblock
    conv3x3p1_k<64, 0><<<16384, 256, 0, stream>>>(B2, er1w, nullptr, B3, N, 32, 32);
    bn_stats_k<<<64 * NSLICE, 256, 0, stream>>>(B3, bn_part, N, 64, HW32, NSLICE);
    bn_fin_k<<<1, 64, 0, stream>>>(bn_part, bn_fin, 64, NSLICE, invM);
    bn_apply_k<0><<<16384, 256, 0, stream>>>(B3, bn_fin, er1g, er1b, nullptr, B1, N, 64, HW32);
    conv1x1_k<64, 64, 0><<<16384, 256, 0, stream>>>(B1, er2w, nullptr, B3, N, HW32);
    bn_stats_k<<<64 * NSLICE, 256, 0, stream>>>(B3, bn_part, N, 64, HW32, NSLICE);
    bn_fin_k<<<1, 64, 0, stream>>>(bn_part, bn_fin, 64, NSLICE, invM);
    bn_apply_k<1><<<16384, 256, 0, stream>>>(B3, bn_fin, er2g, er2b, B2, B1, N, 64, HW32);

    // e4 (encoded) + VQ
    conv1x1_k<64, 64, 1><<<16384, 256, 0, stream>>>(B1, e4w, e4b, B2, N, HW32);
    vq_k<<<256, 256, 0, stream>>>(B2, emb, B1, out_q, out_e, vq_part, N, HW32);
    vq_fin_k<<<1, 256, 0, stream>>>(vq_part, out_loss);

    // ---------------- decoder ----------------
    conv3x3p1_k<64, 1><<<16384, 256, 0, stream>>>(B1, d1w, d1b, B2, N, 32, 32);

    // decoder resblock
    conv3x3p1_k<64, 0><<<16384, 256, 0, stream>>>(B2, dr1w, nullptr, B3, N, 32, 32);
    bn_stats_k<<<64 * NSLICE, 256, 0, stream>>>(B3, bn_part, N, 64, HW32, NSLICE);
    bn_fin_k<<<1, 64, 0, stream>>>(bn_part, bn_fin, 64, NSLICE, invM);
    bn_apply_k<0><<<16384, 256, 0, stream>>>(B3, bn_fin, dr1g, dr1b, nullptr, B4, N, 64, HW32);
    conv1x1_k<64, 64, 0><<<16384, 256, 0, stream>>>(B4, dr2w, nullptr, B3, N, HW32);
    bn_stats_k<<<64 * NSLICE, 256, 0, stream>>>(B3, bn_part, N, 64, HW32, NSLICE);
    bn_fin_k<<<1, 64, 0, stream>>>(bn_part, bn_fin, 64, NSLICE, invM);
    bn_apply_k<1><<<16384, 256, 0, stream>>>(B3, bn_fin, dr2g, dr2b, B2, B1, N, 64, HW32);

    // deconvs
    deconv4x4s2_k<64, 32, 1><<<(N * 32 * 64 * 64) / 256, 256, 0, stream>>>(
        B1, dt1w, dt1b, B0, N, 32, 32, 64, 64);
    deconv4x4s2_k<32, 3, 2><<<(N * 3 * 128 * 128) / 256, 256, 0, stream>>>(
        B0, dt2w, dt2b, out_recon, N, 64, 64, 128, 128);
}

// Round 3
// 963.877 us; speedup vs baseline: 5.9064x; 5.9064x over previous
//
#include <hip/hip_runtime.h>
#include <math.h>

#define LREL 0.01f
__device__ __forceinline__ float lrelu(float x) { return x > 0.f ? x : LREL * x; }
__device__ __forceinline__ float fast_tanh(float x) {
    x = fminf(fmaxf(x, -10.f), 10.f);
    float a = __expf(2.f * x);
    return (a - 1.f) / (a + 1.f);
}

// ================= e1: 3->32, 128x128 -> 64x64, 4x4 s2 p1, lrelu =================
// grid 512: b -> n = b&63 ; t = b>>6 : tile = t&3 (2x2 of 32x32 out), cg = t>>2 (2 groups of 16 co)
__global__ void __launch_bounds__(256) conv_e1_t(
    const float* __restrict__ x, const float* __restrict__ w,
    const float* __restrict__ bias, float* __restrict__ out)
{
    __shared__ float lin[3][66][67];
    __shared__ float lw[3][16][16];
    int b = blockIdx.x;
    int n = b & 63, t = b >> 6;
    int tile = t & 3, cg = t >> 2;
    int ty = tile >> 1, tx = tile & 1;
    int tid = threadIdx.x;
    int r = tid >> 3, g = tid & 7, c0 = g << 2;
    const float* inp = x + (size_t)n * 3 * 16384;

    for (int i = tid; i < 3 * 66 * 66; i += 256) {
        int ci = i / 4356, rr = i % 4356;
        int y = rr / 66, xx = rr % 66;
        int gy = ty * 64 - 1 + y, gx = tx * 64 - 1 + xx;
        float v = 0.f;
        if (gy >= 0 && gy < 128 && gx >= 0 && gx < 128)
            v = inp[ci * 16384 + gy * 128 + gx];
        lin[ci][y][xx] = v;
    }
    for (int i = tid; i < 768; i += 256) {
        int ci = i >> 8, rr = i & 255, co = rr >> 4, tt = rr & 15;
        lw[ci][co][tt] = w[((cg * 16 + co) * 3 + ci) * 16 + tt];
    }
    __syncthreads();

    float acc[16][4];
    #pragma unroll
    for (int co = 0; co < 16; ++co) { acc[co][0]=acc[co][1]=acc[co][2]=acc[co][3]=0.f; }

    #pragma unroll
    for (int ci = 0; ci < 3; ++ci) {
        float win[4][10];
        #pragma unroll
        for (int dy = 0; dy < 4; ++dy)
            #pragma unroll
            for (int dx = 0; dx < 10; ++dx)
                win[dy][dx] = lin[ci][2 * r + dy][8 * g + dx];
        #pragma unroll
        for (int co = 0; co < 16; ++co) {
            #pragma unroll
            for (int ky = 0; ky < 4; ++ky)
                #pragma unroll
                for (int kx = 0; kx < 4; ++kx) {
                    float wv = lw[ci][co][ky * 4 + kx];
                    #pragma unroll
                    for (int j = 0; j < 4; ++j)
                        acc[co][j] = fmaf(win[ky][2 * j + kx], wv, acc[co][j]);
                }
        }
    }
    int oy = ty * 32 + r, ox0 = tx * 32 + c0;
    #pragma unroll
    for (int co = 0; co < 16; ++co) {
        float bv = bias[cg * 16 + co];
        float4 v;
        v.x = lrelu(acc[co][0] + bv); v.y = lrelu(acc[co][1] + bv);
        v.z = lrelu(acc[co][2] + bv); v.w = lrelu(acc[co][3] + bv);
        *(float4*)(out + ((size_t)(n * 32 + cg * 16 + co) * 4096) + oy * 64 + ox0) = v;
    }
}

// ================= e2: 32->64, 64x64 -> 32x32, 4x4 s2 p1, lrelu =================
// grid 512: n = b&63 ; cg = b>>6 (8 groups of 8 co)
__global__ void __launch_bounds__(256) conv_e2_t(
    const float* __restrict__ in, const float* __restrict__ w,
    const float* __restrict__ bias, float* __restrict__ out)
{
    __shared__ float lin[2][66][66];
    __shared__ float lw[2][8][16];
    int b = blockIdx.x;
    int n = b & 63, cg = b >> 6;
    int tid = threadIdx.x;
    int r = tid >> 3, g = tid & 7, c0 = g << 2;
    const float* inp = in + (size_t)n * 32 * 4096;

    float acc[8][4];
    #pragma unroll
    for (int co = 0; co < 8; ++co) { acc[co][0]=acc[co][1]=acc[co][2]=acc[co][3]=0.f; }

    for (int i = tid; i < 2 * 66 * 66; i += 256) ((float*)lin)[i] = 0.f;

    for (int cic = 0; cic < 16; ++cic) {
        __syncthreads();
        for (int i = tid; i < 8192; i += 256) {
            int ci = i >> 12, p = i & 4095;
            lin[ci][(p >> 6) + 1][(p & 63) + 1] = inp[(cic * 2 + ci) * 4096 + p];
        }
        {
            int i = tid;
            if (i < 256) {
                int ci = i >> 7, rr = i & 127, co = rr >> 4, tt = rr & 15;
                lw[ci][co][tt] = w[((cg * 8 + co) * 32 + cic * 2 + ci) * 16 + tt];
            }
        }
        __syncthreads();
        #pragma unroll
        for (int ci = 0; ci < 2; ++ci) {
            float win[4][10];
            #pragma unroll
            for (int dy = 0; dy < 4; ++dy)
                #pragma unroll
                for (int dx = 0; dx < 10; ++dx)
                    win[dy][dx] = lin[ci][2 * r + dy][8 * g + dx];
            #pragma unroll
            for (int co = 0; co < 8; ++co) {
                #pragma unroll
                for (int ky = 0; ky < 4; ++ky)
                    #pragma unroll
                    for (int kx = 0; kx < 4; ++kx) {
                        float wv = lw[ci][co][ky * 4 + kx];
                        #pragma unroll
                        for (int j = 0; j < 4; ++j)
                            acc[co][j] = fmaf(win[ky][2 * j + kx], wv, acc[co][j]);
                    }
            }
        }
    }
    size_t ob = ((size_t)(n * 64 + cg * 8) << 10) + (r << 5) + c0;
    #pragma unroll
    for (int co = 0; co < 8; ++co) {
        float bv = bias[cg * 8 + co];
        float4 v;
        v.x = lrelu(acc[co][0] + bv); v.y = lrelu(acc[co][1] + bv);
        v.z = lrelu(acc[co][2] + bv); v.w = lrelu(acc[co][3] + bv);
        *(float4*)(out + ob + ((size_t)co << 10)) = v;
    }
}

// ================= conv3x3 p1, 64->64 @ 32x32 =================
// grid 512: n = b&63 ; cg = b>>6 (8 groups of 8 co). ACT: 0 none, 1 lrelu. bias may be null.
template<int ACT>
__global__ void __launch_bounds__(256) conv3x3_t(
    const float* __restrict__ in, const float* __restrict__ w,
    const float* __restrict__ bias, float* __restrict__ out)
{
    __shared__ float lin[8][34][34];
    __shared__ float lw[8][8][9];
    int b = blockIdx.x;
    int n = b & 63, cg = b >> 6;
    int tid = threadIdx.x;
    int r = tid >> 3, g = tid & 7, c0 = g << 2;
    const float* inp = in + (size_t)n * 65536;

    float acc[8][4];
    #pragma unroll
    for (int co = 0; co < 8; ++co) { acc[co][0]=acc[co][1]=acc[co][2]=acc[co][3]=0.f; }

    for (int i = tid; i < 8 * 34 * 34; i += 256) ((float*)lin)[i] = 0.f;

    for (int cic = 0; cic < 8; ++cic) {
        __syncthreads();
        for (int i = tid; i < 8192; i += 256) {
            int ci = i >> 10, p = i & 1023;
            lin[ci][(p >> 5) + 1][(p & 31) + 1] = inp[(cic * 8 + ci) * 1024 + p];
        }
        for (int i = tid; i < 576; i += 256) {
            int ci = i / 72, rr = i % 72;
            int co = rr / 9, tt = rr % 9;
            lw[ci][co][tt] = w[((cg * 8 + co) * 64 + cic * 8 + ci) * 9 + tt];
        }
        __syncthreads();
        #pragma unroll 2
        for (int ci = 0; ci < 8; ++ci) {
            float win[3][6];
            #pragma unroll
            for (int dy = 0; dy < 3; ++dy)
                #pragma unroll
                for (int dx = 0; dx < 6; ++dx)
                    win[dy][dx] = lin[ci][r + dy][c0 + dx];
            #pragma unroll
            for (int co = 0; co < 8; ++co) {
                #pragma unroll
                for (int dy = 0; dy < 3; ++dy)
                    #pragma unroll
                    for (int dx = 0; dx < 3; ++dx) {
                        float wv = lw[ci][co][dy * 3 + dx];
                        #pragma unroll
                        for (int j = 0; j < 4; ++j)
                            acc[co][j] = fmaf(win[dy][j + dx], wv, acc[co][j]);
                    }
            }
        }
    }
    size_t ob = ((size_t)(n * 64 + cg * 8) << 10) + (r << 5) + c0;
    #pragma unroll
    for (int co = 0; co < 8; ++co) {
        float bv = bias ? bias[cg * 8 + co] : 0.f;
        float4 v;
        float a0 = acc[co][0] + bv, a1 = acc[co][1] + bv, a2 = acc[co][2] + bv, a3 = acc[co][3] + bv;
        if (ACT == 1) { a0 = lrelu(a0); a1 = lrelu(a1); a2 = lrelu(a2); a3 = lrelu(a3); }
        v.x = a0; v.y = a1; v.z = a2; v.w = a3;
        *(float4*)(out + ob + ((size_t)co << 10)) = v;
    }
}

// ================= conv1x1 64->64 @ 32x32 =================
// grid 256: n = b&63 ; cg = b>>6 (4 groups of 16 co). bias may be null.
template<int ACT>
__global__ void __launch_bounds__(256) conv1x1_t(
    const float* __restrict__ in, const float* __restrict__ w,
    const float* __restrict__ bias, float* __restrict__ out)
{
    __shared__ float lw[64][16];
    int b = blockIdx.x;
    int n = b & 63, cg = b >> 6;
    int tid = threadIdx.x;
    for (int i = tid; i < 1024; i += 256) {
        int ci = i >> 4, co = i & 15;
        lw[ci][co] = w[(cg * 16 + co) * 64 + ci];
    }
    __syncthreads();
    const float4* in4 = (const float4*)(in + (size_t)n * 65536);
    float acc[16][4];
    #pragma unroll
    for (int co = 0; co < 16; ++co) { acc[co][0]=acc[co][1]=acc[co][2]=acc[co][3]=0.f; }
    #pragma unroll 8
    for (int ci = 0; ci < 64; ++ci) {
        float4 xv = in4[(ci << 8) + tid];
        const float4* wv4 = (const float4*)lw[ci];
        #pragma unroll
        for (int q = 0; q < 4; ++q) {
            float4 wv = wv4[q];
            acc[4*q+0][0] = fmaf(xv.x, wv.x, acc[4*q+0][0]);
            acc[4*q+0][1] = fmaf(xv.y, wv.x, acc[4*q+0][1]);
            acc[4*q+0][2] = fmaf(xv.z, wv.x, acc[4*q+0][2]);
            acc[4*q+0][3] = fmaf(xv.w, wv.x, acc[4*q+0][3]);
            acc[4*q+1][0] = fmaf(xv.x, wv.y, acc[4*q+1][0]);
            acc[4*q+1][1] = fmaf(xv.y, wv.y, acc[4*q+1][1]);
            acc[4*q+1][2] = fmaf(xv.z, wv.y, acc[4*q+1][2]);
            acc[4*q+1][3] = fmaf(xv.w, wv.y, acc[4*q+1][3]);
            acc[4*q+2][0] = fmaf(xv.x, wv.z, acc[4*q+2][0]);
            acc[4*q+2][1] = fmaf(xv.y, wv.z, acc[4*q+2][1]);
            acc[4*q+2][2] = fmaf(xv.z, wv.z, acc[4*q+2][2]);
            acc[4*q+2][3] = fmaf(xv.w, wv.z, acc[4*q+2][3]);
            acc[4*q+3][0] = fmaf(xv.x, wv.w, acc[4*q+3][0]);
            acc[4*q+3][1] = fmaf(xv.y, wv.w, acc[4*q+3][1]);
            acc[4*q+3][2] = fmaf(xv.z, wv.w, acc[4*q+3][2]);
            acc[4*q+3][3] = fmaf(xv.w, wv.w, acc[4*q+3][3]);
        }
    }
    #pragma unroll
    for (int co = 0; co < 16; ++co) {
        float bv = bias ? bias[cg * 16 + co] : 0.f;
        float a0 = acc[co][0] + bv, a1 = acc[co][1] + bv, a2 = acc[co][2] + bv, a3 = acc[co][3] + bv;
        if (ACT == 1) { a0 = lrelu(a0); a1 = lrelu(a1); a2 = lrelu(a2); a3 = lrelu(a3); }
        float4 v; v.x = a0; v.y = a1; v.z = a2; v.w = a3;
        ((float4*)(out + (size_t)n * 65536 + (size_t)(cg * 16 + co) * 1024))[tid] = v;
    }
}

// ================= BN stats (float4, deterministic) =================
// grid 512: c = b>>3, s = b&7 ; each handles 8 images' (n,c) planes
__global__ void __launch_bounds__(256) bn_stats2_k(
    const float* __restrict__ in, float* __restrict__ part)
{
    int b = blockIdx.x;
    int c = b >> 3, s = b & 7;
    int tid = threadIdx.x;
    float sum = 0.f, ss = 0.f;
    for (int nn = 0; nn < 8; ++nn) {
        int n = s * 8 + nn;
        float4 v = ((const float4*)(in + ((size_t)(n * 64 + c) << 10)))[tid];
        sum += v.x + v.y + v.z + v.w;
        ss = fmaf(v.x, v.x, ss); ss = fmaf(v.y, v.y, ss);
        ss = fmaf(v.z, v.z, ss); ss = fmaf(v.w, v.w, ss);
    }
    __shared__ float s1[256], s2[256];
    s1[tid] = sum; s2[tid] = ss;
    __syncthreads();
    for (int st = 128; st > 0; st >>= 1) {
        if (tid < st) { s1[tid] += s1[tid + st]; s2[tid] += s2[tid + st]; }
        __syncthreads();
    }
    if (tid == 0) {
        part[(2 * c) * 8 + s]     = s1[0];
        part[(2 * c + 1) * 8 + s] = s2[0];
    }
}

__global__ void bn_fin_k(const float* __restrict__ part, float* __restrict__ fin, float invM)
{
    int c = threadIdx.x;
    if (c >= 64) return;
    float sum = 0.f, ss = 0.f;
    for (int s = 0; s < 8; ++s) { sum += part[(2 * c) * 8 + s]; ss += part[(2 * c + 1) * 8 + s]; }
    float mean = sum * invM;
    float var  = ss * invM - mean * mean;
    fin[2 * c] = mean;
    fin[2 * c + 1] = rsqrtf(var + 1e-5f);
}

// ================= BN apply (+act / +residual), float4 =================
template<int MODE>  // 0: relu(bn(x)) ; 1: lrelu(res + bn(x))
__global__ void __launch_bounds__(256) bn_apply2_k(
    const float* __restrict__ in, const float* __restrict__ fin,
    const float* __restrict__ g, const float* __restrict__ beta,
    const float* __restrict__ res, float* __restrict__ out)
{
    int i = blockIdx.x * 256 + threadIdx.x;   // float4 index over 64*64*1024 elements
    int c = (i >> 8) & 63;
    float ga = g[c] * fin[2 * c + 1];
    float bb = beta[c] - fin[2 * c] * ga;
    float4 v = ((const float4*)in)[i];
    float y0 = fmaf(v.x, ga, bb), y1 = fmaf(v.y, ga, bb);
    float y2 = fmaf(v.z, ga, bb), y3 = fmaf(v.w, ga, bb);
    float4 o;
    if (MODE == 0) {
        o.x = fmaxf(y0, 0.f); o.y = fmaxf(y1, 0.f); o.z = fmaxf(y2, 0.f); o.w = fmaxf(y3, 0.f);
    } else {
        float4 rv = ((const float4*)res)[i];
        o.x = lrelu(rv.x + y0); o.y = lrelu(rv.y + y1); o.z = lrelu(rv.z + y2); o.w = lrelu(rv.w + y3);
    }
    ((float4*)out)[i] = o;
}

// ================= VQ =================
__global__ void __launch_bounds__(256) vq_enorm_k(const float* __restrict__ emb, float* __restrict__ enorm)
{
    int k = blockIdx.x * 256 + threadIdx.x;
    if (k >= 512) return;
    const float4* e4 = (const float4*)(emb + (k << 6));
    float s = 0.f;
    #pragma unroll
    for (int j = 0; j < 16; ++j) {
        float4 e = e4[j];
        s = fmaf(e.x, e.x, s); s = fmaf(e.y, e.y, s);
        s = fmaf(e.z, e.z, s); s = fmaf(e.w, e.w, s);
    }
    enorm[k] = s;
}

__global__ void __launch_bounds__(256) vq_k(
    const float* __restrict__ z, const float* __restrict__ emb,
    const float* __restrict__ enorm,
    float* __restrict__ out_q, float* __restrict__ out_e,
    float* __restrict__ partials)
{
    __shared__ float se[64][64];
    __shared__ float sn[64];
    int m = blockIdx.x * 256 + threadIdx.x;
    int n = m >> 10, p = m & 1023;
    size_t base = (size_t)n * 65536 + p;
    float zr[64];
    #pragma unroll
    for (int d = 0; d < 64; ++d) zr[d] = z[base + (size_t)d * 1024];
    #pragma unroll
    for (int d = 0; d < 64; ++d) out_e[base + (size_t)d * 1024] = zr[d];

    float best = 3.4e38f;
    int bi = 0;
    for (int cic = 0; cic < 8; ++cic) {
        __syncthreads();
        for (int i = threadIdx.x; i < 4096; i += 256)
            se[i >> 6][i & 63] = emb[(cic << 12) + i];
        if (threadIdx.x < 64) sn[threadIdx.x] = enorm[(cic << 6) + threadIdx.x];
        __syncthreads();
        for (int k = 0; k < 64; ++k) {
            const float4* e4 = (const float4*)se[k];
            float dot = 0.f;
            #pragma unroll
            for (int j = 0; j < 16; ++j) {
                float4 e = e4[j];
                dot = fmaf(zr[4*j],   e.x, dot);
                dot = fmaf(zr[4*j+1], e.y, dot);
                dot = fmaf(zr[4*j+2], e.z, dot);
                dot = fmaf(zr[4*j+3], e.w, dot);
            }
            float s = fmaf(-2.f, dot, sn[k]);
            if (s < best) { best = s; bi = (cic << 6) + k; }
        }
    }

    float lsum = 0.f;
    const float* eb = emb + (bi << 6);
    #pragma unroll
    for (int d = 0; d < 64; ++d) {
        float q = eb[d];
        out_q[base + (size_t)d * 1024] = q;
        float df = q - zr[d];
        lsum = fmaf(df, df, lsum);
    }
    __shared__ float sh[256];
    sh[threadIdx.x] = lsum;
    __syncthreads();
    for (int st = 128; st > 0; st >>= 1) {
        if (threadIdx.x < st) sh[threadIdx.x] += sh[threadIdx.x + st];
        __syncthreads();
    }
    if (threadIdx.x == 0) partials[blockIdx.x] = sh[0];
}

__global__ void vq_fin_k(const float* __restrict__ partials, float* __restrict__ out)
{
    __shared__ float sh[256];
    sh[threadIdx.x] = partials[threadIdx.x];
    __syncthreads();
    for (int st = 128; st > 0; st >>= 1) {
        if (threadIdx.x < st) sh[threadIdx.x] += sh[threadIdx.x + st];
        __syncthreads();
    }
    if (threadIdx.x == 0) out[0] = sh[0] * (0.25f / (65536.f * 64.f));
}

// ================= dt1: deconv 64->32, 32x32 -> 64x64, lrelu =================
// grid 1024: n = b&63 ; rt = (b>>6)&3 (4 row tiles of 16) ; cg = b>>8 (4 groups of 8 co)
__global__ void __launch_bounds__(256) deconv_dt1_t(
    const float* __restrict__ in, const float* __restrict__ w,
    const float* __restrict__ bias, float* __restrict__ out)
{
    __shared__ float lin[8][10][37];
    __shared__ float lw[8][8][16];
    int b = blockIdx.x;
    int n = b & 63, rt = (b >> 6) & 3, cg = b >> 8;
    int tid = threadIdx.x;
    int r16 = tid >> 4, g = tid & 15;
    int oy = rt * 16 + r16;
    const float* inp = in + (size_t)n * 65536;
    int iy0 = rt * 8 - 1;
    int ky0 = (oy + 1) & 1;
    int iyA = ((oy + 1 - ky0) >> 1) - iy0;
    int iyB = iyA - 1;
    int lx = 2 * g;

    float acc[8][4];
    #pragma unroll
    for (int co = 0; co < 8; ++co) { acc[co][0]=acc[co][1]=acc[co][2]=acc[co][3]=0.f; }

    for (int cic = 0; cic < 8; ++cic) {
        __syncthreads();
        for (int i = tid; i < 2720; i += 256) {
            int ci = i / 340, rr = i % 340;
            int y = rr / 34, xx = rr % 34;
            int gy = iy0 + y, gx = xx - 1;
            float v = 0.f;
            if (gy >= 0 && gy < 32 && gx >= 0 && gx < 32)
                v = inp[(cic * 8 + ci) * 1024 + gy * 32 + gx];
            lin[ci][y][xx] = v;
        }
        for (int i = tid; i < 1024; i += 256) {
            int ci = i >> 7, rr = i & 127, co = rr >> 4, tt = rr & 15;
            lw[ci][co][tt] = w[((cic * 8 + ci) * 32 + cg * 8 + co) * 16 + tt];
        }
        __syncthreads();
        #pragma unroll 2
        for (int ci = 0; ci < 8; ++ci) {
            float vA0 = lin[ci][iyA][lx],     vA1 = lin[ci][iyA][lx + 1];
            float vA2 = lin[ci][iyA][lx + 2], vA3 = lin[ci][iyA][lx + 3];
            float vB0 = lin[ci][iyB][lx],     vB1 = lin[ci][iyB][lx + 1];
            float vB2 = lin[ci][iyB][lx + 2], vB3 = lin[ci][iyB][lx + 3];
            #pragma unroll
            for (int co = 0; co < 8; ++co) {
                const float4* wp = (const float4*)lw[ci][co];
                float4 wA = wp[ky0];
                float4 wB = wp[ky0 + 2];
                acc[co][0] = fmaf(vA1, wA.y, fmaf(vA0, wA.w, fmaf(vB1, wB.y, fmaf(vB0, wB.w, acc[co][0]))));
                acc[co][1] = fmaf(vA2, wA.x, fmaf(vA1, wA.z, fmaf(vB2, wB.x, fmaf(vB1, wB.z, acc[co][1]))));
                acc[co][2] = fmaf(vA2, wA.y, fmaf(vA1, wA.w, fmaf(vB2, wB.y, fmaf(vB1, wB.w, acc[co][2]))));
                acc[co][3] = fmaf(vA3, wA.x, fmaf(vA2, wA.z, fmaf(vB3, wB.x, fmaf(vB2, wB.z, acc[co][3]))));
            }
        }
    }
    #pragma unroll
    for (int co = 0; co < 8; ++co) {
        float bv = bias[cg * 8 + co];
        float4 v;
        v.x = lrelu(acc[co][0] + bv); v.y = lrelu(acc[co][1] + bv);
        v.z = lrelu(acc[co][2] + bv); v.w = lrelu(acc[co][3] + bv);
        *(float4*)(out + ((size_t)(n * 32 + cg * 8 + co) * 4096) + oy * 64 + 4 * g) = v;
    }
}

// ================= dt2: deconv 32->3, 64x64 -> 128x128, tanh =================
// grid 1024: n = b&63 ; rt = b>>6 (16 row tiles of 8)
__global__ void __launch_bounds__(256) deconv_dt2_t(
    const float* __restrict__ in, const float* __restrict__ w,
    const float* __restrict__ bias, float* __restrict__ out)
{
    __shared__ float lin[8][6][67];
    __shared__ float lw[8][3][16];
    int b = blockIdx.x;
    int n = b & 63, rt = b >> 6;
    int tid = threadIdx.x;
    int r8 = tid >> 5, g = tid & 31;
    int oy = rt * 8 + r8;
    const float* inp = in + (size_t)n * 32 * 4096;
    int iy0 = rt * 4 - 1;
    int ky0 = (oy + 1) & 1;
    int iyA = ((oy + 1 - ky0) >> 1) - iy0;
    int iyB = iyA - 1;
    int lx = 2 * g;

    float acc[3][4];
    #pragma unroll
    for (int co = 0; co < 3; ++co) { acc[co][0]=acc[co][1]=acc[co][2]=acc[co][3]=0.f; }

    for (int cic = 0; cic < 4; ++cic) {
        __syncthreads();
        for (int i = tid; i < 3168; i += 256) {
            int ci = i / 396, rr = i % 396;
            int y = rr / 66, xx = rr % 66;
            int gy = iy0 + y, gx = xx - 1;
            float v = 0.f;
            if (gy >= 0 && gy < 64 && gx >= 0 && gx < 64)
                v = inp[(cic * 8 + ci) * 4096 + gy * 64 + gx];
            lin[ci][y][xx] = v;
        }
        for (int i = tid; i < 384; i += 256) {
            int ci = i / 48, rr = i % 48;
            int co = rr >> 4, tt = rr & 15;
            lw[ci][co][tt] = w[((cic * 8 + ci) * 3 + co) * 16 + tt];
        }
        __syncthreads();
        #pragma unroll 2
        for (int ci = 0; ci < 8; ++ci) {
            float vA0 = lin[ci][iyA][lx],     vA1 = lin[ci][iyA][lx + 1];
            float vA2 = lin[ci][iyA][lx + 2], vA3 = lin[ci][iyA][lx + 3];
            float vB0 = lin[ci][iyB][lx],     vB1 = lin[ci][iyB][lx + 1];
            float vB2 = lin[ci][iyB][lx + 2], vB3 = lin[ci][iyB][lx + 3];
            #pragma unroll
            for (int co = 0; co < 3; ++co) {
                const float4* wp = (const float4*)lw[ci][co];
                float4 wA = wp[ky0];
                float4 wB = wp[ky0 + 2];
                acc[co][0] = fmaf(vA1, wA.y, fmaf(vA0, wA.w, fmaf(vB1, wB.y, fmaf(vB0, wB.w, acc[co][0]))));
                acc[co][1] = fmaf(vA2, wA.x, fmaf(vA1, wA.z, fmaf(vB2, wB.x, fmaf(vB1, wB.z, acc[co][1]))));
                acc[co][2] = fmaf(vA2, wA.y, fmaf(vA1, wA.w, fmaf(vB2, wB.y, fmaf(vB1, wB.w, acc[co][2]))));
                acc[co][3] = fmaf(vA3, wA.x, fmaf(vA2, wA.z, fmaf(vB3, wB.x, fmaf(vB2, wB.z, acc[co][3]))));
            }
        }
    }
    #pragma unroll
    for (int co = 0; co < 3; ++co) {
        float bv = bias[co];
        float4 v;
        v.x = fast_tanh(acc[co][0] + bv); v.y = fast_tanh(acc[co][1] + bv);
        v.z = fast_tanh(acc[co][2] + bv); v.w = fast_tanh(acc[co][3] + bv);
        *(float4*)(out + ((size_t)(n * 3 + co) * 16384) + oy * 128 + 4 * g) = v;
    }
}

extern "C" void kernel_launch(void* const* d_in, const int* in_sizes, int n_in,
                              void* d_out, int out_size, void* d_ws, size_t ws_size,
                              hipStream_t stream)
{
    const float* x    = (const float*)d_in[0];
    const float* e1w  = (const float*)d_in[1];
    const float* e1b  = (const float*)d_in[2];
    const float* e2w  = (const float*)d_in[3];
    const float* e2b  = (const float*)d_in[4];
    const float* e3w  = (const float*)d_in[5];
    const float* e3b  = (const float*)d_in[6];
    const float* er1w = (const float*)d_in[7];
    const float* er1g = (const float*)d_in[8];
    const float* er1b = (const float*)d_in[9];
    const float* er2w = (const float*)d_in[10];
    const float* er2g = (const float*)d_in[11];
    const float* er2b = (const float*)d_in[12];
    const float* e4w  = (const float*)d_in[13];
    const float* e4b  = (const float*)d_in[14];
    const float* emb  = (const float*)d_in[15];
    const float* d1w  = (const float*)d_in[16];
    const float* d1b  = (const float*)d_in[17];
    const float* dr1w = (const float*)d_in[18];
    const float* dr1g = (const float*)d_in[19];
    const float* dr1b = (const float*)d_in[20];
    const float* dr2w = (const float*)d_in[21];
    const float* dr2g = (const float*)d_in[22];
    const float* dr2b = (const float*)d_in[23];
    const float* dt1w = (const float*)d_in[24];
    const float* dt1b = (const float*)d_in[25];
    const float* dt2w = (const float*)d_in[26];
    const float* dt2b = (const float*)d_in[27];

    float* out = (float*)d_out;
    float* ws  = (float*)d_ws;

    // workspace layout (floats)
    float* B0 = ws;                   // 8,388,608  (64x32x64x64)
    float* B1 = ws + 8388608;         // 4,194,304  (64x64x32x32)
    float* B2 = B1 + 4194304;
    float* B3 = B2 + 4194304;
    float* B4 = B3 + 4194304;
    float* bn_part = B4 + 4194304;    // 1024 floats
    float* bn_fin  = bn_part + 2048;  // 128
    float* vq_part = bn_fin + 128;    // 256
    float* enorm   = vq_part + 256;   // 512

    float* out_recon = out;                 // 3,145,728
    float* out_q     = out + 3145728;       // 4,194,304
    float* out_e     = out + 7340032;       // 4,194,304
    float* out_loss  = out + 11534336;      // 1

    const float invM = 1.f / 65536.f;

    // ---------------- encoder ----------------
    conv_e1_t<<<512, 256, 0, stream>>>(x, e1w, e1b, B0);
    conv_e2_t<<<512, 256, 0, stream>>>(B0, e2w, e2b, B1);
    conv3x3_t<1><<<512, 256, 0, stream>>>(B1, e3w, e3b, B2);

    // encoder resblock
    conv3x3_t<0><<<512, 256, 0, stream>>>(B2, er1w, nullptr, B3);
    bn_stats2_k<<<512, 256, 0, stream>>>(B3, bn_part);
    bn_fin_k<<<1, 64, 0, stream>>>(bn_part, bn_fin, invM);
    bn_apply2_k<0><<<4096, 256, 0, stream>>>(B3, bn_fin, er1g, er1b, nullptr, B1);
    conv1x1_t<0><<<256, 256, 0, stream>>>(B1, er2w, nullptr, B3);
    bn_stats2_k<<<512, 256, 0, stream>>>(B3, bn_part);
    bn_fin_k<<<1, 64, 0, stream>>>(bn_part, bn_fin, invM);
    bn_apply2_k<1><<<4096, 256, 0, stream>>>(B3, bn_fin, er2g, er2b, B2, B1);

    // e4 + VQ
    conv1x1_t<1><<<256, 256, 0, stream>>>(B1, e4w, e4b, B2);
    vq_enorm_k<<<2, 256, 0, stream>>>(emb, enorm);
    vq_k<<<256, 256, 0, stream>>>(B2, emb, enorm, out_q, out_e, vq_part);
    vq_fin_k<<<1, 256, 0, stream>>>(vq_part, out_loss);

    // ---------------- decoder ----------------
    conv3x3_t<1><<<512, 256, 0, stream>>>(out_q, d1w, d1b, B2);

    conv3x3_t<0><<<512, 256, 0, stream>>>(B2, dr1w, nullptr, B3);
    bn_stats2_k<<<512, 256, 0, stream>>>(B3, bn_part);
    bn_fin_k<<<1, 64, 0, stream>>>(bn_part, bn_fin, invM);
    bn_apply2_k<0><<<4096, 256, 0, stream>>>(B3, bn_fin, dr1g, dr1b, nullptr, B4);
    conv1x1_t<0><<<256, 256, 0, stream>>>(B4, dr2w, nullptr, B3);
    bn_stats2_k<<<512, 256, 0, stream>>>(B3, bn_part);
    bn_fin_k<<<1, 64, 0, stream>>>(bn_part, bn_fin, invM);
    bn_apply2_k<1><<<4096, 256, 0, stream>>>(B3, bn_fin, dr2g, dr2b, B2, B1);

    // deconvs
    deconv_dt1_t<<<1024, 256, 0, stream>>>(B1, dt1w, dt1b, B0);
    deconv_dt2_t<<<1024, 256, 0, stream>>>(B0, dt2w, dt2b, out_recon);
}

// Round 6
// 765.471 us; speedup vs baseline: 7.4372x; 1.2592x over previous
//
#include <hip/hip_runtime.h>
#include <math.h>

#define LREL 0.01f
__device__ __forceinline__ float lrelu(float x) { return x > 0.f ? x : LREL * x; }
__device__ __forceinline__ float fast_tanh(float x) {
    x = fminf(fmaxf(x, -10.f), 10.f);
    float a = __expf(2.f * x);
    return (a - 1.f) / (a + 1.f);
}

// ================= e1: 3->32, 128x128 -> 64x64, 4x4 s2 p1, lrelu =================
__global__ void __launch_bounds__(256) conv_e1_t(
    const float* __restrict__ x, const float* __restrict__ w,
    const float* __restrict__ bias, float* __restrict__ out)
{
    __shared__ float lin[3][66][67];
    __shared__ float lw[3][16][16];
    int b = blockIdx.x;
    int n = b & 63, t = b >> 6;
    int tile = t & 3, cg = t >> 2;
    int ty = tile >> 1, tx = tile & 1;
    int tid = threadIdx.x;
    int r = tid >> 3, g = tid & 7, c0 = g << 2;
    const float* inp = x + (size_t)n * 3 * 16384;

    for (int i = tid; i < 3 * 66 * 66; i += 256) {
        int ci = i / 4356, rr = i % 4356;
        int y = rr / 66, xx = rr % 66;
        int gy = ty * 64 - 1 + y, gx = tx * 64 - 1 + xx;
        float v = 0.f;
        if (gy >= 0 && gy < 128 && gx >= 0 && gx < 128)
            v = inp[ci * 16384 + gy * 128 + gx];
        lin[ci][y][xx] = v;
    }
    for (int i = tid; i < 768; i += 256) {
        int ci = i >> 8, rr = i & 255, co = rr >> 4, tt = rr & 15;
        lw[ci][co][tt] = w[((cg * 16 + co) * 3 + ci) * 16 + tt];
    }
    __syncthreads();

    float acc[16][4];
    #pragma unroll
    for (int co = 0; co < 16; ++co) { acc[co][0]=acc[co][1]=acc[co][2]=acc[co][3]=0.f; }

    #pragma unroll
    for (int ci = 0; ci < 3; ++ci) {
        float win[4][10];
        #pragma unroll
        for (int dy = 0; dy < 4; ++dy)
            #pragma unroll
            for (int dx = 0; dx < 10; ++dx)
                win[dy][dx] = lin[ci][2 * r + dy][8 * g + dx];
        #pragma unroll
        for (int co = 0; co < 16; ++co) {
            #pragma unroll
            for (int ky = 0; ky < 4; ++ky)
                #pragma unroll
                for (int kx = 0; kx < 4; ++kx) {
                    float wv = lw[ci][co][ky * 4 + kx];
                    #pragma unroll
                    for (int j = 0; j < 4; ++j)
                        acc[co][j] = fmaf(win[ky][2 * j + kx], wv, acc[co][j]);
                }
        }
    }
    int oy = ty * 32 + r, ox0 = tx * 32 + c0;
    #pragma unroll
    for (int co = 0; co < 16; ++co) {
        float bv = bias[cg * 16 + co];
        float4 v;
        v.x = lrelu(acc[co][0] + bv); v.y = lrelu(acc[co][1] + bv);
        v.z = lrelu(acc[co][2] + bv); v.w = lrelu(acc[co][3] + bv);
        *(float4*)(out + ((size_t)(n * 32 + cg * 16 + co) * 4096) + oy * 64 + ox0) = v;
    }
}

// ================= e2: 32->64, 64x64 -> 32x32, 4x4 s2 p1, lrelu =================
__global__ void __launch_bounds__(256) conv_e2_t(
    const float* __restrict__ in, const float* __restrict__ w,
    const float* __restrict__ bias, float* __restrict__ out)
{
    __shared__ float lin[2][66][66];
    __shared__ float lw[2][8][16];
    int b = blockIdx.x;
    int n = b & 63, cg = b >> 6;
    int tid = threadIdx.x;
    int r = tid >> 3, g = tid & 7, c0 = g << 2;
    const float* inp = in + (size_t)n * 32 * 4096;

    float acc[8][4];
    #pragma unroll
    for (int co = 0; co < 8; ++co) { acc[co][0]=acc[co][1]=acc[co][2]=acc[co][3]=0.f; }

    for (int i = tid; i < 2 * 66 * 66; i += 256) ((float*)lin)[i] = 0.f;

    for (int cic = 0; cic < 16; ++cic) {
        __syncthreads();
        for (int i = tid; i < 8192; i += 256) {
            int ci = i >> 12, p = i & 4095;
            lin[ci][(p >> 6) + 1][(p & 63) + 1] = inp[(cic * 2 + ci) * 4096 + p];
        }
        {
            int i = tid;
            if (i < 256) {
                int ci = i >> 7, rr = i & 127, co = rr >> 4, tt = rr & 15;
                lw[ci][co][tt] = w[((cg * 8 + co) * 32 + cic * 2 + ci) * 16 + tt];
            }
        }
        __syncthreads();
        #pragma unroll
        for (int ci = 0; ci < 2; ++ci) {
            float win[4][10];
            #pragma unroll
            for (int dy = 0; dy < 4; ++dy)
                #pragma unroll
                for (int dx = 0; dx < 10; ++dx)
                    win[dy][dx] = lin[ci][2 * r + dy][8 * g + dx];
            #pragma unroll
            for (int co = 0; co < 8; ++co) {
                #pragma unroll
                for (int ky = 0; ky < 4; ++ky)
                    #pragma unroll
                    for (int kx = 0; kx < 4; ++kx) {
                        float wv = lw[ci][co][ky * 4 + kx];
                        #pragma unroll
                        for (int j = 0; j < 4; ++j)
                            acc[co][j] = fmaf(win[ky][2 * j + kx], wv, acc[co][j]);
                    }
            }
        }
    }
    size_t ob = ((size_t)(n * 64 + cg * 8) << 10) + (r << 5) + c0;
    #pragma unroll
    for (int co = 0; co < 8; ++co) {
        float bv = bias[cg * 8 + co];
        float4 v;
        v.x = lrelu(acc[co][0] + bv); v.y = lrelu(acc[co][1] + bv);
        v.z = lrelu(acc[co][2] + bv); v.w = lrelu(acc[co][3] + bv);
        *(float4*)(out + ob + ((size_t)co << 10)) = v;
    }
}

// ================= conv3x3 p1, 64->64 @ 32x32 =================
template<int ACT>
__global__ void __launch_bounds__(256) conv3x3_t(
    const float* __restrict__ in, const float* __restrict__ w,
    const float* __restrict__ bias, float* __restrict__ out)
{
    __shared__ float lin[8][34][34];
    __shared__ float lw[8][8][9];
    int b = blockIdx.x;
    int n = b & 63, cg = b >> 6;
    int tid = threadIdx.x;
    int r = tid >> 3, g = tid & 7, c0 = g << 2;
    const float* inp = in + (size_t)n * 65536;

    float acc[8][4];
    #pragma unroll
    for (int co = 0; co < 8; ++co) { acc[co][0]=acc[co][1]=acc[co][2]=acc[co][3]=0.f; }

    for (int i = tid; i < 8 * 34 * 34; i += 256) ((float*)lin)[i] = 0.f;

    for (int cic = 0; cic < 8; ++cic) {
        __syncthreads();
        for (int i = tid; i < 8192; i += 256) {
            int ci = i >> 10, p = i & 1023;
            lin[ci][(p >> 5) + 1][(p & 31) + 1] = inp[(cic * 8 + ci) * 1024 + p];
        }
        for (int i = tid; i < 576; i += 256) {
            int ci = i / 72, rr = i % 72;
            int co = rr / 9, tt = rr % 9;
            lw[ci][co][tt] = w[((cg * 8 + co) * 64 + cic * 8 + ci) * 9 + tt];
        }
        __syncthreads();
        #pragma unroll 2
        for (int ci = 0; ci < 8; ++ci) {
            float win[3][6];
            #pragma unroll
            for (int dy = 0; dy < 3; ++dy)
                #pragma unroll
                for (int dx = 0; dx < 6; ++dx)
                    win[dy][dx] = lin[ci][r + dy][c0 + dx];
            #pragma unroll
            for (int co = 0; co < 8; ++co) {
                #pragma unroll
                for (int dy = 0; dy < 3; ++dy)
                    #pragma unroll
                    for (int dx = 0; dx < 3; ++dx) {
                        float wv = lw[ci][co][dy * 3 + dx];
                        #pragma unroll
                        for (int j = 0; j < 4; ++j)
                            acc[co][j] = fmaf(win[dy][j + dx], wv, acc[co][j]);
                    }
            }
        }
    }
    size_t ob = ((size_t)(n * 64 + cg * 8) << 10) + (r << 5) + c0;
    #pragma unroll
    for (int co = 0; co < 8; ++co) {
        float bv = bias ? bias[cg * 8 + co] : 0.f;
        float4 v;
        float a0 = acc[co][0] + bv, a1 = acc[co][1] + bv, a2 = acc[co][2] + bv, a3 = acc[co][3] + bv;
        if (ACT == 1) { a0 = lrelu(a0); a1 = lrelu(a1); a2 = lrelu(a2); a3 = lrelu(a3); }
        v.x = a0; v.y = a1; v.z = a2; v.w = a3;
        *(float4*)(out + ob + ((size_t)co << 10)) = v;
    }
}

// ================= conv1x1 64->64 @ 32x32 =================
template<int ACT>
__global__ void __launch_bounds__(256) conv1x1_t(
    const float* __restrict__ in, const float* __restrict__ w,
    const float* __restrict__ bias, float* __restrict__ out)
{
    __shared__ float lw[64][16];
    int b = blockIdx.x;
    int n = b & 63, cg = b >> 6;
    int tid = threadIdx.x;
    for (int i = tid; i < 1024; i += 256) {
        int ci = i >> 4, co = i & 15;
        lw[ci][co] = w[(cg * 16 + co) * 64 + ci];
    }
    __syncthreads();
    const float4* in4 = (const float4*)(in + (size_t)n * 65536);
    float acc[16][4];
    #pragma unroll
    for (int co = 0; co < 16; ++co) { acc[co][0]=acc[co][1]=acc[co][2]=acc[co][3]=0.f; }
    #pragma unroll 8
    for (int ci = 0; ci < 64; ++ci) {
        float4 xv = in4[(ci << 8) + tid];
        const float4* wv4 = (const float4*)lw[ci];
        #pragma unroll
        for (int q = 0; q < 4; ++q) {
            float4 wv = wv4[q];
            acc[4*q+0][0] = fmaf(xv.x, wv.x, acc[4*q+0][0]);
            acc[4*q+0][1] = fmaf(xv.y, wv.x, acc[4*q+0][1]);
            acc[4*q+0][2] = fmaf(xv.z, wv.x, acc[4*q+0][2]);
            acc[4*q+0][3] = fmaf(xv.w, wv.x, acc[4*q+0][3]);
            acc[4*q+1][0] = fmaf(xv.x, wv.y, acc[4*q+1][0]);
            acc[4*q+1][1] = fmaf(xv.y, wv.y, acc[4*q+1][1]);
            acc[4*q+1][2] = fmaf(xv.z, wv.y, acc[4*q+1][2]);
            acc[4*q+1][3] = fmaf(xv.w, wv.y, acc[4*q+1][3]);
            acc[4*q+2][0] = fmaf(xv.x, wv.z, acc[4*q+2][0]);
            acc[4*q+2][1] = fmaf(xv.y, wv.z, acc[4*q+2][1]);
            acc[4*q+2][2] = fmaf(xv.z, wv.z, acc[4*q+2][2]);
            acc[4*q+2][3] = fmaf(xv.w, wv.z, acc[4*q+2][3]);
            acc[4*q+3][0] = fmaf(xv.x, wv.w, acc[4*q+3][0]);
            acc[4*q+3][1] = fmaf(xv.y, wv.w, acc[4*q+3][1]);
            acc[4*q+3][2] = fmaf(xv.z, wv.w, acc[4*q+3][2]);
            acc[4*q+3][3] = fmaf(xv.w, wv.w, acc[4*q+3][3]);
        }
    }
    #pragma unroll
    for (int co = 0; co < 16; ++co) {
        float bv = bias ? bias[cg * 16 + co] : 0.f;
        float a0 = acc[co][0] + bv, a1 = acc[co][1] + bv, a2 = acc[co][2] + bv, a3 = acc[co][3] + bv;
        if (ACT == 1) { a0 = lrelu(a0); a1 = lrelu(a1); a2 = lrelu(a2); a3 = lrelu(a3); }
        float4 v; v.x = a0; v.y = a1; v.z = a2; v.w = a3;
        ((float4*)(out + (size_t)n * 65536 + (size_t)(cg * 16 + co) * 1024))[tid] = v;
    }
}

// ================= BN stats (float4, deterministic) =================
__global__ void __launch_bounds__(256) bn_stats2_k(
    const float* __restrict__ in, float* __restrict__ part)
{
    int b = blockIdx.x;
    int c = b >> 3, s = b & 7;
    int tid = threadIdx.x;
    float sum = 0.f, ss = 0.f;
    for (int nn = 0; nn < 8; ++nn) {
        int n = s * 8 + nn;
        float4 v = ((const float4*)(in + ((size_t)(n * 64 + c) << 10)))[tid];
        sum += v.x + v.y + v.z + v.w;
        ss = fmaf(v.x, v.x, ss); ss = fmaf(v.y, v.y, ss);
        ss = fmaf(v.z, v.z, ss); ss = fmaf(v.w, v.w, ss);
    }
    __shared__ float s1[256], s2[256];
    s1[tid] = sum; s2[tid] = ss;
    __syncthreads();
    for (int st = 128; st > 0; st >>= 1) {
        if (tid < st) { s1[tid] += s1[tid + st]; s2[tid] += s2[tid + st]; }
        __syncthreads();
    }
    if (tid == 0) {
        part[(2 * c) * 8 + s]     = s1[0];
        part[(2 * c + 1) * 8 + s] = s2[0];
    }
}

__global__ void bn_fin_k(const float* __restrict__ part, float* __restrict__ fin, float invM)
{
    int c = threadIdx.x;
    if (c >= 64) return;
    float sum = 0.f, ss = 0.f;
    for (int s = 0; s < 8; ++s) { sum += part[(2 * c) * 8 + s]; ss += part[(2 * c + 1) * 8 + s]; }
    float mean = sum * invM;
    float var  = ss * invM - mean * mean;
    fin[2 * c] = mean;
    fin[2 * c + 1] = rsqrtf(var + 1e-5f);
}

// ================= BN apply (+act / +residual), float4 =================
template<int MODE>
__global__ void __launch_bounds__(256) bn_apply2_k(
    const float* __restrict__ in, const float* __restrict__ fin,
    const float* __restrict__ g, const float* __restrict__ beta,
    const float* __restrict__ res, float* __restrict__ out)
{
    int i = blockIdx.x * 256 + threadIdx.x;
    int c = (i >> 8) & 63;
    float ga = g[c] * fin[2 * c + 1];
    float bb = beta[c] - fin[2 * c] * ga;
    float4 v = ((const float4*)in)[i];
    float y0 = fmaf(v.x, ga, bb), y1 = fmaf(v.y, ga, bb);
    float y2 = fmaf(v.z, ga, bb), y3 = fmaf(v.w, ga, bb);
    float4 o;
    if (MODE == 0) {
        o.x = fmaxf(y0, 0.f); o.y = fmaxf(y1, 0.f); o.z = fmaxf(y2, 0.f); o.w = fmaxf(y3, 0.f);
    } else {
        float4 rv = ((const float4*)res)[i];
        o.x = lrelu(rv.x + y0); o.y = lrelu(rv.y + y1); o.z = lrelu(rv.z + y2); o.w = lrelu(rv.w + y3);
    }
    ((float4*)out)[i] = o;
}

// ================= VQ =================
__global__ void __launch_bounds__(256) vq_enorm_k(const float* __restrict__ emb, float* __restrict__ enorm)
{
    int k = blockIdx.x * 256 + threadIdx.x;
    if (k >= 512) return;
    const float4* e4 = (const float4*)(emb + (k << 6));
    float s = 0.f;
    #pragma unroll
    for (int j = 0; j < 16; ++j) {
        float4 e = e4[j];
        s = fmaf(e.x, e.x, s); s = fmaf(e.y, e.y, s);
        s = fmaf(e.z, e.z, s); s = fmaf(e.w, e.w, s);
    }
    enorm[k] = s;
}

__device__ __forceinline__ unsigned order_u32(float s) {
    unsigned u = __float_as_uint(s);
    return (s < 0.f) ? ~u : (u | 0x80000000u);
}

// grid 1024: kb = b&7 (code block of 64), pg = b>>3 (pixel group of 512)
// thread: 2 pixels (m0 = pg*512+tid, m1 = m0+256); writes packed (dist,idx) per (kb, pixel)
__global__ void __launch_bounds__(256) vq_dist_k(
    const float* __restrict__ z, const float* __restrict__ emb,
    const float* __restrict__ enorm, unsigned long long* __restrict__ best)
{
    __shared__ float se[64][64];
    __shared__ float sn[64];
    int b = blockIdx.x;
    int kb = b & 7, pg = b >> 3;
    int tid = threadIdx.x;
    for (int i = tid; i < 4096; i += 256)
        ((float*)se)[i] = emb[(kb << 12) + i];
    if (tid < 64) sn[tid] = enorm[(kb << 6) + tid];
    __syncthreads();

    int n = pg >> 1;
    int p0 = ((pg & 1) << 9) + tid;
    size_t base0 = (size_t)n * 65536 + p0;
    float z0[64], z1[64];
    #pragma unroll
    for (int d = 0; d < 64; ++d) z0[d] = z[base0 + (size_t)d * 1024];
    #pragma unroll
    for (int d = 0; d < 64; ++d) z1[d] = z[base0 + 256 + (size_t)d * 1024];

    unsigned long long b0 = ~0ULL, b1 = ~0ULL;
    for (int k = 0; k < 64; ++k) {
        const float4* e4 = (const float4*)se[k];
        float dot0 = 0.f, dot1 = 0.f;
        #pragma unroll
        for (int j = 0; j < 16; ++j) {
            float4 e = e4[j];
            dot0 = fmaf(z0[4*j],   e.x, dot0);
            dot0 = fmaf(z0[4*j+1], e.y, dot0);
            dot0 = fmaf(z0[4*j+2], e.z, dot0);
            dot0 = fmaf(z0[4*j+3], e.w, dot0);
            dot1 = fmaf(z1[4*j],   e.x, dot1);
            dot1 = fmaf(z1[4*j+1], e.y, dot1);
            dot1 = fmaf(z1[4*j+2], e.z, dot1);
            dot1 = fmaf(z1[4*j+3], e.w, dot1);
        }
        float s0 = fmaf(-2.f, dot0, sn[k]);
        float s1 = fmaf(-2.f, dot1, sn[k]);
        unsigned kk = (unsigned)((kb << 6) + k);
        unsigned long long p0k = ((unsigned long long)order_u32(s0) << 32) | kk;
        unsigned long long p1k = ((unsigned long long)order_u32(s1) << 32) | kk;
        b0 = p0k < b0 ? p0k : b0;
        b1 = p1k < b1 ? p1k : b1;
    }
    size_t m0 = ((size_t)pg << 9) + tid;
    best[((size_t)kb << 16) + m0]       = b0;
    best[((size_t)kb << 16) + m0 + 256] = b1;
}

// grid 256 x 256thr: per pixel min over 8 code-blocks, gather q, loss partials
__global__ void __launch_bounds__(256) vq_combine_k(
    const float* __restrict__ z, const float* __restrict__ emb,
    const unsigned long long* __restrict__ best,
    float* __restrict__ out_q, float* __restrict__ partials)
{
    int m = blockIdx.x * 256 + threadIdx.x;
    unsigned long long bb = best[m];
    #pragma unroll
    for (int kb = 1; kb < 8; ++kb) {
        unsigned long long v = best[((size_t)kb << 16) + m];
        bb = v < bb ? v : bb;
    }
    int bi = (int)(bb & 0x1ffu);
    int n = m >> 10, p = m & 1023;
    size_t base = (size_t)n * 65536 + p;
    const float* eb = emb + (bi << 6);
    float lsum = 0.f;
    #pragma unroll
    for (int d = 0; d < 64; ++d) {
        float zz = z[base + (size_t)d * 1024];
        float q = eb[d];
        out_q[base + (size_t)d * 1024] = q;
        float df = q - zz;
        lsum = fmaf(df, df, lsum);
    }
    __shared__ float sh[256];
    sh[threadIdx.x] = lsum;
    __syncthreads();
    for (int st = 128; st > 0; st >>= 1) {
        if (threadIdx.x < st) sh[threadIdx.x] += sh[threadIdx.x + st];
        __syncthreads();
    }
    if (threadIdx.x == 0) partials[blockIdx.x] = sh[0];
}

__global__ void vq_fin_k(const float* __restrict__ partials, float* __restrict__ out)
{
    __shared__ float sh[256];
    sh[threadIdx.x] = partials[threadIdx.x];
    __syncthreads();
    for (int st = 128; st > 0; st >>= 1) {
        if (threadIdx.x < st) sh[threadIdx.x] += sh[threadIdx.x + st];
        __syncthreads();
    }
    if (threadIdx.x == 0) out[0] = sh[0] * (0.25f / (65536.f * 64.f));
}

// ================= dt1: deconv 64->32, 32x32 -> 64x64, lrelu =================
__global__ void __launch_bounds__(256) deconv_dt1_t(
    const float* __restrict__ in, const float* __restrict__ w,
    const float* __restrict__ bias, float* __restrict__ out)
{
    __shared__ float lin[8][10][37];
    __shared__ float lw[8][8][16];
    int b = blockIdx.x;
    int n = b & 63, rt = (b >> 6) & 3, cg = b >> 8;
    int tid = threadIdx.x;
    int r16 = tid >> 4, g = tid & 15;
    int oy = rt * 16 + r16;
    const float* inp = in + (size_t)n * 65536;
    int iy0 = rt * 8 - 1;
    int ky0 = (oy + 1) & 1;
    int iyA = ((oy + 1 - ky0) >> 1) - iy0;
    int iyB = iyA - 1;
    int lx = 2 * g;

    float acc[8][4];
    #pragma unroll
    for (int co = 0; co < 8; ++co) { acc[co][0]=acc[co][1]=acc[co][2]=acc[co][3]=0.f; }

    for (int cic = 0; cic < 8; ++cic) {
        __syncthreads();
        for (int i = tid; i < 2720; i += 256) {
            int ci = i / 340, rr = i % 340;
            int y = rr / 34, xx = rr % 34;
            int gy = iy0 + y, gx = xx - 1;
            float v = 0.f;
            if (gy >= 0 && gy < 32 && gx >= 0 && gx < 32)
                v = inp[(cic * 8 + ci) * 1024 + gy * 32 + gx];
            lin[ci][y][xx] = v;
        }
        for (int i = tid; i < 1024; i += 256) {
            int ci = i >> 7, rr = i & 127, co = rr >> 4, tt = rr & 15;
            lw[ci][co][tt] = w[((cic * 8 + ci) * 32 + cg * 8 + co) * 16 + tt];
        }
        __syncthreads();
        #pragma unroll 2
        for (int ci = 0; ci < 8; ++ci) {
            float vA0 = lin[ci][iyA][lx],     vA1 = lin[ci][iyA][lx + 1];
            float vA2 = lin[ci][iyA][lx + 2], vA3 = lin[ci][iyA][lx + 3];
            float vB0 = lin[ci][iyB][lx],     vB1 = lin[ci][iyB][lx + 1];
            float vB2 = lin[ci][iyB][lx + 2], vB3 = lin[ci][iyB][lx + 3];
            #pragma unroll
            for (int co = 0; co < 8; ++co) {
                const float4* wp = (const float4*)lw[ci][co];
                float4 wA = wp[ky0];
                float4 wB = wp[ky0 + 2];
                acc[co][0] = fmaf(vA1, wA.y, fmaf(vA0, wA.w, fmaf(vB1, wB.y, fmaf(vB0, wB.w, acc[co][0]))));
                acc[co][1] = fmaf(vA2, wA.x, fmaf(vA1, wA.z, fmaf(vB2, wB.x, fmaf(vB1, wB.z, acc[co][1]))));
                acc[co][2] = fmaf(vA2, wA.y, fmaf(vA1, wA.w, fmaf(vB2, wB.y, fmaf(vB1, wB.w, acc[co][2]))));
                acc[co][3] = fmaf(vA3, wA.x, fmaf(vA2, wA.z, fmaf(vB3, wB.x, fmaf(vB2, wB.z, acc[co][3]))));
            }
        }
    }
    #pragma unroll
    for (int co = 0; co < 8; ++co) {
        float bv = bias[cg * 8 + co];
        float4 v;
        v.x = lrelu(acc[co][0] + bv); v.y = lrelu(acc[co][1] + bv);
        v.z = lrelu(acc[co][2] + bv); v.w = lrelu(acc[co][3] + bv);
        *(float4*)(out + ((size_t)(n * 32 + cg * 8 + co) * 4096) + oy * 64 + 4 * g) = v;
    }
}

// ================= dt2: deconv 32->3, 64x64 -> 128x128, tanh =================
__global__ void __launch_bounds__(256) deconv_dt2_t(
    const float* __restrict__ in, const float* __restrict__ w,
    const float* __restrict__ bias, float* __restrict__ out)
{
    __shared__ float lin[8][6][67];
    __shared__ float lw[8][3][16];
    int b = blockIdx.x;
    int n = b & 63, rt = b >> 6;
    int tid = threadIdx.x;
    int r8 = tid >> 5, g = tid & 31;
    int oy = rt * 8 + r8;
    const float* inp = in + (size_t)n * 32 * 4096;
    int iy0 = rt * 4 - 1;
    int ky0 = (oy + 1) & 1;
    int iyA = ((oy + 1 - ky0) >> 1) - iy0;
    int iyB = iyA - 1;
    int lx = 2 * g;

    float acc[3][4];
    #pragma unroll
    for (int co = 0; co < 3; ++co) { acc[co][0]=acc[co][1]=acc[co][2]=acc[co][3]=0.f; }

    for (int cic = 0; cic < 4; ++cic) {
        __syncthreads();
        for (int i = tid; i < 3168; i += 256) {
            int ci = i / 396, rr = i % 396;
            int y = rr / 66, xx = rr % 66;
            int gy = iy0 + y, gx = xx - 1;
            float v = 0.f;
            if (gy >= 0 && gy < 64 && gx >= 0 && gx < 64)
                v = inp[(cic * 8 + ci) * 4096 + gy * 64 + gx];
            lin[ci][y][xx] = v;
        }
        for (int i = tid; i < 384; i += 256) {
            int ci = i / 48, rr = i % 48;
            int co = rr >> 4, tt = rr & 15;
            lw[ci][co][tt] = w[((cic * 8 + ci) * 3 + co) * 16 + tt];
        }
        __syncthreads();
        #pragma unroll 2
        for (int ci = 0; ci < 8; ++ci) {
            float vA0 = lin[ci][iyA][lx],     vA1 = lin[ci][iyA][lx + 1];
            float vA2 = lin[ci][iyA][lx + 2], vA3 = lin[ci][iyA][lx + 3];
            float vB0 = lin[ci][iyB][lx],     vB1 = lin[ci][iyB][lx + 1];
            float vB2 = lin[ci][iyB][lx + 2], vB3 = lin[ci][iyB][lx + 3];
            #pragma unroll
            for (int co = 0; co < 3; ++co) {
                const float4* wp = (const float4*)lw[ci][co];
                float4 wA = wp[ky0];
                float4 wB = wp[ky0 + 2];
                acc[co][0] = fmaf(vA1, wA.y, fmaf(vA0, wA.w, fmaf(vB1, wB.y, fmaf(vB0, wB.w, acc[co][0]))));
                acc[co][1] = fmaf(vA2, wA.x, fmaf(vA1, wA.z, fmaf(vB2, wB.x, fmaf(vB1, wB.z, acc[co][1]))));
                acc[co][2] = fmaf(vA2, wA.y, fmaf(vA1, wA.w, fmaf(vB2, wB.y, fmaf(vB1, wB.w, acc[co][2]))));
                acc[co][3] = fmaf(vA3, wA.x, fmaf(vA2, wA.z, fmaf(vB3, wB.x, fmaf(vB2, wB.z, acc[co][3]))));
            }
        }
    }
    #pragma unroll
    for (int co = 0; co < 3; ++co) {
        float bv = bias[co];
        float4 v;
        v.x = fast_tanh(acc[co][0] + bv); v.y = fast_tanh(acc[co][1] + bv);
        v.z = fast_tanh(acc[co][2] + bv); v.w = fast_tanh(acc[co][3] + bv);
        *(float4*)(out + ((size_t)(n * 3 + co) * 16384) + oy * 128 + 4 * g) = v;
    }
}

extern "C" void kernel_launch(void* const* d_in, const int* in_sizes, int n_in,
                              void* d_out, int out_size, void* d_ws, size_t ws_size,
                              hipStream_t stream)
{
    const float* x    = (const float*)d_in[0];
    const float* e1w  = (const float*)d_in[1];
    const float* e1b  = (const float*)d_in[2];
    const float* e2w  = (const float*)d_in[3];
    const float* e2b  = (const float*)d_in[4];
    const float* e3w  = (const float*)d_in[5];
    const float* e3b  = (const float*)d_in[6];
    const float* er1w = (const float*)d_in[7];
    const float* er1g = (const float*)d_in[8];
    const float* er1b = (const float*)d_in[9];
    const float* er2w = (const float*)d_in[10];
    const float* er2g = (const float*)d_in[11];
    const float* er2b = (const float*)d_in[12];
    const float* e4w  = (const float*)d_in[13];
    const float* e4b  = (const float*)d_in[14];
    const float* emb  = (const float*)d_in[15];
    const float* d1w  = (const float*)d_in[16];
    const float* d1b  = (const float*)d_in[17];
    const float* dr1w = (const float*)d_in[18];
    const float* dr1g = (const float*)d_in[19];
    const float* dr1b = (const float*)d_in[20];
    const float* dr2w = (const float*)d_in[21];
    const float* dr2g = (const float*)d_in[22];
    const float* dr2b = (const float*)d_in[23];
    const float* dt1w = (const float*)d_in[24];
    const float* dt1b = (const float*)d_in[25];
    const float* dt2w = (const float*)d_in[26];
    const float* dt2b = (const float*)d_in[27];

    float* out = (float*)d_out;
    float* ws  = (float*)d_ws;

    // workspace layout (floats)
    float* B0 = ws;                   // 8,388,608  (64x32x64x64)
    float* B1 = ws + 8388608;         // 4,194,304  (64x64x32x32)
    float* B2 = B1 + 4194304;
    float* B3 = B2 + 4194304;
    float* B4 = B3 + 4194304;
    float* bn_part = B4 + 4194304;    // 1024 floats
    float* bn_fin  = bn_part + 2048;  // 128
    float* vq_part = bn_fin + 128;    // 256
    float* enorm   = vq_part + 256;   // 512
    unsigned long long* bestbuf = (unsigned long long*)(enorm + 512);  // 8*65536 u64 = 4MB

    float* out_recon = out;                 // 3,145,728
    float* out_q     = out + 3145728;       // 4,194,304
    float* out_e     = out + 7340032;       // 4,194,304
    float* out_loss  = out + 11534336;      // 1

    const float invM = 1.f / 65536.f;

    // ---------------- encoder ----------------
    conv_e1_t<<<512, 256, 0, stream>>>(x, e1w, e1b, B0);
    conv_e2_t<<<512, 256, 0, stream>>>(B0, e2w, e2b, B1);
    conv3x3_t<1><<<512, 256, 0, stream>>>(B1, e3w, e3b, B2);

    // encoder resblock
    conv3x3_t<0><<<512, 256, 0, stream>>>(B2, er1w, nullptr, B3);
    bn_stats2_k<<<512, 256, 0, stream>>>(B3, bn_part);
    bn_fin_k<<<1, 64, 0, stream>>>(bn_part, bn_fin, invM);
    bn_apply2_k<0><<<4096, 256, 0, stream>>>(B3, bn_fin, er1g, er1b, nullptr, B1);
    conv1x1_t<0><<<256, 256, 0, stream>>>(B1, er2w, nullptr, B3);
    bn_stats2_k<<<512, 256, 0, stream>>>(B3, bn_part);
    bn_fin_k<<<1, 64, 0, stream>>>(bn_part, bn_fin, invM);
    bn_apply2_k<1><<<4096, 256, 0, stream>>>(B3, bn_fin, er2g, er2b, B2, B1);

    // e4 writes encoded straight to out_e; VQ reads from out_e
    conv1x1_t<1><<<256, 256, 0, stream>>>(B1, e4w, e4b, out_e);
    vq_enorm_k<<<2, 256, 0, stream>>>(emb, enorm);
    vq_dist_k<<<1024, 256, 0, stream>>>(out_e, emb, enorm, bestbuf);
    vq_combine_k<<<256, 256, 0, stream>>>(out_e, emb, bestbuf, out_q, vq_part);
    vq_fin_k<<<1, 256, 0, stream>>>(vq_part, out_loss);

    // ---------------- decoder ----------------
    conv3x3_t<1><<<512, 256, 0, stream>>>(out_q, d1w, d1b, B2);

    conv3x3_t<0><<<512, 256, 0, stream>>>(B2, dr1w, nullptr, B3);
    bn_stats2_k<<<512, 256, 0, stream>>>(B3, bn_part);
    bn_fin_k<<<1, 64, 0, stream>>>(bn_part, bn_fin, invM);
    bn_apply2_k<0><<<4096, 256, 0, stream>>>(B3, bn_fin, dr1g, dr1b, nullptr, B4);
    conv1x1_t<0><<<256, 256, 0, stream>>>(B4, dr2w, nullptr, B3);
    bn_stats2_k<<<512, 256, 0, stream>>>(B3, bn_part);
    bn_fin_k<<<1, 64, 0, stream>>>(bn_part, bn_fin, invM);
    bn_apply2_k<1><<<4096, 256, 0, stream>>>(B3, bn_fin, dr2g, dr2b, B2, B1);

    // deconvs
    deconv_dt1_t<<<1024, 256, 0, stream>>>(B1, dt1w, dt1b, B0);
    deconv_dt2_t<<<1024, 256, 0, stream>>>(B0, dt2w, dt2b, out_recon);
}

// Round 7
// 721.409 us; speedup vs baseline: 7.8915x; 1.0611x over previous
//
#include <hip/hip_runtime.h>
#include <math.h>

#define LREL 0.01f
__device__ __forceinline__ float lrelu(float x) { return x > 0.f ? x : LREL * x; }
__device__ __forceinline__ float fast_tanh(float x) {
    x = fminf(fmaxf(x, -10.f), 10.f);
    float a = __expf(2.f * x);
    return (a - 1.f) / (a + 1.f);
}

// ================= e1: 3->32, 128x128 -> 64x64, 4x4 s2 p1, lrelu =================
__global__ void __launch_bounds__(256) conv_e1_t(
    const float* __restrict__ x, const float* __restrict__ w,
    const float* __restrict__ bias, float* __restrict__ out)
{
    __shared__ float lin[3][66][67];
    __shared__ float lw[3][16][16];
    int b = blockIdx.x;
    int n = b & 63, t = b >> 6;
    int tile = t & 3, cg = t >> 2;
    int ty = tile >> 1, tx = tile & 1;
    int tid = threadIdx.x;
    int r = tid >> 3, g = tid & 7, c0 = g << 2;
    const float* inp = x + (size_t)n * 3 * 16384;

    for (int i = tid; i < 3 * 66 * 66; i += 256) {
        int ci = i / 4356, rr = i % 4356;
        int y = rr / 66, xx = rr % 66;
        int gy = ty * 64 - 1 + y, gx = tx * 64 - 1 + xx;
        float v = 0.f;
        if (gy >= 0 && gy < 128 && gx >= 0 && gx < 128)
            v = inp[ci * 16384 + gy * 128 + gx];
        lin[ci][y][xx] = v;
    }
    for (int i = tid; i < 768; i += 256) {
        int ci = i >> 8, rr = i & 255, co = rr >> 4, tt = rr & 15;
        lw[ci][co][tt] = w[((cg * 16 + co) * 3 + ci) * 16 + tt];
    }
    __syncthreads();

    float acc[16][4];
    #pragma unroll
    for (int co = 0; co < 16; ++co) { acc[co][0]=acc[co][1]=acc[co][2]=acc[co][3]=0.f; }

    #pragma unroll
    for (int ci = 0; ci < 3; ++ci) {
        float win[4][10];
        #pragma unroll
        for (int dy = 0; dy < 4; ++dy)
            #pragma unroll
            for (int dx = 0; dx < 10; ++dx)
                win[dy][dx] = lin[ci][2 * r + dy][8 * g + dx];
        #pragma unroll
        for (int co = 0; co < 16; ++co) {
            #pragma unroll
            for (int ky = 0; ky < 4; ++ky)
                #pragma unroll
                for (int kx = 0; kx < 4; ++kx) {
                    float wv = lw[ci][co][ky * 4 + kx];
                    #pragma unroll
                    for (int j = 0; j < 4; ++j)
                        acc[co][j] = fmaf(win[ky][2 * j + kx], wv, acc[co][j]);
                }
        }
    }
    int oy = ty * 32 + r, ox0 = tx * 32 + c0;
    #pragma unroll
    for (int co = 0; co < 16; ++co) {
        float bv = bias[cg * 16 + co];
        float4 v;
        v.x = lrelu(acc[co][0] + bv); v.y = lrelu(acc[co][1] + bv);
        v.z = lrelu(acc[co][2] + bv); v.w = lrelu(acc[co][3] + bv);
        *(float4*)(out + ((size_t)(n * 32 + cg * 16 + co) * 4096) + oy * 64 + ox0) = v;
    }
}

// ================= e2 NEW: 32->64, 64x64 -> 32x32, all 64 co per block =================
// grid 512: n = b&63, ry = b>>6 (8 tiles of 4 out rows). thread: c = tid&31 (out col), cog = tid>>5.
__global__ void __launch_bounds__(256) conv_e2_t(
    const float* __restrict__ in, const float* __restrict__ w,
    const float* __restrict__ bias, float* __restrict__ out)
{
    __shared__ float lin[8][10][66];   // 21.1 KB: rows 8ry-1..8ry+8, cols -1..64
    __shared__ float lw[8][64][16];    // 32 KB
    int b = blockIdx.x;
    int n = b & 63, ry = b >> 6;
    int tid = threadIdx.x;
    int c = tid & 31, cog = tid >> 5;
    int iy0 = 8 * ry - 1;
    const float* inp = in + (size_t)n * 32 * 4096;

    float acc[8][4];
    #pragma unroll
    for (int q = 0; q < 8; ++q) { acc[q][0]=acc[q][1]=acc[q][2]=acc[q][3]=0.f; }

    for (int cic = 0; cic < 4; ++cic) {
        __syncthreads();
        for (int i = tid; i < 5280; i += 256) {
            int ci = i / 660, rr = i % 660;
            int riy = rr / 66, j = rr % 66;
            int gy = iy0 + riy, gx = j - 1;
            float v = 0.f;
            if (gy >= 0 && gy < 64 && gx >= 0 && gx < 64)
                v = inp[(cic * 8 + ci) * 4096 + gy * 64 + gx];
            lin[ci][riy][j] = v;
        }
        for (int i = tid; i < 8192; i += 256) {
            int ci = i >> 10, rr = i & 1023, co = rr >> 4, tt = rr & 15;
            lw[ci][co][tt] = w[(co * 32 + cic * 8 + ci) * 16 + tt];
        }
        __syncthreads();
        #pragma unroll 2
        for (int ci = 0; ci < 8; ++ci) {
            float win[10][4];
            #pragma unroll
            for (int riy = 0; riy < 10; ++riy)
                #pragma unroll
                for (int q = 0; q < 4; ++q)
                    win[riy][q] = lin[ci][riy][2 * c + q];
            #pragma unroll
            for (int cq = 0; cq < 8; ++cq) {
                const float* wp = lw[ci][cog * 8 + cq];
                #pragma unroll
                for (int r = 0; r < 4; ++r)
                    #pragma unroll
                    for (int ky = 0; ky < 4; ++ky)
                        #pragma unroll
                        for (int kx = 0; kx < 4; ++kx)
                            acc[cq][r] = fmaf(win[2 * r + ky][kx], wp[ky * 4 + kx], acc[cq][r]);
            }
        }
    }
    #pragma unroll
    for (int cq = 0; cq < 8; ++cq) {
        int co = cog * 8 + cq;
        float bv = bias[co];
        #pragma unroll
        for (int r = 0; r < 4; ++r)
            out[((size_t)(n * 64 + co) << 10) + (4 * ry + r) * 32 + c] = lrelu(acc[cq][r] + bv);
    }
}

// ================= conv3x3 p1, 64->64 @ 32x32 (+optional fused BN stats) =================
// grid 512: n = b&63 ; cg = b>>6 (8 groups of 8 co). ACT: 0 none, 1 lrelu.
template<int ACT, int STATS>
__global__ void __launch_bounds__(256) conv3x3_t(
    const float* __restrict__ in, const float* __restrict__ w,
    const float* __restrict__ bias, float* __restrict__ out,
    float* __restrict__ psum, float* __restrict__ pss)
{
    __shared__ float lin[8][34][35];   // stride 35: win bank = 3r+4g -> 2-way (free)
    __shared__ float lw[8][8][9];
    __shared__ float sS[8][4], sQ[8][4];
    int b = blockIdx.x;
    int n = b & 63, cg = b >> 6;
    int tid = threadIdx.x;
    int r = tid >> 3, g = tid & 7, c0 = g << 2;
    int lane = tid & 63, wv_id = tid >> 6;
    const float* inp = in + (size_t)n * 65536;
    const float4* in4 = (const float4*)inp;

    float acc[8][4];
    #pragma unroll
    for (int co = 0; co < 8; ++co) { acc[co][0]=acc[co][1]=acc[co][2]=acc[co][3]=0.f; }

    for (int i = tid; i < 8 * 34 * 35; i += 256) ((float*)lin)[i] = 0.f;

    for (int cic = 0; cic < 8; ++cic) {
        __syncthreads();
        for (int i = tid; i < 2048; i += 256) {
            int ci = i >> 8, p = i & 255;
            int row = p >> 3, qq = p & 7;
            float4 v = in4[(cic * 8 + ci) * 256 + p];
            float* dst = &lin[ci][row + 1][1 + 4 * qq];
            dst[0] = v.x; dst[1] = v.y; dst[2] = v.z; dst[3] = v.w;
        }
        for (int i = tid; i < 576; i += 256) {
            int ci = i / 72, rr = i % 72;
            int co = rr / 9, tt = rr % 9;
            lw[ci][co][tt] = w[((cg * 8 + co) * 64 + cic * 8 + ci) * 9 + tt];
        }
        __syncthreads();
        #pragma unroll 2
        for (int ci = 0; ci < 8; ++ci) {
            float win[3][6];
            #pragma unroll
            for (int dy = 0; dy < 3; ++dy)
                #pragma unroll
                for (int dx = 0; dx < 6; ++dx)
                    win[dy][dx] = lin[ci][r + dy][c0 + dx];
            #pragma unroll
            for (int co = 0; co < 8; ++co) {
                #pragma unroll
                for (int dy = 0; dy < 3; ++dy)
                    #pragma unroll
                    for (int dx = 0; dx < 3; ++dx) {
                        float wvv = lw[ci][co][dy * 3 + dx];
                        #pragma unroll
                        for (int j = 0; j < 4; ++j)
                            acc[co][j] = fmaf(win[dy][j + dx], wvv, acc[co][j]);
                    }
            }
        }
    }
    size_t ob = ((size_t)(n * 64 + cg * 8) << 10) + (r << 5) + c0;
    #pragma unroll
    for (int co = 0; co < 8; ++co) {
        float bv = bias ? bias[cg * 8 + co] : 0.f;
        float a0 = acc[co][0] + bv, a1 = acc[co][1] + bv, a2 = acc[co][2] + bv, a3 = acc[co][3] + bv;
        if (ACT == 1) { a0 = lrelu(a0); a1 = lrelu(a1); a2 = lrelu(a2); a3 = lrelu(a3); }
        float4 v; v.x = a0; v.y = a1; v.z = a2; v.w = a3;
        *(float4*)(out + ob + ((size_t)co << 10)) = v;
        if (STATS) {
            float s = a0 + a1 + a2 + a3;
            float q = a0*a0 + a1*a1 + a2*a2 + a3*a3;
            #pragma unroll
            for (int m = 1; m < 64; m <<= 1) {
                s += __shfl_xor(s, m);
                q += __shfl_xor(q, m);
            }
            if (lane == 0) { sS[co][wv_id] = s; sQ[co][wv_id] = q; }
        }
    }
    if (STATS) {
        __syncthreads();
        if (tid < 8) {
            float s = sS[tid][0] + sS[tid][1] + sS[tid][2] + sS[tid][3];
            float q = sQ[tid][0] + sQ[tid][1] + sQ[tid][2] + sQ[tid][3];
            psum[(cg * 8 + tid) * 64 + n] = s;
            pss [(cg * 8 + tid) * 64 + n] = q;
        }
    }
}

// ================= conv1x1 64->64 @ 32x32, fused BN input / stats =================
// grid 512: n = b&63 ; cg = b>>6 (8 groups of 8 co).
// IN: 0 plain, 1 relu(bn(x)), 2 lrelu(res + bn(x)). ACT: 0 none, 1 lrelu.
template<int IN, int ACT, int STATS>
__global__ void __launch_bounds__(256) conv1x1_t(
    const float* __restrict__ in, const float* __restrict__ res,
    const float* __restrict__ w, const float* __restrict__ bias,
    const float* __restrict__ fin, const float* __restrict__ g,
    const float* __restrict__ beta, float* __restrict__ out,
    float* __restrict__ psum, float* __restrict__ pss)
{
    __shared__ float lw[64][8];
    __shared__ float sga[64], sbb[64];
    __shared__ float sS[8][4], sQ[8][4];
    int b = blockIdx.x;
    int n = b & 63, cg = b >> 6;
    int tid = threadIdx.x;
    int lane = tid & 63, wv_id = tid >> 6;
    for (int i = tid; i < 512; i += 256) {
        int ci = i >> 3, co = i & 7;
        lw[ci][co] = w[(cg * 8 + co) * 64 + ci];
    }
    if (IN >= 1 && tid < 64) {
        float ga = g[tid] * fin[2 * tid + 1];
        sga[tid] = ga;
        sbb[tid] = beta[tid] - fin[2 * tid] * ga;
    }
    __syncthreads();
    const float4* in4 = (const float4*)(in + (size_t)n * 65536);
    const float4* res4 = (IN == 2) ? (const float4*)(res + (size_t)n * 65536) : nullptr;
    float acc[8][4];
    #pragma unroll
    for (int co = 0; co < 8; ++co) { acc[co][0]=acc[co][1]=acc[co][2]=acc[co][3]=0.f; }
    #pragma unroll 4
    for (int ci = 0; ci < 64; ++ci) {
        float4 xv = in4[(ci << 8) + tid];
        float x0, x1, x2, x3;
        if (IN == 1) {
            float ga = sga[ci], bb = sbb[ci];
            x0 = fmaxf(fmaf(xv.x, ga, bb), 0.f);
            x1 = fmaxf(fmaf(xv.y, ga, bb), 0.f);
            x2 = fmaxf(fmaf(xv.z, ga, bb), 0.f);
            x3 = fmaxf(fmaf(xv.w, ga, bb), 0.f);
        } else if (IN == 2) {
            float4 rv = res4[(ci << 8) + tid];
            float ga = sga[ci], bb = sbb[ci];
            x0 = lrelu(rv.x + fmaf(xv.x, ga, bb));
            x1 = lrelu(rv.y + fmaf(xv.y, ga, bb));
            x2 = lrelu(rv.z + fmaf(xv.z, ga, bb));
            x3 = lrelu(rv.w + fmaf(xv.w, ga, bb));
        } else {
            x0 = xv.x; x1 = xv.y; x2 = xv.z; x3 = xv.w;
        }
        #pragma unroll
        for (int co = 0; co < 8; ++co) {
            float wvv = lw[ci][co];
            acc[co][0] = fmaf(x0, wvv, acc[co][0]);
            acc[co][1] = fmaf(x1, wvv, acc[co][1]);
            acc[co][2] = fmaf(x2, wvv, acc[co][2]);
            acc[co][3] = fmaf(x3, wvv, acc[co][3]);
        }
    }
    #pragma unroll
    for (int co = 0; co < 8; ++co) {
        float bv = bias ? bias[cg * 8 + co] : 0.f;
        float a0 = acc[co][0] + bv, a1 = acc[co][1] + bv, a2 = acc[co][2] + bv, a3 = acc[co][3] + bv;
        if (ACT == 1) { a0 = lrelu(a0); a1 = lrelu(a1); a2 = lrelu(a2); a3 = lrelu(a3); }
        float4 v; v.x = a0; v.y = a1; v.z = a2; v.w = a3;
        ((float4*)(out + (size_t)n * 65536 + (size_t)(cg * 8 + co) * 1024))[tid] = v;
        if (STATS) {
            float s = a0 + a1 + a2 + a3;
            float q = a0*a0 + a1*a1 + a2*a2 + a3*a3;
            #pragma unroll
            for (int m = 1; m < 64; m <<= 1) {
                s += __shfl_xor(s, m);
                q += __shfl_xor(q, m);
            }
            if (lane == 0) { sS[co][wv_id] = s; sQ[co][wv_id] = q; }
        }
    }
    if (STATS) {
        __syncthreads();
        if (tid < 8) {
            float s = sS[tid][0] + sS[tid][1] + sS[tid][2] + sS[tid][3];
            float q = sQ[tid][0] + sQ[tid][1] + sQ[tid][2] + sQ[tid][3];
            psum[(cg * 8 + tid) * 64 + n] = s;
            pss [(cg * 8 + tid) * 64 + n] = q;
        }
    }
}

// ================= BN finalize from per-(c,n) partials =================
__global__ void bn_fin2_k(const float* __restrict__ psum, const float* __restrict__ pss,
                          float* __restrict__ fin, float invM)
{
    int c = threadIdx.x;
    if (c >= 64) return;
    float s = 0.f, q = 0.f;
    for (int n = 0; n < 64; ++n) { s += psum[c * 64 + n]; q += pss[c * 64 + n]; }
    float mean = s * invM;
    float var  = q * invM - mean * mean;
    fin[2 * c] = mean;
    fin[2 * c + 1] = rsqrtf(var + 1e-5f);
}

// ================= VQ =================
__global__ void __launch_bounds__(256) vq_enorm_k(const float* __restrict__ emb, float* __restrict__ enorm)
{
    int k = blockIdx.x * 256 + threadIdx.x;
    if (k >= 512) return;
    const float4* e4 = (const float4*)(emb + (k << 6));
    float s = 0.f;
    #pragma unroll
    for (int j = 0; j < 16; ++j) {
        float4 e = e4[j];
        s = fmaf(e.x, e.x, s); s = fmaf(e.y, e.y, s);
        s = fmaf(e.z, e.z, s); s = fmaf(e.w, e.w, s);
    }
    enorm[k] = s;
}

__device__ __forceinline__ unsigned order_u32(float s) {
    unsigned u = __float_as_uint(s);
    return (s < 0.f) ? ~u : (u | 0x80000000u);
}

__global__ void __launch_bounds__(256) vq_dist_k(
    const float* __restrict__ z, const float* __restrict__ emb,
    const float* __restrict__ enorm, unsigned long long* __restrict__ best)
{
    __shared__ float se[64][64];
    __shared__ float sn[64];
    int b = blockIdx.x;
    int kb = b & 7, pg = b >> 3;
    int tid = threadIdx.x;
    for (int i = tid; i < 4096; i += 256)
        ((float*)se)[i] = emb[(kb << 12) + i];
    if (tid < 64) sn[tid] = enorm[(kb << 6) + tid];
    __syncthreads();

    int n = pg >> 1;
    int p0 = ((pg & 1) << 9) + tid;
    size_t base0 = (size_t)n * 65536 + p0;
    float z0[64], z1[64];
    #pragma unroll
    for (int d = 0; d < 64; ++d) z0[d] = z[base0 + (size_t)d * 1024];
    #pragma unroll
    for (int d = 0; d < 64; ++d) z1[d] = z[base0 + 256 + (size_t)d * 1024];

    unsigned long long b0 = ~0ULL, b1 = ~0ULL;
    for (int k = 0; k < 64; ++k) {
        const float4* e4 = (const float4*)se[k];
        float dot0 = 0.f, dot1 = 0.f;
        #pragma unroll
        for (int j = 0; j < 16; ++j) {
            float4 e = e4[j];
            dot0 = fmaf(z0[4*j],   e.x, dot0);
            dot0 = fmaf(z0[4*j+1], e.y, dot0);
            dot0 = fmaf(z0[4*j+2], e.z, dot0);
            dot0 = fmaf(z0[4*j+3], e.w, dot0);
            dot1 = fmaf(z1[4*j],   e.x, dot1);
            dot1 = fmaf(z1[4*j+1], e.y, dot1);
            dot1 = fmaf(z1[4*j+2], e.z, dot1);
            dot1 = fmaf(z1[4*j+3], e.w, dot1);
        }
        float s0 = fmaf(-2.f, dot0, sn[k]);
        float s1 = fmaf(-2.f, dot1, sn[k]);
        unsigned kk = (unsigned)((kb << 6) + k);
        unsigned long long p0k = ((unsigned long long)order_u32(s0) << 32) | kk;
        unsigned long long p1k = ((unsigned long long)order_u32(s1) << 32) | kk;
        b0 = p0k < b0 ? p0k : b0;
        b1 = p1k < b1 ? p1k : b1;
    }
    size_t m0 = ((size_t)pg << 9) + tid;
    best[((size_t)kb << 16) + m0]       = b0;
    best[((size_t)kb << 16) + m0 + 256] = b1;
}

__global__ void __launch_bounds__(256) vq_combine_k(
    const float* __restrict__ z, const float* __restrict__ emb,
    const unsigned long long* __restrict__ best,
    float* __restrict__ out_q, float* __restrict__ partials)
{
    int m = blockIdx.x * 256 + threadIdx.x;
    unsigned long long bb = best[m];
    #pragma unroll
    for (int kb = 1; kb < 8; ++kb) {
        unsigned long long v = best[((size_t)kb << 16) + m];
        bb = v < bb ? v : bb;
    }
    int bi = (int)(bb & 0x1ffu);
    int n = m >> 10, p = m & 1023;
    size_t base = (size_t)n * 65536 + p;
    const float* eb = emb + (bi << 6);
    float lsum = 0.f;
    #pragma unroll
    for (int d = 0; d < 64; ++d) {
        float zz = z[base + (size_t)d * 1024];
        float q = eb[d];
        out_q[base + (size_t)d * 1024] = q;
        float df = q - zz;
        lsum = fmaf(df, df, lsum);
    }
    __shared__ float sh[256];
    sh[threadIdx.x] = lsum;
    __syncthreads();
    for (int st = 128; st > 0; st >>= 1) {
        if (threadIdx.x < st) sh[threadIdx.x] += sh[threadIdx.x + st];
        __syncthreads();
    }
    if (threadIdx.x == 0) partials[blockIdx.x] = sh[0];
}

__global__ void vq_fin_k(const float* __restrict__ partials, float* __restrict__ out)
{
    __shared__ float sh[256];
    sh[threadIdx.x] = partials[threadIdx.x];
    __syncthreads();
    for (int st = 128; st > 0; st >>= 1) {
        if (threadIdx.x < st) sh[threadIdx.x] += sh[threadIdx.x + st];
        __syncthreads();
    }
    if (threadIdx.x == 0) out[0] = sh[0] * (0.25f / (65536.f * 64.f));
}

// ================= dt1: deconv 64->32, 32x32 -> 64x64, lrelu; fused BN-res input =================
// input element = lrelu(res + ga*x + bb)
__global__ void __launch_bounds__(256) deconv_dt1_t(
    const float* __restrict__ xin, const float* __restrict__ resin,
    const float* __restrict__ fin, const float* __restrict__ g,
    const float* __restrict__ beta,
    const float* __restrict__ w, const float* __restrict__ bias,
    float* __restrict__ out)
{
    __shared__ float lin[8][10][37];
    __shared__ float lw[8][8][16];
    __shared__ float sga[64], sbb[64];
    int b = blockIdx.x;
    int n = b & 63, rt = (b >> 6) & 3, cg = b >> 8;
    int tid = threadIdx.x;
    int r16 = tid >> 4, gg = tid & 15;
    int oy = rt * 16 + r16;
    const float* xn = xin + (size_t)n * 65536;
    const float* rn = resin + (size_t)n * 65536;
    int iy0 = rt * 8 - 1;
    int ky0 = (oy + 1) & 1;
    int iyA = ((oy + 1 - ky0) >> 1) - iy0;
    int iyB = iyA - 1;
    int lx = 2 * gg;

    if (tid < 64) {
        float ga = g[tid] * fin[2 * tid + 1];
        sga[tid] = ga;
        sbb[tid] = beta[tid] - fin[2 * tid] * ga;
    }

    float acc[8][4];
    #pragma unroll
    for (int co = 0; co < 8; ++co) { acc[co][0]=acc[co][1]=acc[co][2]=acc[co][3]=0.f; }

    for (int cic = 0; cic < 8; ++cic) {
        __syncthreads();
        for (int i = tid; i < 2720; i += 256) {
            int ci = i / 340, rr = i % 340;
            int y = rr / 34, xx = rr % 34;
            int gy = iy0 + y, gx = xx - 1;
            float v = 0.f;
            if (gy >= 0 && gy < 32 && gx >= 0 && gx < 32) {
                int gi = (cic * 8 + ci) * 1024 + gy * 32 + gx;
                v = lrelu(rn[gi] + fmaf(xn[gi], sga[cic * 8 + ci], sbb[cic * 8 + ci]));
            }
            lin[ci][y][xx] = v;
        }
        for (int i = tid; i < 1024; i += 256) {
            int ci = i >> 7, rr = i & 127, co = rr >> 4, tt = rr & 15;
            lw[ci][co][tt] = w[((cic * 8 + ci) * 32 + cg * 8 + co) * 16 + tt];
        }
        __syncthreads();
        #pragma unroll 2
        for (int ci = 0; ci < 8; ++ci) {
            float vA0 = lin[ci][iyA][lx],     vA1 = lin[ci][iyA][lx + 1];
            float vA2 = lin[ci][iyA][lx + 2], vA3 = lin[ci][iyA][lx + 3];
            float vB0 = lin[ci][iyB][lx],     vB1 = lin[ci][iyB][lx + 1];
            float vB2 = lin[ci][iyB][lx + 2], vB3 = lin[ci][iyB][lx + 3];
            #pragma unroll
            for (int co = 0; co < 8; ++co) {
                const float4* wp = (const float4*)lw[ci][co];
                float4 wA = wp[ky0];
                float4 wB = wp[ky0 + 2];
                acc[co][0] = fmaf(vA1, wA.y, fmaf(vA0, wA.w, fmaf(vB1, wB.y, fmaf(vB0, wB.w, acc[co][0]))));
                acc[co][1] = fmaf(vA2, wA.x, fmaf(vA1, wA.z, fmaf(vB2, wB.x, fmaf(vB1, wB.z, acc[co][1]))));
                acc[co][2] = fmaf(vA2, wA.y, fmaf(vA1, wA.w, fmaf(vB2, wB.y, fmaf(vB1, wB.w, acc[co][2]))));
                acc[co][3] = fmaf(vA3, wA.x, fmaf(vA2, wA.z, fmaf(vB3, wB.x, fmaf(vB2, wB.z, acc[co][3]))));
            }
        }
    }
    #pragma unroll
    for (int co = 0; co < 8; ++co) {
        float bv = bias[cg * 8 + co];
        float4 v;
        v.x = lrelu(acc[co][0] + bv); v.y = lrelu(acc[co][1] + bv);
        v.z = lrelu(acc[co][2] + bv); v.w = lrelu(acc[co][3] + bv);
        *(float4*)(out + ((size_t)(n * 32 + cg * 8 + co) * 4096) + oy * 64 + 4 * gg) = v;
    }
}

// ================= dt2: deconv 32->3, 64x64 -> 128x128, tanh =================
__global__ void __launch_bounds__(256) deconv_dt2_t(
    const float* __restrict__ in, const float* __restrict__ w,
    const float* __restrict__ bias, float* __restrict__ out)
{
    __shared__ float lin[8][6][67];
    __shared__ float lw[8][3][16];
    int b = blockIdx.x;
    int n = b & 63, rt = b >> 6;
    int tid = threadIdx.x;
    int r8 = tid >> 5, gg = tid & 31;
    int oy = rt * 8 + r8;
    const float* inp = in + (size_t)n * 32 * 4096;
    int iy0 = rt * 4 - 1;
    int ky0 = (oy + 1) & 1;
    int iyA = ((oy + 1 - ky0) >> 1) - iy0;
    int iyB = iyA - 1;
    int lx = 2 * gg;

    float acc[3][4];
    #pragma unroll
    for (int co = 0; co < 3; ++co) { acc[co][0]=acc[co][1]=acc[co][2]=acc[co][3]=0.f; }

    for (int cic = 0; cic < 4; ++cic) {
        __syncthreads();
        for (int i = tid; i < 3168; i += 256) {
            int ci = i / 396, rr = i % 396;
            int y = rr / 66, xx = rr % 66;
            int gy = iy0 + y, gx = xx - 1;
            float v = 0.f;
            if (gy >= 0 && gy < 64 && gx >= 0 && gx < 64)
                v = inp[(cic * 8 + ci) * 4096 + gy * 64 + gx];
            lin[ci][y][xx] = v;
        }
        for (int i = tid; i < 384; i += 256) {
            int ci = i / 48, rr = i % 48;
            int co = rr >> 4, tt = rr & 15;
            lw[ci][co][tt] = w[((cic * 8 + ci) * 3 + co) * 16 + tt];
        }
        __syncthreads();
        #pragma unroll 2
        for (int ci = 0; ci < 8; ++ci) {
            float vA0 = lin[ci][iyA][lx],     vA1 = lin[ci][iyA][lx + 1];
            float vA2 = lin[ci][iyA][lx + 2], vA3 = lin[ci][iyA][lx + 3];
            float vB0 = lin[ci][iyB][lx],     vB1 = lin[ci][iyB][lx + 1];
            float vB2 = lin[ci][iyB][lx + 2], vB3 = lin[ci][iyB][lx + 3];
            #pragma unroll
            for (int co = 0; co < 3; ++co) {
                const float4* wp = (const float4*)lw[ci][co];
                float4 wA = wp[ky0];
                float4 wB = wp[ky0 + 2];
                acc[co][0] = fmaf(vA1, wA.y, fmaf(vA0, wA.w, fmaf(vB1, wB.y, fmaf(vB0, wB.w, acc[co][0]))));
                acc[co][1] = fmaf(vA2, wA.x, fmaf(vA1, wA.z, fmaf(vB2, wB.x, fmaf(vB1, wB.z, acc[co][1]))));
                acc[co][2] = fmaf(vA2, wA.y, fmaf(vA1, wA.w, fmaf(vB2, wB.y, fmaf(vB1, wB.w, acc[co][2]))));
                acc[co][3] = fmaf(vA3, wA.x, fmaf(vA2, wA.z, fmaf(vB3, wB.x, fmaf(vB2, wB.z, acc[co][3]))));
            }
        }
    }
    #pragma unroll
    for (int co = 0; co < 3; ++co) {
        float bv = bias[co];
        float4 v;
        v.x = fast_tanh(acc[co][0] + bv); v.y = fast_tanh(acc[co][1] + bv);
        v.z = fast_tanh(acc[co][2] + bv); v.w = fast_tanh(acc[co][3] + bv);
        *(float4*)(out + ((size_t)(n * 3 + co) * 16384) + oy * 128 + 4 * gg) = v;
    }
}

extern "C" void kernel_launch(void* const* d_in, const int* in_sizes, int n_in,
                              void* d_out, int out_size, void* d_ws, size_t ws_size,
                              hipStream_t stream)
{
    const float* x    = (const float*)d_in[0];
    const float* e1w  = (const float*)d_in[1];
    const float* e1b  = (const float*)d_in[2];
    const float* e2w  = (const float*)d_in[3];
    const float* e2b  = (const float*)d_in[4];
    const float* e3w  = (const float*)d_in[5];
    const float* e3b  = (const float*)d_in[6];
    const float* er1w = (const float*)d_in[7];
    const float* er1g = (const float*)d_in[8];
    const float* er1b = (const float*)d_in[9];
    const float* er2w = (const float*)d_in[10];
    const float* er2g = (const float*)d_in[11];
    const float* er2b = (const float*)d_in[12];
    const float* e4w  = (const float*)d_in[13];
    const float* e4b  = (const float*)d_in[14];
    const float* emb  = (const float*)d_in[15];
    const float* d1w  = (const float*)d_in[16];
    const float* d1b  = (const float*)d_in[17];
    const float* dr1w = (const float*)d_in[18];
    const float* dr1g = (const float*)d_in[19];
    const float* dr1b = (const float*)d_in[20];
    const float* dr2w = (const float*)d_in[21];
    const float* dr2g = (const float*)d_in[22];
    const float* dr2b = (const float*)d_in[23];
    const float* dt1w = (const float*)d_in[24];
    const float* dt1b = (const float*)d_in[25];
    const float* dt2w = (const float*)d_in[26];
    const float* dt2b = (const float*)d_in[27];

    float* out = (float*)d_out;
    float* ws  = (float*)d_ws;

    // workspace layout (floats)
    float* B0 = ws;                   // 8,388,608  (64x32x64x64)
    float* B1 = ws + 8388608;         // 4,194,304  (64x64x32x32)
    float* B2 = B1 + 4194304;
    float* B3 = B2 + 4194304;
    float* B4 = B3 + 4194304;
    float* psum   = B4 + 4194304;     // 4096
    float* pss    = psum + 4096;      // 4096
    float* fin    = pss + 4096;       // 128
    float* vq_part = fin + 128;       // 256
    float* enorm   = vq_part + 256;   // 512
    unsigned long long* bestbuf = (unsigned long long*)(enorm + 512);  // 8*65536 u64 = 4MB

    float* out_recon = out;                 // 3,145,728
    float* out_q     = out + 3145728;       // 4,194,304
    float* out_e     = out + 7340032;       // 4,194,304
    float* out_loss  = out + 11534336;      // 1

    const float invM = 1.f / 65536.f;

    // ---------------- encoder ----------------
    conv_e1_t<<<512, 256, 0, stream>>>(x, e1w, e1b, B0);
    conv_e2_t<<<512, 256, 0, stream>>>(B0, e2w, e2b, B1);
    conv3x3_t<1,0><<<512, 256, 0, stream>>>(B1, e3w, e3b, B2, nullptr, nullptr);

    // encoder resblock (stats fused into convs, BN-apply fused into consumers)
    conv3x3_t<0,1><<<512, 256, 0, stream>>>(B2, er1w, nullptr, B3, psum, pss);
    bn_fin2_k<<<1, 64, 0, stream>>>(psum, pss, fin, invM);
    conv1x1_t<1,0,1><<<512, 256, 0, stream>>>(B3, nullptr, er2w, nullptr, fin, er1g, er1b, B4, psum, pss);
    bn_fin2_k<<<1, 64, 0, stream>>>(psum, pss, fin, invM);
    // e4: input = lrelu(res(B2) + bn(B4)); output lrelu -> out_e
    conv1x1_t<2,1,0><<<512, 256, 0, stream>>>(B4, B2, e4w, e4b, fin, er2g, er2b, out_e, nullptr, nullptr);

    // VQ
    vq_enorm_k<<<2, 256, 0, stream>>>(emb, enorm);
    vq_dist_k<<<1024, 256, 0, stream>>>(out_e, emb, enorm, bestbuf);
    vq_combine_k<<<256, 256, 0, stream>>>(out_e, emb, bestbuf, out_q, vq_part);
    vq_fin_k<<<1, 256, 0, stream>>>(vq_part, out_loss);

    // ---------------- decoder ----------------
    conv3x3_t<1,0><<<512, 256, 0, stream>>>(out_q, d1w, d1b, B2, nullptr, nullptr);

    conv3x3_t<0,1><<<512, 256, 0, stream>>>(B2, dr1w, nullptr, B3, psum, pss);
    bn_fin2_k<<<1, 64, 0, stream>>>(psum, pss, fin, invM);
    conv1x1_t<1,0,1><<<512, 256, 0, stream>>>(B3, nullptr, dr2w, nullptr, fin, dr1g, dr1b, B4, psum, pss);
    bn_fin2_k<<<1, 64, 0, stream>>>(psum, pss, fin, invM);

    // dt1: input = lrelu(res(B2) + bn(B4))
    deconv_dt1_t<<<1024, 256, 0, stream>>>(B4, B2, fin, dr2g, dr2b, dt1w, dt1b, B0);
    deconv_dt2_t<<<1024, 256, 0, stream>>>(B0, dt2w, dt2b, out_recon);
}

// Round 8
// 652.700 us; speedup vs baseline: 8.7222x; 1.1053x over previous
//
#include <hip/hip_runtime.h>
#include <math.h>

#define LREL 0.01f
__device__ __forceinline__ float lrelu(float x) { return x > 0.f ? x : LREL * x; }
__device__ __forceinline__ float fast_tanh(float x) {
    x = fminf(fmaxf(x, -10.f), 10.f);
    float a = __expf(2.f * x);
    return (a - 1.f) / (a + 1.f);
}
__device__ __forceinline__ unsigned short f2bf(float f) {
    unsigned u = __float_as_uint(f);
    unsigned r = u + 0x7FFFu + ((u >> 16) & 1u);
    return (unsigned short)(r >> 16);
}

typedef __attribute__((ext_vector_type(8))) short short8;
typedef __attribute__((ext_vector_type(4))) float f32x4;

// ================= e1: 3->32, 128x128 -> 64x64, 4x4 s2 p1, lrelu (fp32) =================
__global__ void __launch_bounds__(256) conv_e1_t(
    const float* __restrict__ x, const float* __restrict__ w,
    const float* __restrict__ bias, float* __restrict__ out)
{
    __shared__ float lin[3][66][67];
    __shared__ float lw[3][16][16];
    int b = blockIdx.x;
    int n = b & 63, t = b >> 6;
    int tile = t & 3, cg = t >> 2;
    int ty = tile >> 1, tx = tile & 1;
    int tid = threadIdx.x;
    int r = tid >> 3, g = tid & 7, c0 = g << 2;
    const float* inp = x + (size_t)n * 3 * 16384;

    for (int i = tid; i < 3 * 66 * 66; i += 256) {
        int ci = i / 4356, rr = i % 4356;
        int y = rr / 66, xx = rr % 66;
        int gy = ty * 64 - 1 + y, gx = tx * 64 - 1 + xx;
        float v = 0.f;
        if (gy >= 0 && gy < 128 && gx >= 0 && gx < 128)
            v = inp[ci * 16384 + gy * 128 + gx];
        lin[ci][y][xx] = v;
    }
    for (int i = tid; i < 768; i += 256) {
        int ci = i >> 8, rr = i & 255, co = rr >> 4, tt = rr & 15;
        lw[ci][co][tt] = w[((cg * 16 + co) * 3 + ci) * 16 + tt];
    }
    __syncthreads();

    float acc[16][4];
    #pragma unroll
    for (int co = 0; co < 16; ++co) { acc[co][0]=acc[co][1]=acc[co][2]=acc[co][3]=0.f; }

    #pragma unroll
    for (int ci = 0; ci < 3; ++ci) {
        float win[4][10];
        #pragma unroll
        for (int dy = 0; dy < 4; ++dy)
            #pragma unroll
            for (int dx = 0; dx < 10; ++dx)
                win[dy][dx] = lin[ci][2 * r + dy][8 * g + dx];
        #pragma unroll
        for (int co = 0; co < 16; ++co) {
            #pragma unroll
            for (int ky = 0; ky < 4; ++ky)
                #pragma unroll
                for (int kx = 0; kx < 4; ++kx) {
                    float wv = lw[ci][co][ky * 4 + kx];
                    #pragma unroll
                    for (int j = 0; j < 4; ++j)
                        acc[co][j] = fmaf(win[ky][2 * j + kx], wv, acc[co][j]);
                }
        }
    }
    int oy = ty * 32 + r, ox0 = tx * 32 + c0;
    #pragma unroll
    for (int co = 0; co < 16; ++co) {
        float bv = bias[cg * 16 + co];
        float4 v;
        v.x = lrelu(acc[co][0] + bv); v.y = lrelu(acc[co][1] + bv);
        v.z = lrelu(acc[co][2] + bv); v.w = lrelu(acc[co][3] + bv);
        *(float4*)(out + ((size_t)(n * 32 + cg * 16 + co) * 4096) + oy * 64 + ox0) = v;
    }
}

// ================= e2: 32->64, 64x64 -> 32x32 (fp32) =================
__global__ void __launch_bounds__(256) conv_e2_t(
    const float* __restrict__ in, const float* __restrict__ w,
    const float* __restrict__ bias, float* __restrict__ out)
{
    __shared__ float lin[8][10][66];
    __shared__ float lw[8][64][16];
    int b = blockIdx.x;
    int n = b & 63, ry = b >> 6;
    int tid = threadIdx.x;
    int c = tid & 31, cog = tid >> 5;
    int iy0 = 8 * ry - 1;
    const float* inp = in + (size_t)n * 32 * 4096;

    float acc[8][4];
    #pragma unroll
    for (int q = 0; q < 8; ++q) { acc[q][0]=acc[q][1]=acc[q][2]=acc[q][3]=0.f; }

    for (int cic = 0; cic < 4; ++cic) {
        __syncthreads();
        for (int i = tid; i < 5280; i += 256) {
            int ci = i / 660, rr = i % 660;
            int riy = rr / 66, j = rr % 66;
            int gy = iy0 + riy, gx = j - 1;
            float v = 0.f;
            if (gy >= 0 && gy < 64 && gx >= 0 && gx < 64)
                v = inp[(cic * 8 + ci) * 4096 + gy * 64 + gx];
            lin[ci][riy][j] = v;
        }
        for (int i = tid; i < 8192; i += 256) {
            int ci = i >> 10, rr = i & 1023, co = rr >> 4, tt = rr & 15;
            lw[ci][co][tt] = w[(co * 32 + cic * 8 + ci) * 16 + tt];
        }
        __syncthreads();
        #pragma unroll 2
        for (int ci = 0; ci < 8; ++ci) {
            float win[10][4];
            #pragma unroll
            for (int riy = 0; riy < 10; ++riy)
                #pragma unroll
                for (int q = 0; q < 4; ++q)
                    win[riy][q] = lin[ci][riy][2 * c + q];
            #pragma unroll
            for (int cq = 0; cq < 8; ++cq) {
                const float* wp = lw[ci][cog * 8 + cq];
                #pragma unroll
                for (int r = 0; r < 4; ++r)
                    #pragma unroll
                    for (int ky = 0; ky < 4; ++ky)
                        #pragma unroll
                        for (int kx = 0; kx < 4; ++kx)
                            acc[cq][r] = fmaf(win[2 * r + ky][kx], wp[ky * 4 + kx], acc[cq][r]);
            }
        }
    }
    #pragma unroll
    for (int cq = 0; cq < 8; ++cq) {
        int co = cog * 8 + cq;
        float bv = bias[co];
        #pragma unroll
        for (int r = 0; r < 4; ++r)
            out[((size_t)(n * 64 + co) << 10) + (4 * ry + r) * 32 + c] = lrelu(acc[cq][r] + bv);
    }
}

// ================= conv3x3 fp32 (encoder), optional fused BN stats =================
template<int ACT, int STATS>
__global__ void __launch_bounds__(256) conv3x3_t(
    const float* __restrict__ in, const float* __restrict__ w,
    const float* __restrict__ bias, float* __restrict__ out,
    float* __restrict__ psum, float* __restrict__ pss)
{
    __shared__ float lin[8][34][35];
    __shared__ float lw[8][8][9];
    __shared__ float sS[8][4], sQ[8][4];
    int b = blockIdx.x;
    int n = b & 63, cg = b >> 6;
    int tid = threadIdx.x;
    int r = tid >> 3, g = tid & 7, c0 = g << 2;
    int lane = tid & 63, wv_id = tid >> 6;
    const float* inp = in + (size_t)n * 65536;
    const float4* in4 = (const float4*)inp;

    float acc[8][4];
    #pragma unroll
    for (int co = 0; co < 8; ++co) { acc[co][0]=acc[co][1]=acc[co][2]=acc[co][3]=0.f; }

    for (int i = tid; i < 8 * 34 * 35; i += 256) ((float*)lin)[i] = 0.f;

    for (int cic = 0; cic < 8; ++cic) {
        __syncthreads();
        for (int i = tid; i < 2048; i += 256) {
            int ci = i >> 8, p = i & 255;
            int row = p >> 3, qq = p & 7;
            float4 v = in4[(cic * 8 + ci) * 256 + p];
            float* dst = &lin[ci][row + 1][1 + 4 * qq];
            dst[0] = v.x; dst[1] = v.y; dst[2] = v.z; dst[3] = v.w;
        }
        for (int i = tid; i < 576; i += 256) {
            int ci = i / 72, rr = i % 72;
            int co = rr / 9, tt = rr % 9;
            lw[ci][co][tt] = w[((cg * 8 + co) * 64 + cic * 8 + ci) * 9 + tt];
        }
        __syncthreads();
        #pragma unroll 2
        for (int ci = 0; ci < 8; ++ci) {
            float win[3][6];
            #pragma unroll
            for (int dy = 0; dy < 3; ++dy)
                #pragma unroll
                for (int dx = 0; dx < 6; ++dx)
                    win[dy][dx] = lin[ci][r + dy][c0 + dx];
            #pragma unroll
            for (int co = 0; co < 8; ++co) {
                #pragma unroll
                for (int dy = 0; dy < 3; ++dy)
                    #pragma unroll
                    for (int dx = 0; dx < 3; ++dx) {
                        float wvv = lw[ci][co][dy * 3 + dx];
                        #pragma unroll
                        for (int j = 0; j < 4; ++j)
                            acc[co][j] = fmaf(win[dy][j + dx], wvv, acc[co][j]);
                    }
            }
        }
    }
    size_t ob = ((size_t)(n * 64 + cg * 8) << 10) + (r << 5) + c0;
    #pragma unroll
    for (int co = 0; co < 8; ++co) {
        float bv = bias ? bias[cg * 8 + co] : 0.f;
        float a0 = acc[co][0] + bv, a1 = acc[co][1] + bv, a2 = acc[co][2] + bv, a3 = acc[co][3] + bv;
        if (ACT == 1) { a0 = lrelu(a0); a1 = lrelu(a1); a2 = lrelu(a2); a3 = lrelu(a3); }
        float4 v; v.x = a0; v.y = a1; v.z = a2; v.w = a3;
        *(float4*)(out + ob + ((size_t)co << 10)) = v;
        if (STATS) {
            float s = a0 + a1 + a2 + a3;
            float q = a0*a0 + a1*a1 + a2*a2 + a3*a3;
            #pragma unroll
            for (int m = 1; m < 64; m <<= 1) {
                s += __shfl_xor(s, m);
                q += __shfl_xor(q, m);
            }
            if (lane == 0) { sS[co][wv_id] = s; sQ[co][wv_id] = q; }
        }
    }
    if (STATS) {
        __syncthreads();
        if (tid < 8) {
            float s = sS[tid][0] + sS[tid][1] + sS[tid][2] + sS[tid][3];
            float q = sQ[tid][0] + sQ[tid][1] + sQ[tid][2] + sQ[tid][3];
            psum[(cg * 8 + tid) * 64 + n] = s;
            pss [(cg * 8 + tid) * 64 + n] = q;
        }
    }
}

// ================= conv1x1 fp32 (encoder), fused BN input / stats =================
template<int IN, int ACT, int STATS>
__global__ void __launch_bounds__(256) conv1x1_t(
    const float* __restrict__ in, const float* __restrict__ res,
    const float* __restrict__ w, const float* __restrict__ bias,
    const float* __restrict__ fin, const float* __restrict__ g,
    const float* __restrict__ beta, float* __restrict__ out,
    float* __restrict__ psum, float* __restrict__ pss)
{
    __shared__ float lw[64][8];
    __shared__ float sga[64], sbb[64];
    __shared__ float sS[8][4], sQ[8][4];
    int b = blockIdx.x;
    int n = b & 63, cg = b >> 6;
    int tid = threadIdx.x;
    int lane = tid & 63, wv_id = tid >> 6;
    for (int i = tid; i < 512; i += 256) {
        int ci = i >> 3, co = i & 7;
        lw[ci][co] = w[(cg * 8 + co) * 64 + ci];
    }
    if (IN >= 1 && tid < 64) {
        float ga = g[tid] * fin[2 * tid + 1];
        sga[tid] = ga;
        sbb[tid] = beta[tid] - fin[2 * tid] * ga;
    }
    __syncthreads();
    const float4* in4 = (const float4*)(in + (size_t)n * 65536);
    const float4* res4 = (IN == 2) ? (const float4*)(res + (size_t)n * 65536) : nullptr;
    float acc[8][4];
    #pragma unroll
    for (int co = 0; co < 8; ++co) { acc[co][0]=acc[co][1]=acc[co][2]=acc[co][3]=0.f; }
    #pragma unroll 4
    for (int ci = 0; ci < 64; ++ci) {
        float4 xv = in4[(ci << 8) + tid];
        float x0, x1, x2, x3;
        if (IN == 1) {
            float ga = sga[ci], bb = sbb[ci];
            x0 = fmaxf(fmaf(xv.x, ga, bb), 0.f);
            x1 = fmaxf(fmaf(xv.y, ga, bb), 0.f);
            x2 = fmaxf(fmaf(xv.z, ga, bb), 0.f);
            x3 = fmaxf(fmaf(xv.w, ga, bb), 0.f);
        } else if (IN == 2) {
            float4 rv = res4[(ci << 8) + tid];
            float ga = sga[ci], bb = sbb[ci];
            x0 = lrelu(rv.x + fmaf(xv.x, ga, bb));
            x1 = lrelu(rv.y + fmaf(xv.y, ga, bb));
            x2 = lrelu(rv.z + fmaf(xv.z, ga, bb));
            x3 = lrelu(rv.w + fmaf(xv.w, ga, bb));
        } else {
            x0 = xv.x; x1 = xv.y; x2 = xv.z; x3 = xv.w;
        }
        #pragma unroll
        for (int co = 0; co < 8; ++co) {
            float wvv = lw[ci][co];
            acc[co][0] = fmaf(x0, wvv, acc[co][0]);
            acc[co][1] = fmaf(x1, wvv, acc[co][1]);
            acc[co][2] = fmaf(x2, wvv, acc[co][2]);
            acc[co][3] = fmaf(x3, wvv, acc[co][3]);
        }
    }
    #pragma unroll
    for (int co = 0; co < 8; ++co) {
        float bv = bias ? bias[cg * 8 + co] : 0.f;
        float a0 = acc[co][0] + bv, a1 = acc[co][1] + bv, a2 = acc[co][2] + bv, a3 = acc[co][3] + bv;
        if (ACT == 1) { a0 = lrelu(a0); a1 = lrelu(a1); a2 = lrelu(a2); a3 = lrelu(a3); }
        float4 v; v.x = a0; v.y = a1; v.z = a2; v.w = a3;
        ((float4*)(out + (size_t)n * 65536 + (size_t)(cg * 8 + co) * 1024))[tid] = v;
        if (STATS) {
            float s = a0 + a1 + a2 + a3;
            float q = a0*a0 + a1*a1 + a2*a2 + a3*a3;
            #pragma unroll
            for (int m = 1; m < 64; m <<= 1) {
                s += __shfl_xor(s, m);
                q += __shfl_xor(q, m);
            }
            if (lane == 0) { sS[co][wv_id] = s; sQ[co][wv_id] = q; }
        }
    }
    if (STATS) {
        __syncthreads();
        if (tid < 8) {
            float s = sS[tid][0] + sS[tid][1] + sS[tid][2] + sS[tid][3];
            float q = sQ[tid][0] + sQ[tid][1] + sQ[tid][2] + sQ[tid][3];
            psum[(cg * 8 + tid) * 64 + n] = s;
            pss [(cg * 8 + tid) * 64 + n] = q;
        }
    }
}

// ================= BN finalize (encoder partials: [c][64]) =================
__global__ void bn_fin2_k(const float* __restrict__ psum, const float* __restrict__ pss,
                          float* __restrict__ fin, float invM)
{
    int c = threadIdx.x;
    if (c >= 64) return;
    float s = 0.f, q = 0.f;
    for (int n = 0; n < 64; ++n) { s += psum[c * 64 + n]; q += pss[c * 64 + n]; }
    float mean = s * invM;
    float var  = q * invM - mean * mean;
    fin[2 * c] = mean;
    fin[2 * c + 1] = rsqrtf(var + 1e-5f);
}

// ================= BN finalize (decoder MFMA partials: [c][256]) =================
__global__ void bn_fin3_k(const float* __restrict__ psum, const float* __restrict__ pss,
                          float* __restrict__ fin, float invM)
{
    int c = threadIdx.x;
    if (c >= 64) return;
    float s = 0.f, q = 0.f;
    for (int i = 0; i < 256; ++i) { s += psum[c * 256 + i]; q += pss[c * 256 + i]; }
    float mean = s * invM;
    float var  = q * invM - mean * mean;
    fin[2 * c] = mean;
    fin[2 * c + 1] = rsqrtf(var + 1e-5f);
}

// ================= BN apply: out = lrelu(res + bn(in)), float4 =================
__global__ void __launch_bounds__(256) bn_apply_res_k(
    const float* __restrict__ in, const float* __restrict__ fin,
    const float* __restrict__ g, const float* __restrict__ beta,
    const float* __restrict__ res, float* __restrict__ out)
{
    int i = blockIdx.x * 256 + threadIdx.x;
    int c = (i >> 8) & 63;
    float ga = g[c] * fin[2 * c + 1];
    float bb = beta[c] - fin[2 * c] * ga;
    float4 v = ((const float4*)in)[i];
    float4 rv = ((const float4*)res)[i];
    float4 o;
    o.x = lrelu(rv.x + fmaf(v.x, ga, bb));
    o.y = lrelu(rv.y + fmaf(v.y, ga, bb));
    o.z = lrelu(rv.z + fmaf(v.z, ga, bb));
    o.w = lrelu(rv.w + fmaf(v.w, ga, bb));
    ((float4*)out)[i] = o;
}

// ================= transpose NCHW fp32 -> NHWC bf16 (+optional BN-relu) =================
// grid 256: n = b>>2, pxb = b&3 (256 px)
template<int MODE>  // 0 plain, 1 relu(bn(x))
__global__ void __launch_bounds__(256) trans_k(
    const float* __restrict__ in, const float* __restrict__ fin,
    const float* __restrict__ g, const float* __restrict__ beta,
    unsigned short* __restrict__ outT)
{
    __shared__ unsigned short tt[256][68];
    __shared__ float sga[64], sbb[64];
    int b = blockIdx.x;
    int n = b >> 2, pxb = b & 3;
    int tid = threadIdx.x;
    if (MODE == 1) {
        if (tid < 64) {
            float ga = g[tid] * fin[2 * tid + 1];
            sga[tid] = ga;
            sbb[tid] = beta[tid] - fin[2 * tid] * ga;
        }
        __syncthreads();
    }
    for (int i = tid; i < 16384; i += 256) {
        int ci = i >> 8, px = i & 255;
        float v = in[((size_t)(n * 64 + ci) << 10) + pxb * 256 + px];
        if (MODE == 1) v = fmaxf(fmaf(v, sga[ci], sbb[ci]), 0.f);
        tt[px][ci] = f2bf(v);
    }
    __syncthreads();
    for (int o = tid; o < 4096; o += 256) {
        int px = o >> 4, c4 = o & 15;
        uint2 v = *(const uint2*)&tt[px][c4 * 4];
        *(uint2*)(outT + ((((size_t)n << 10) + pxb * 256 + px) << 6) + c4 * 4) = v;
    }
}

// ================= MFMA conv3x3 64->64 @32x32, bf16 (decoder) =================
// in: NHWC bf16 [n][32][32][64]; out: NCHW fp32. grid 512: cg=b&1 (32 co), pxb=(b>>1)&3 (8 rows), n=b>>3
template<int ACT, int STATS>
__global__ void __launch_bounds__(256) mfma_conv3x3_k(
    const unsigned short* __restrict__ inT, const float* __restrict__ w,
    const float* __restrict__ bias, float* __restrict__ out,
    float* __restrict__ psum, float* __restrict__ pss)
{
    __shared__ unsigned short lin[10][34][40];
    __shared__ unsigned short lwA[32][296];
    __shared__ float sS[4][32], sQ[4][32];
    int b = blockIdx.x;
    int cg = b & 1, pxb = (b >> 1) & 3, n = b >> 3;
    int tid = threadIdx.x;
    int wv = tid >> 6, l = tid & 63;
    int l15 = l & 15, lhi = l >> 4;

    f32x4 acc[2][4];
    #pragma unroll
    for (int ct = 0; ct < 2; ++ct)
        #pragma unroll
        for (int bt = 0; bt < 4; ++bt) {
            f32x4 z = {0.f, 0.f, 0.f, 0.f};
            acc[ct][bt] = z;
        }

    for (int c2 = 0; c2 < 2; ++c2) {
        __syncthreads();
        // stage input tile: rows iy = 8*pxb-1 .. 8*pxb+8, cols -1..32, 32 ci
        for (int i = tid; i < 1360; i += 256) {
            int pos = i >> 2, q = i & 3;
            int row = pos / 34, col = pos % 34;
            int iy = pxb * 8 - 1 + row, ix = col - 1;
            uint4 v = make_uint4(0u, 0u, 0u, 0u);
            if (iy >= 0 && iy < 32 && ix >= 0 && ix < 32)
                v = *(const uint4*)(inT + ((((size_t)n << 10) + iy * 32 + ix) << 6) + c2 * 32 + q * 8);
            *(uint4*)&lin[row][col][q * 8] = v;
        }
        // stage weights: k' = tap*32 + ci'  (32 co of this cg)
        for (int i = tid; i < 9216; i += 256) {
            int col = i / 288, k = i % 288;
            int tap = k >> 5, cc = k & 31;
            int co = cg * 32 + col;
            lwA[col][k] = f2bf(w[(co * 64 + c2 * 32 + cc) * 9 + tap]);
        }
        __syncthreads();
        #pragma unroll
        for (int tap = 0; tap < 9; ++tap) {
            const int dy = tap / 3, dx = tap % 3;
            short8 a[2], bb[4];
            #pragma unroll
            for (int ct = 0; ct < 2; ++ct)
                a[ct] = *(const short8*)&lwA[ct * 16 + l15][tap * 32 + lhi * 8];
            #pragma unroll
            for (int bt = 0; bt < 4; ++bt) {
                int rr = 2 * wv + (bt >> 1);
                int cc0 = (bt & 1) * 16;
                bb[bt] = *(const short8*)&lin[rr + dy][cc0 + l15 + dx][lhi * 8];
            }
            #pragma unroll
            for (int ct = 0; ct < 2; ++ct)
                #pragma unroll
                for (int bt = 0; bt < 4; ++bt)
                    acc[ct][bt] = __builtin_amdgcn_mfma_f32_16x16x32_bf16(a[ct], bb[bt], acc[ct][bt], 0, 0, 0);
        }
    }

    int orow0 = pxb * 8 + 2 * wv;
    #pragma unroll
    for (int ct = 0; ct < 2; ++ct) {
        #pragma unroll
        for (int j = 0; j < 4; ++j) {
            int co_l = ct * 16 + lhi * 4 + j;
            int co = cg * 32 + co_l;
            float bv = bias ? bias[co] : 0.f;
            float s = 0.f, q = 0.f;
            #pragma unroll
            for (int bt = 0; bt < 4; ++bt) {
                float v = acc[ct][bt][j] + bv;
                if (ACT == 1) v = lrelu(v);
                int row = orow0 + (bt >> 1);
                int col = (bt & 1) * 16 + l15;
                out[(((size_t)n * 64 + co) << 10) + row * 32 + col] = v;
                if (STATS) { s += v; q = fmaf(v, v, q); }
            }
            if (STATS) {
                #pragma unroll
                for (int m = 1; m < 16; m <<= 1) {
                    s += __shfl_xor(s, m);
                    q += __shfl_xor(q, m);
                }
                if (l15 == 0) { sS[wv][co_l] = s; sQ[wv][co_l] = q; }
            }
        }
    }
    if (STATS) {
        __syncthreads();
        if (tid < 32) {
            float s = sS[0][tid] + sS[1][tid] + sS[2][tid] + sS[3][tid];
            float q = sQ[0][tid] + sQ[1][tid] + sQ[2][tid] + sQ[3][tid];
            psum[(cg * 32 + tid) * 256 + n * 4 + pxb] = s;
            pss [(cg * 32 + tid) * 256 + n * 4 + pxb] = q;
        }
    }
}

// ================= MFMA conv1x1 64->64 @32x32, bf16 (decoder) =================
// grid 512: cg=b&1, pxb=(b>>1)&3, n=b>>3
template<int ACT, int STATS>
__global__ void __launch_bounds__(256) mfma_conv1x1_k(
    const unsigned short* __restrict__ inT, const float* __restrict__ w,
    const float* __restrict__ bias, float* __restrict__ out,
    float* __restrict__ psum, float* __restrict__ pss)
{
    __shared__ unsigned short lin[256][72];
    __shared__ unsigned short lwA[32][72];
    __shared__ float sS[4][32], sQ[4][32];
    int b = blockIdx.x;
    int cg = b & 1, pxb = (b >> 1) & 3, n = b >> 3;
    int tid = threadIdx.x;
    int wv = tid >> 6, l = tid & 63;
    int l15 = l & 15, lhi = l >> 4;

    for (int i = tid; i < 2048; i += 256) {
        int px = i >> 3, q = i & 7;
        uint4 v = *(const uint4*)(inT + ((((size_t)n << 10) + pxb * 256 + px) << 6) + q * 8);
        *(uint4*)&lin[px][q * 8] = v;
    }
    for (int i = tid; i < 2048; i += 256) {
        int col = i >> 6, ci = i & 63;
        lwA[col][ci] = f2bf(w[(cg * 32 + col) * 64 + ci]);
    }
    __syncthreads();

    f32x4 acc[2][4];
    #pragma unroll
    for (int ct = 0; ct < 2; ++ct)
        #pragma unroll
        for (int bt = 0; bt < 4; ++bt) {
            f32x4 z = {0.f, 0.f, 0.f, 0.f};
            acc[ct][bt] = z;
        }

    #pragma unroll
    for (int ks = 0; ks < 2; ++ks) {
        short8 a[2], bb[4];
        #pragma unroll
        for (int ct = 0; ct < 2; ++ct)
            a[ct] = *(const short8*)&lwA[ct * 16 + l15][ks * 32 + lhi * 8];
        #pragma unroll
        for (int bt = 0; bt < 4; ++bt)
            bb[bt] = *(const short8*)&lin[wv * 64 + bt * 16 + l15][ks * 32 + lhi * 8];
        #pragma unroll
        for (int ct = 0; ct < 2; ++ct)
            #pragma unroll
            for (int bt = 0; bt < 4; ++bt)
                acc[ct][bt] = __builtin_amdgcn_mfma_f32_16x16x32_bf16(a[ct], bb[bt], acc[ct][bt], 0, 0, 0);
    }

    #pragma unroll
    for (int ct = 0; ct < 2; ++ct) {
        #pragma unroll
        for (int j = 0; j < 4; ++j) {
            int co_l = ct * 16 + lhi * 4 + j;
            int co = cg * 32 + co_l;
            float bv = bias ? bias[co] : 0.f;
            float s = 0.f, q = 0.f;
            #pragma unroll
            for (int bt = 0; bt < 4; ++bt) {
                float v = acc[ct][bt][j] + bv;
                if (ACT == 1) v = lrelu(v);
                int px = pxb * 256 + wv * 64 + bt * 16 + l15;
                out[(((size_t)n * 64 + co) << 10) + px] = v;
                if (STATS) { s += v; q = fmaf(v, v, q); }
            }
            if (STATS) {
                #pragma unroll
                for (int m = 1; m < 16; m <<= 1) {
                    s += __shfl_xor(s, m);
                    q += __shfl_xor(q, m);
                }
                if (l15 == 0) { sS[wv][co_l] = s; sQ[wv][co_l] = q; }
            }
        }
    }
    if (STATS) {
        __syncthreads();
        if (tid < 32) {
            float s = sS[0][tid] + sS[1][tid] + sS[2][tid] + sS[3][tid];
            float q = sQ[0][tid] + sQ[1][tid] + sQ[2][tid] + sQ[3][tid];
            psum[(cg * 32 + tid) * 256 + n * 4 + pxb] = s;
            pss [(cg * 32 + tid) * 256 + n * 4 + pxb] = q;
        }
    }
}

// ================= VQ =================
__global__ void __launch_bounds__(256) vq_enorm_k(const float* __restrict__ emb, float* __restrict__ enorm)
{
    int k = blockIdx.x * 256 + threadIdx.x;
    if (k >= 512) return;
    const float4* e4 = (const float4*)(emb + (k << 6));
    float s = 0.f;
    #pragma unroll
    for (int j = 0; j < 16; ++j) {
        float4 e = e4[j];
        s = fmaf(e.x, e.x, s); s = fmaf(e.y, e.y, s);
        s = fmaf(e.z, e.z, s); s = fmaf(e.w, e.w, s);
    }
    enorm[k] = s;
}

__device__ __forceinline__ unsigned order_u32(float s) {
    unsigned u = __float_as_uint(s);
    return (s < 0.f) ? ~u : (u | 0x80000000u);
}

__global__ void __launch_bounds__(256) vq_dist_k(
    const float* __restrict__ z, const float* __restrict__ emb,
    const float* __restrict__ enorm, unsigned long long* __restrict__ best)
{
    __shared__ float se[64][64];
    __shared__ float sn[64];
    int b = blockIdx.x;
    int kb = b & 7, pg = b >> 3;
    int tid = threadIdx.x;
    for (int i = tid; i < 4096; i += 256)
        ((float*)se)[i] = emb[(kb << 12) + i];
    if (tid < 64) sn[tid] = enorm[(kb << 6) + tid];
    __syncthreads();

    int n = pg >> 1;
    int p0 = ((pg & 1) << 9) + tid;
    size_t base0 = (size_t)n * 65536 + p0;
    float z0[64], z1[64];
    #pragma unroll
    for (int d = 0; d < 64; ++d) z0[d] = z[base0 + (size_t)d * 1024];
    #pragma unroll
    for (int d = 0; d < 64; ++d) z1[d] = z[base0 + 256 + (size_t)d * 1024];

    unsigned long long b0 = ~0ULL, b1 = ~0ULL;
    for (int k = 0; k < 64; ++k) {
        const float4* e4 = (const float4*)se[k];
        float dot0 = 0.f, dot1 = 0.f;
        #pragma unroll
        for (int j = 0; j < 16; ++j) {
            float4 e = e4[j];
            dot0 = fmaf(z0[4*j],   e.x, dot0);
            dot0 = fmaf(z0[4*j+1], e.y, dot0);
            dot0 = fmaf(z0[4*j+2], e.z, dot0);
            dot0 = fmaf(z0[4*j+3], e.w, dot0);
            dot1 = fmaf(z1[4*j],   e.x, dot1);
            dot1 = fmaf(z1[4*j+1], e.y, dot1);
            dot1 = fmaf(z1[4*j+2], e.z, dot1);
            dot1 = fmaf(z1[4*j+3], e.w, dot1);
        }
        float s0 = fmaf(-2.f, dot0, sn[k]);
        float s1 = fmaf(-2.f, dot1, sn[k]);
        unsigned kk = (unsigned)((kb << 6) + k);
        unsigned long long p0k = ((unsigned long long)order_u32(s0) << 32) | kk;
        unsigned long long p1k = ((unsigned long long)order_u32(s1) << 32) | kk;
        b0 = p0k < b0 ? p0k : b0;
        b1 = p1k < b1 ? p1k : b1;
    }
    size_t m0 = ((size_t)pg << 9) + tid;
    best[((size_t)kb << 16) + m0]       = b0;
    best[((size_t)kb << 16) + m0 + 256] = b1;
}

__global__ void __launch_bounds__(256) vq_combine_k(
    const float* __restrict__ z, const float* __restrict__ emb,
    const unsigned long long* __restrict__ best,
    float* __restrict__ out_q, float* __restrict__ partials)
{
    int m = blockIdx.x * 256 + threadIdx.x;
    unsigned long long bb = best[m];
    #pragma unroll
    for (int kb = 1; kb < 8; ++kb) {
        unsigned long long v = best[((size_t)kb << 16) + m];
        bb = v < bb ? v : bb;
    }
    int bi = (int)(bb & 0x1ffu);
    int n = m >> 10, p = m & 1023;
    size_t base = (size_t)n * 65536 + p;
    const float* eb = emb + (bi << 6);
    float lsum = 0.f;
    #pragma unroll
    for (int d = 0; d < 64; ++d) {
        float zz = z[base + (size_t)d * 1024];
        float q = eb[d];
        out_q[base + (size_t)d * 1024] = q;
        float df = q - zz;
        lsum = fmaf(df, df, lsum);
    }
    __shared__ float sh[256];
    sh[threadIdx.x] = lsum;
    __syncthreads();
    for (int st = 128; st > 0; st >>= 1) {
        if (threadIdx.x < st) sh[threadIdx.x] += sh[threadIdx.x + st];
        __syncthreads();
    }
    if (threadIdx.x == 0) partials[blockIdx.x] = sh[0];
}

__global__ void vq_fin_k(const float* __restrict__ partials, float* __restrict__ out)
{
    __shared__ float sh[256];
    sh[threadIdx.x] = partials[threadIdx.x];
    __syncthreads();
    for (int st = 128; st > 0; st >>= 1) {
        if (threadIdx.x < st) sh[threadIdx.x] += sh[threadIdx.x + st];
        __syncthreads();
    }
    if (threadIdx.x == 0) out[0] = sh[0] * (0.25f / (65536.f * 64.f));
}

// ================= dt1: deconv 64->32, 32x32 -> 64x64, lrelu (plain input) =================
__global__ void __launch_bounds__(256) deconv_dt1_t(
    const float* __restrict__ in, const float* __restrict__ w,
    const float* __restrict__ bias, float* __restrict__ out)
{
    __shared__ float lin[8][10][37];
    __shared__ float lw[8][8][16];
    int b = blockIdx.x;
    int n = b & 63, rt = (b >> 6) & 3, cg = b >> 8;
    int tid = threadIdx.x;
    int r16 = tid >> 4, g = tid & 15;
    int oy = rt * 16 + r16;
    const float* inp = in + (size_t)n * 65536;
    int iy0 = rt * 8 - 1;
    int ky0 = (oy + 1) & 1;
    int iyA = ((oy + 1 - ky0) >> 1) - iy0;
    int iyB = iyA - 1;
    int lx = 2 * g;

    float acc[8][4];
    #pragma unroll
    for (int co = 0; co < 8; ++co) { acc[co][0]=acc[co][1]=acc[co][2]=acc[co][3]=0.f; }

    for (int cic = 0; cic < 8; ++cic) {
        __syncthreads();
        for (int i = tid; i < 2720; i += 256) {
            int ci = i / 340, rr = i % 340;
            int y = rr / 34, xx = rr % 34;
            int gy = iy0 + y, gx = xx - 1;
            float v = 0.f;
            if (gy >= 0 && gy < 32 && gx >= 0 && gx < 32)
                v = inp[(cic * 8 + ci) * 1024 + gy * 32 + gx];
            lin[ci][y][xx] = v;
        }
        for (int i = tid; i < 1024; i += 256) {
            int ci = i >> 7, rr = i & 127, co = rr >> 4, tt = rr & 15;
            lw[ci][co][tt] = w[((cic * 8 + ci) * 32 + cg * 8 + co) * 16 + tt];
        }
        __syncthreads();
        #pragma unroll 2
        for (int ci = 0; ci < 8; ++ci) {
            float vA0 = lin[ci][iyA][lx],     vA1 = lin[ci][iyA][lx + 1];
            float vA2 = lin[ci][iyA][lx + 2], vA3 = lin[ci][iyA][lx + 3];
            float vB0 = lin[ci][iyB][lx],     vB1 = lin[ci][iyB][lx + 1];
            float vB2 = lin[ci][iyB][lx + 2], vB3 = lin[ci][iyB][lx + 3];
            #pragma unroll
            for (int co = 0; co < 8; ++co) {
                const float4* wp = (const float4*)lw[ci][co];
                float4 wA = wp[ky0];
                float4 wB = wp[ky0 + 2];
                acc[co][0] = fmaf(vA1, wA.y, fmaf(vA0, wA.w, fmaf(vB1, wB.y, fmaf(vB0, wB.w, acc[co][0]))));
                acc[co][1] = fmaf(vA2, wA.x, fmaf(vA1, wA.z, fmaf(vB2, wB.x, fmaf(vB1, wB.z, acc[co][1]))));
                acc[co][2] = fmaf(vA2, wA.y, fmaf(vA1, wA.w, fmaf(vB2, wB.y, fmaf(vB1, wB.w, acc[co][2]))));
                acc[co][3] = fmaf(vA3, wA.x, fmaf(vA2, wA.z, fmaf(vB3, wB.x, fmaf(vB2, wB.z, acc[co][3]))));
            }
        }
    }
    #pragma unroll
    for (int co = 0; co < 8; ++co) {
        float bv = bias[cg * 8 + co];
        float4 v;
        v.x = lrelu(acc[co][0] + bv); v.y = lrelu(acc[co][1] + bv);
        v.z = lrelu(acc[co][2] + bv); v.w = lrelu(acc[co][3] + bv);
        *(float4*)(out + ((size_t)(n * 32 + cg * 8 + co) * 4096) + oy * 64 + 4 * g) = v;
    }
}

// ================= dt2: deconv 32->3, 64x64 -> 128x128, tanh =================
__global__ void __launch_bounds__(256) deconv_dt2_t(
    const float* __restrict__ in, const float* __restrict__ w,
    const float* __restrict__ bias, float* __restrict__ out)
{
    __shared__ float lin[8][6][67];
    __shared__ float lw[8][3][16];
    int b = blockIdx.x;
    int n = b & 63, rt = b >> 6;
    int tid = threadIdx.x;
    int r8 = tid >> 5, g = tid & 31;
    int oy = rt * 8 + r8;
    const float* inp = in + (size_t)n * 32 * 4096;
    int iy0 = rt * 4 - 1;
    int ky0 = (oy + 1) & 1;
    int iyA = ((oy + 1 - ky0) >> 1) - iy0;
    int iyB = iyA - 1;
    int lx = 2 * g;

    float acc[3][4];
    #pragma unroll
    for (int co = 0; co < 3; ++co) { acc[co][0]=acc[co][1]=acc[co][2]=acc[co][3]=0.f; }

    for (int cic = 0; cic < 4; ++cic) {
        __syncthreads();
        for (int i = tid; i < 3168; i += 256) {
            int ci = i / 396, rr = i % 396;
            int y = rr / 66, xx = rr % 66;
            int gy = iy0 + y, gx = xx - 1;
            float v = 0.f;
            if (gy >= 0 && gy < 64 && gx >= 0 && gx < 64)
                v = inp[(cic * 8 + ci) * 4096 + gy * 64 + gx];
            lin[ci][y][xx] = v;
        }
        for (int i = tid; i < 384; i += 256) {
            int ci = i / 48, rr = i % 48;
            int co = rr >> 4, tt = rr & 15;
            lw[ci][co][tt] = w[((cic * 8 + ci) * 3 + co) * 16 + tt];
        }
        __syncthreads();
        #pragma unroll 2
        for (int ci = 0; ci < 8; ++ci) {
            float vA0 = lin[ci][iyA][lx],     vA1 = lin[ci][iyA][lx + 1];
            float vA2 = lin[ci][iyA][lx + 2], vA3 = lin[ci][iyA][lx + 3];
            float vB0 = lin[ci][iyB][lx],     vB1 = lin[ci][iyB][lx + 1];
            float vB2 = lin[ci][iyB][lx + 2], vB3 = lin[ci][iyB][lx + 3];
            #pragma unroll
            for (int co = 0; co < 3; ++co) {
                const float4* wp = (const float4*)lw[ci][co];
                float4 wA = wp[ky0];
                float4 wB = wp[ky0 + 2];
                acc[co][0] = fmaf(vA1, wA.y, fmaf(vA0, wA.w, fmaf(vB1, wB.y, fmaf(vB0, wB.w, acc[co][0]))));
                acc[co][1] = fmaf(vA2, wA.x, fmaf(vA1, wA.z, fmaf(vB2, wB.x, fmaf(vB1, wB.z, acc[co][1]))));
                acc[co][2] = fmaf(vA2, wA.y, fmaf(vA1, wA.w, fmaf(vB2, wB.y, fmaf(vB1, wB.w, acc[co][2]))));
                acc[co][3] = fmaf(vA3, wA.x, fmaf(vA2, wA.z, fmaf(vB3, wB.x, fmaf(vB2, wB.z, acc[co][3]))));
            }
        }
    }
    #pragma unroll
    for (int co = 0; co < 3; ++co) {
        float bv = bias[co];
        float4 v;
        v.x = fast_tanh(acc[co][0] + bv); v.y = fast_tanh(acc[co][1] + bv);
        v.z = fast_tanh(acc[co][2] + bv); v.w = fast_tanh(acc[co][3] + bv);
        *(float4*)(out + ((size_t)(n * 3 + co) * 16384) + oy * 128 + 4 * g) = v;
    }
}

extern "C" void kernel_launch(void* const* d_in, const int* in_sizes, int n_in,
                              void* d_out, int out_size, void* d_ws, size_t ws_size,
                              hipStream_t stream)
{
    const float* x    = (const float*)d_in[0];
    const float* e1w  = (const float*)d_in[1];
    const float* e1b  = (const float*)d_in[2];
    const float* e2w  = (const float*)d_in[3];
    const float* e2b  = (const float*)d_in[4];
    const float* e3w  = (const float*)d_in[5];
    const float* e3b  = (const float*)d_in[6];
    const float* er1w = (const float*)d_in[7];
    const float* er1g = (const float*)d_in[8];
    const float* er1b = (const float*)d_in[9];
    const float* er2w = (const float*)d_in[10];
    const float* er2g = (const float*)d_in[11];
    const float* er2b = (const float*)d_in[12];
    const float* e4w  = (const float*)d_in[13];
    const float* e4b  = (const float*)d_in[14];
    const float* emb  = (const float*)d_in[15];
    const float* d1w  = (const float*)d_in[16];
    const float* d1b  = (const float*)d_in[17];
    const float* dr1w = (const float*)d_in[18];
    const float* dr1g = (const float*)d_in[19];
    const float* dr1b = (const float*)d_in[20];
    const float* dr2w = (const float*)d_in[21];
    const float* dr2g = (const float*)d_in[22];
    const float* dr2b = (const float*)d_in[23];
    const float* dt1w = (const float*)d_in[24];
    const float* dt1b = (const float*)d_in[25];
    const float* dt2w = (const float*)d_in[26];
    const float* dt2b = (const float*)d_in[27];

    float* out = (float*)d_out;
    float* ws  = (float*)d_ws;

    // workspace layout (floats)
    float* B0 = ws;                   // 8,388,608
    float* B1 = ws + 8388608;         // 4,194,304 (fp32 in encoder; reused as bf16 Tbuf in decoder)
    float* B2 = B1 + 4194304;
    float* B3 = B2 + 4194304;
    float* B4 = B3 + 4194304;
    float* psum   = B4 + 4194304;     // 16384
    float* pss    = psum + 16384;     // 16384
    float* fin    = pss + 16384;      // 128
    float* vq_part = fin + 128;       // 256
    float* enorm   = vq_part + 256;   // 512
    unsigned long long* bestbuf = (unsigned long long*)(enorm + 512);  // 4MB

    unsigned short* tbuf = (unsigned short*)B1;  // 8.4MB bf16 NHWC

    float* out_recon = out;                 // 3,145,728
    float* out_q     = out + 3145728;       // 4,194,304
    float* out_e     = out + 7340032;       // 4,194,304
    float* out_loss  = out + 11534336;      // 1

    const float invM = 1.f / 65536.f;

    // ---------------- encoder (fp32 — protects VQ argmin) ----------------
    conv_e1_t<<<512, 256, 0, stream>>>(x, e1w, e1b, B0);
    conv_e2_t<<<512, 256, 0, stream>>>(B0, e2w, e2b, B1);
    conv3x3_t<1,0><<<512, 256, 0, stream>>>(B1, e3w, e3b, B2, nullptr, nullptr);

    conv3x3_t<0,1><<<512, 256, 0, stream>>>(B2, er1w, nullptr, B3, psum, pss);
    bn_fin2_k<<<1, 64, 0, stream>>>(psum, pss, fin, invM);
    conv1x1_t<1,0,1><<<512, 256, 0, stream>>>(B3, nullptr, er2w, nullptr, fin, er1g, er1b, B4, psum, pss);
    bn_fin2_k<<<1, 64, 0, stream>>>(psum, pss, fin, invM);
    conv1x1_t<2,1,0><<<512, 256, 0, stream>>>(B4, B2, e4w, e4b, fin, er2g, er2b, out_e, nullptr, nullptr);

    // VQ (fp32)
    vq_enorm_k<<<2, 256, 0, stream>>>(emb, enorm);
    vq_dist_k<<<1024, 256, 0, stream>>>(out_e, emb, enorm, bestbuf);
    vq_combine_k<<<256, 256, 0, stream>>>(out_e, emb, bestbuf, out_q, vq_part);
    vq_fin_k<<<1, 256, 0, stream>>>(vq_part, out_loss);

    // ---------------- decoder (bf16 MFMA) ----------------
    // d1: conv3x3 + lrelu
    trans_k<0><<<256, 256, 0, stream>>>(out_q, nullptr, nullptr, nullptr, tbuf);
    mfma_conv3x3_k<1,0><<<512, 256, 0, stream>>>(tbuf, d1w, d1b, B2, nullptr, nullptr);

    // dr1: conv3x3 (no bias) + stats
    trans_k<0><<<256, 256, 0, stream>>>(B2, nullptr, nullptr, nullptr, tbuf);
    mfma_conv3x3_k<0,1><<<512, 256, 0, stream>>>(tbuf, dr1w, nullptr, B3, psum, pss);
    bn_fin3_k<<<1, 64, 0, stream>>>(psum, pss, fin, invM);

    // dr2: relu(bn(.)) fused into transpose; conv1x1 (no bias) + stats
    trans_k<1><<<256, 256, 0, stream>>>(B3, fin, dr1g, dr1b, tbuf);
    mfma_conv1x1_k<0,1><<<512, 256, 0, stream>>>(tbuf, dr2w, nullptr, B4, psum, pss);
    bn_fin3_k<<<1, 64, 0, stream>>>(psum, pss, fin, invM);

    // h = lrelu(res(B2) + bn(B4)) -> B1 (tbuf dead now)
    bn_apply_res_k<<<4096, 256, 0, stream>>>(B4, fin, dr2g, dr2b, B2, B1);

    // deconvs (fp32)
    deconv_dt1_t<<<1024, 256, 0, stream>>>(B1, dt1w, dt1b, B0);
    deconv_dt2_t<<<1024, 256, 0, stream>>>(B0, dt2w, dt2b, out_recon);
}

// Round 9
// 609.548 us; speedup vs baseline: 9.3397x; 1.0708x over previous
//
#include <hip/hip_runtime.h>
#include <math.h>

#define LREL 0.01f
__device__ __forceinline__ float lrelu(float x) { return x > 0.f ? x : LREL * x; }
__device__ __forceinline__ float fast_tanh(float x) {
    x = fminf(fmaxf(x, -10.f), 10.f);
    float a = __expf(2.f * x);
    return (a - 1.f) / (a + 1.f);
}
__device__ __forceinline__ unsigned short f2bf(float f) {
    unsigned u = __float_as_uint(f);
    unsigned r = u + 0x7FFFu + ((u >> 16) & 1u);
    return (unsigned short)(r >> 16);
}

typedef __attribute__((ext_vector_type(8))) short short8;
typedef __attribute__((ext_vector_type(4))) float f32x4;

// ================= e1: 3->32, 128x128 -> 64x64, 4x4 s2 p1, lrelu (fp32) =================
__global__ void __launch_bounds__(256) conv_e1_t(
    const float* __restrict__ x, const float* __restrict__ w,
    const float* __restrict__ bias, float* __restrict__ out)
{
    __shared__ float lin[3][66][67];
    __shared__ float lw[3][16][16];
    int b = blockIdx.x;
    int n = b & 63, t = b >> 6;
    int tile = t & 3, cg = t >> 2;
    int ty = tile >> 1, tx = tile & 1;
    int tid = threadIdx.x;
    int r = tid >> 3, g = tid & 7, c0 = g << 2;
    const float* inp = x + (size_t)n * 3 * 16384;

    for (int i = tid; i < 3 * 66 * 66; i += 256) {
        int ci = i / 4356, rr = i % 4356;
        int y = rr / 66, xx = rr % 66;
        int gy = ty * 64 - 1 + y, gx = tx * 64 - 1 + xx;
        float v = 0.f;
        if (gy >= 0 && gy < 128 && gx >= 0 && gx < 128)
            v = inp[ci * 16384 + gy * 128 + gx];
        lin[ci][y][xx] = v;
    }
    for (int i = tid; i < 768; i += 256) {
        int ci = i >> 8, rr = i & 255, co = rr >> 4, tt = rr & 15;
        lw[ci][co][tt] = w[((cg * 16 + co) * 3 + ci) * 16 + tt];
    }
    __syncthreads();

    float acc[16][4];
    #pragma unroll
    for (int co = 0; co < 16; ++co) { acc[co][0]=acc[co][1]=acc[co][2]=acc[co][3]=0.f; }

    #pragma unroll
    for (int ci = 0; ci < 3; ++ci) {
        float win[4][10];
        #pragma unroll
        for (int dy = 0; dy < 4; ++dy)
            #pragma unroll
            for (int dx = 0; dx < 10; ++dx)
                win[dy][dx] = lin[ci][2 * r + dy][8 * g + dx];
        #pragma unroll
        for (int co = 0; co < 16; ++co) {
            #pragma unroll
            for (int ky = 0; ky < 4; ++ky)
                #pragma unroll
                for (int kx = 0; kx < 4; ++kx) {
                    float wv = lw[ci][co][ky * 4 + kx];
                    #pragma unroll
                    for (int j = 0; j < 4; ++j)
                        acc[co][j] = fmaf(win[ky][2 * j + kx], wv, acc[co][j]);
                }
        }
    }
    int oy = ty * 32 + r, ox0 = tx * 32 + c0;
    #pragma unroll
    for (int co = 0; co < 16; ++co) {
        float bv = bias[cg * 16 + co];
        float4 v;
        v.x = lrelu(acc[co][0] + bv); v.y = lrelu(acc[co][1] + bv);
        v.z = lrelu(acc[co][2] + bv); v.w = lrelu(acc[co][3] + bv);
        *(float4*)(out + ((size_t)(n * 32 + cg * 16 + co) * 4096) + oy * 64 + ox0) = v;
    }
}

// ================= e2: 32->64, 64x64 -> 32x32 (fp32), 4-ci chunks for occupancy =================
__global__ void __launch_bounds__(256) conv_e2_t(
    const float* __restrict__ in, const float* __restrict__ w,
    const float* __restrict__ bias, float* __restrict__ out)
{
    __shared__ float lin[4][10][66];   // 10.6 KB
    __shared__ float lw[4][64][16];    // 16.4 KB  -> 27 KB total: 5 blocks/CU
    int b = blockIdx.x;
    int n = b & 63, ry = b >> 6;
    int tid = threadIdx.x;
    int c = tid & 31, cog = tid >> 5;
    int iy0 = 8 * ry - 1;
    const float* inp = in + (size_t)n * 32 * 4096;

    float acc[8][4];
    #pragma unroll
    for (int q = 0; q < 8; ++q) { acc[q][0]=acc[q][1]=acc[q][2]=acc[q][3]=0.f; }

    for (int cic = 0; cic < 8; ++cic) {
        __syncthreads();
        for (int i = tid; i < 2640; i += 256) {
            int ci = i / 660, rr = i % 660;
            int riy = rr / 66, j = rr % 66;
            int gy = iy0 + riy, gx = j - 1;
            float v = 0.f;
            if (gy >= 0 && gy < 64 && gx >= 0 && gx < 64)
                v = inp[(cic * 4 + ci) * 4096 + gy * 64 + gx];
            lin[ci][riy][j] = v;
        }
        for (int i = tid; i < 4096; i += 256) {
            int ci = i >> 10, rr = i & 1023, co = rr >> 4, tt = rr & 15;
            lw[ci][co][tt] = w[(co * 32 + cic * 4 + ci) * 16 + tt];
        }
        __syncthreads();
        #pragma unroll
        for (int ci = 0; ci < 4; ++ci) {
            float win[10][4];
            #pragma unroll
            for (int riy = 0; riy < 10; ++riy)
                #pragma unroll
                for (int q = 0; q < 4; ++q)
                    win[riy][q] = lin[ci][riy][2 * c + q];
            #pragma unroll
            for (int cq = 0; cq < 8; ++cq) {
                const float* wp = lw[ci][cog * 8 + cq];
                #pragma unroll
                for (int r = 0; r < 4; ++r)
                    #pragma unroll
                    for (int ky = 0; ky < 4; ++ky)
                        #pragma unroll
                        for (int kx = 0; kx < 4; ++kx)
                            acc[cq][r] = fmaf(win[2 * r + ky][kx], wp[ky * 4 + kx], acc[cq][r]);
            }
        }
    }
    #pragma unroll
    for (int cq = 0; cq < 8; ++cq) {
        int co = cog * 8 + cq;
        float bv = bias[co];
        #pragma unroll
        for (int r = 0; r < 4; ++r)
            out[((size_t)(n * 64 + co) << 10) + (4 * ry + r) * 32 + c] = lrelu(acc[cq][r] + bv);
    }
}

// ================= conv3x3 fp32 (encoder), optional fused BN stats =================
template<int ACT, int STATS>
__global__ void __launch_bounds__(256) conv3x3_t(
    const float* __restrict__ in, const float* __restrict__ w,
    const float* __restrict__ bias, float* __restrict__ out,
    float* __restrict__ psum, float* __restrict__ pss)
{
    __shared__ float lin[8][34][35];
    __shared__ float lw[8][8][9];
    __shared__ float sS[8][4], sQ[8][4];
    int b = blockIdx.x;
    int n = b & 63, cg = b >> 6;
    int tid = threadIdx.x;
    int r = tid >> 3, g = tid & 7, c0 = g << 2;
    int lane = tid & 63, wv_id = tid >> 6;
    const float* inp = in + (size_t)n * 65536;
    const float4* in4 = (const float4*)inp;

    float acc[8][4];
    #pragma unroll
    for (int co = 0; co < 8; ++co) { acc[co][0]=acc[co][1]=acc[co][2]=acc[co][3]=0.f; }

    for (int i = tid; i < 8 * 34 * 35; i += 256) ((float*)lin)[i] = 0.f;

    for (int cic = 0; cic < 8; ++cic) {
        __syncthreads();
        for (int i = tid; i < 2048; i += 256) {
            int ci = i >> 8, p = i & 255;
            int row = p >> 3, qq = p & 7;
            float4 v = in4[(cic * 8 + ci) * 256 + p];
            float* dst = &lin[ci][row + 1][1 + 4 * qq];
            dst[0] = v.x; dst[1] = v.y; dst[2] = v.z; dst[3] = v.w;
        }
        for (int i = tid; i < 576; i += 256) {
            int ci = i / 72, rr = i % 72;
            int co = rr / 9, tt = rr % 9;
            lw[ci][co][tt] = w[((cg * 8 + co) * 64 + cic * 8 + ci) * 9 + tt];
        }
        __syncthreads();
        #pragma unroll 2
        for (int ci = 0; ci < 8; ++ci) {
            float win[3][6];
            #pragma unroll
            for (int dy = 0; dy < 3; ++dy)
                #pragma unroll
                for (int dx = 0; dx < 6; ++dx)
                    win[dy][dx] = lin[ci][r + dy][c0 + dx];
            #pragma unroll
            for (int co = 0; co < 8; ++co) {
                #pragma unroll
                for (int dy = 0; dy < 3; ++dy)
                    #pragma unroll
                    for (int dx = 0; dx < 3; ++dx) {
                        float wvv = lw[ci][co][dy * 3 + dx];
                        #pragma unroll
                        for (int j = 0; j < 4; ++j)
                            acc[co][j] = fmaf(win[dy][j + dx], wvv, acc[co][j]);
                    }
            }
        }
    }
    size_t ob = ((size_t)(n * 64 + cg * 8) << 10) + (r << 5) + c0;
    #pragma unroll
    for (int co = 0; co < 8; ++co) {
        float bv = bias ? bias[cg * 8 + co] : 0.f;
        float a0 = acc[co][0] + bv, a1 = acc[co][1] + bv, a2 = acc[co][2] + bv, a3 = acc[co][3] + bv;
        if (ACT == 1) { a0 = lrelu(a0); a1 = lrelu(a1); a2 = lrelu(a2); a3 = lrelu(a3); }
        float4 v; v.x = a0; v.y = a1; v.z = a2; v.w = a3;
        *(float4*)(out + ob + ((size_t)co << 10)) = v;
        if (STATS) {
            float s = a0 + a1 + a2 + a3;
            float q = a0*a0 + a1*a1 + a2*a2 + a3*a3;
            #pragma unroll
            for (int m = 1; m < 64; m <<= 1) {
                s += __shfl_xor(s, m);
                q += __shfl_xor(q, m);
            }
            if (lane == 0) { sS[co][wv_id] = s; sQ[co][wv_id] = q; }
        }
    }
    if (STATS) {
        __syncthreads();
        if (tid < 8) {
            float s = sS[tid][0] + sS[tid][1] + sS[tid][2] + sS[tid][3];
            float q = sQ[tid][0] + sQ[tid][1] + sQ[tid][2] + sQ[tid][3];
            psum[(cg * 8 + tid) * 64 + n] = s;
            pss [(cg * 8 + tid) * 64 + n] = q;
        }
    }
}

// ================= conv1x1 fp32 (encoder), fused BN input / stats =================
template<int IN, int ACT, int STATS>
__global__ void __launch_bounds__(256) conv1x1_t(
    const float* __restrict__ in, const float* __restrict__ res,
    const float* __restrict__ w, const float* __restrict__ bias,
    const float* __restrict__ fin, const float* __restrict__ g,
    const float* __restrict__ beta, float* __restrict__ out,
    float* __restrict__ psum, float* __restrict__ pss)
{
    __shared__ float lw[64][8];
    __shared__ float sga[64], sbb[64];
    __shared__ float sS[8][4], sQ[8][4];
    int b = blockIdx.x;
    int n = b & 63, cg = b >> 6;
    int tid = threadIdx.x;
    int lane = tid & 63, wv_id = tid >> 6;
    for (int i = tid; i < 512; i += 256) {
        int ci = i >> 3, co = i & 7;
        lw[ci][co] = w[(cg * 8 + co) * 64 + ci];
    }
    if (IN >= 1 && tid < 64) {
        float ga = g[tid] * fin[2 * tid + 1];
        sga[tid] = ga;
        sbb[tid] = beta[tid] - fin[2 * tid] * ga;
    }
    __syncthreads();
    const float4* in4 = (const float4*)(in + (size_t)n * 65536);
    const float4* res4 = (IN == 2) ? (const float4*)(res + (size_t)n * 65536) : nullptr;
    float acc[8][4];
    #pragma unroll
    for (int co = 0; co < 8; ++co) { acc[co][0]=acc[co][1]=acc[co][2]=acc[co][3]=0.f; }
    #pragma unroll 4
    for (int ci = 0; ci < 64; ++ci) {
        float4 xv = in4[(ci << 8) + tid];
        float x0, x1, x2, x3;
        if (IN == 1) {
            float ga = sga[ci], bb = sbb[ci];
            x0 = fmaxf(fmaf(xv.x, ga, bb), 0.f);
            x1 = fmaxf(fmaf(xv.y, ga, bb), 0.f);
            x2 = fmaxf(fmaf(xv.z, ga, bb), 0.f);
            x3 = fmaxf(fmaf(xv.w, ga, bb), 0.f);
        } else if (IN == 2) {
            float4 rv = res4[(ci << 8) + tid];
            float ga = sga[ci], bb = sbb[ci];
            x0 = lrelu(rv.x + fmaf(xv.x, ga, bb));
            x1 = lrelu(rv.y + fmaf(xv.y, ga, bb));
            x2 = lrelu(rv.z + fmaf(xv.z, ga, bb));
            x3 = lrelu(rv.w + fmaf(xv.w, ga, bb));
        } else {
            x0 = xv.x; x1 = xv.y; x2 = xv.z; x3 = xv.w;
        }
        #pragma unroll
        for (int co = 0; co < 8; ++co) {
            float wvv = lw[ci][co];
            acc[co][0] = fmaf(x0, wvv, acc[co][0]);
            acc[co][1] = fmaf(x1, wvv, acc[co][1]);
            acc[co][2] = fmaf(x2, wvv, acc[co][2]);
            acc[co][3] = fmaf(x3, wvv, acc[co][3]);
        }
    }
    #pragma unroll
    for (int co = 0; co < 8; ++co) {
        float bv = bias ? bias[cg * 8 + co] : 0.f;
        float a0 = acc[co][0] + bv, a1 = acc[co][1] + bv, a2 = acc[co][2] + bv, a3 = acc[co][3] + bv;
        if (ACT == 1) { a0 = lrelu(a0); a1 = lrelu(a1); a2 = lrelu(a2); a3 = lrelu(a3); }
        float4 v; v.x = a0; v.y = a1; v.z = a2; v.w = a3;
        ((float4*)(out + (size_t)n * 65536 + (size_t)(cg * 8 + co) * 1024))[tid] = v;
        if (STATS) {
            float s = a0 + a1 + a2 + a3;
            float q = a0*a0 + a1*a1 + a2*a2 + a3*a3;
            #pragma unroll
            for (int m = 1; m < 64; m <<= 1) {
                s += __shfl_xor(s, m);
                q += __shfl_xor(q, m);
            }
            if (lane == 0) { sS[co][wv_id] = s; sQ[co][wv_id] = q; }
        }
    }
    if (STATS) {
        __syncthreads();
        if (tid < 8) {
            float s = sS[tid][0] + sS[tid][1] + sS[tid][2] + sS[tid][3];
            float q = sQ[tid][0] + sQ[tid][1] + sQ[tid][2] + sQ[tid][3];
            psum[(cg * 8 + tid) * 64 + n] = s;
            pss [(cg * 8 + tid) * 64 + n] = q;
        }
    }
}

// ================= BN finalize (encoder partials: [c][64]) =================
__global__ void bn_fin2_k(const float* __restrict__ psum, const float* __restrict__ pss,
                          float* __restrict__ fin, float invM)
{
    int c = threadIdx.x;
    if (c >= 64) return;
    float s = 0.f, q = 0.f;
    for (int n = 0; n < 64; ++n) { s += psum[c * 64 + n]; q += pss[c * 64 + n]; }
    float mean = s * invM;
    float var  = q * invM - mean * mean;
    fin[2 * c] = mean;
    fin[2 * c + 1] = rsqrtf(var + 1e-5f);
}

// ================= BN finalize (decoder MFMA partials: [c][256]) =================
__global__ void bn_fin3_k(const float* __restrict__ psum, const float* __restrict__ pss,
                          float* __restrict__ fin, float invM)
{
    int c = threadIdx.x;
    if (c >= 64) return;
    float s = 0.f, q = 0.f;
    for (int i = 0; i < 256; ++i) { s += psum[c * 256 + i]; q += pss[c * 256 + i]; }
    float mean = s * invM;
    float var  = q * invM - mean * mean;
    fin[2 * c] = mean;
    fin[2 * c + 1] = rsqrtf(var + 1e-5f);
}

// ================= transpose NCHW fp32 -> NHWC bf16 (+optional BN-relu) =================
template<int MODE>  // 0 plain, 1 relu(bn(x))
__global__ void __launch_bounds__(256) trans_k(
    const float* __restrict__ in, const float* __restrict__ fin,
    const float* __restrict__ g, const float* __restrict__ beta,
    unsigned short* __restrict__ outT)
{
    __shared__ unsigned short tt[256][68];
    __shared__ float sga[64], sbb[64];
    int b = blockIdx.x;
    int n = b >> 2, pxb = b & 3;
    int tid = threadIdx.x;
    if (MODE == 1) {
        if (tid < 64) {
            float ga = g[tid] * fin[2 * tid + 1];
            sga[tid] = ga;
            sbb[tid] = beta[tid] - fin[2 * tid] * ga;
        }
        __syncthreads();
    }
    for (int i = tid; i < 16384; i += 256) {
        int ci = i >> 8, px = i & 255;
        float v = in[((size_t)(n * 64 + ci) << 10) + pxb * 256 + px];
        if (MODE == 1) v = fmaxf(fmaf(v, sga[ci], sbb[ci]), 0.f);
        tt[px][ci] = f2bf(v);
    }
    __syncthreads();
    for (int o = tid; o < 4096; o += 256) {
        int px = o >> 4, c4 = o & 15;
        uint2 v = *(const uint2*)&tt[px][c4 * 4];
        *(uint2*)(outT + ((((size_t)n << 10) + pxb * 256 + px) << 6) + c4 * 4) = v;
    }
}

// ================= fused lrelu(res + bn(x)) + NCHW fp32 -> NHWC bf16 =================
__global__ void __launch_bounds__(256) bnres_trans_k(
    const float* __restrict__ xin, const float* __restrict__ res,
    const float* __restrict__ fin, const float* __restrict__ g,
    const float* __restrict__ beta, unsigned short* __restrict__ outT)
{
    __shared__ unsigned short tt[256][68];
    __shared__ float sga[64], sbb[64];
    int b = blockIdx.x;
    int n = b >> 2, pxb = b & 3;
    int tid = threadIdx.x;
    if (tid < 64) {
        float ga = g[tid] * fin[2 * tid + 1];
        sga[tid] = ga;
        sbb[tid] = beta[tid] - fin[2 * tid] * ga;
    }
    __syncthreads();
    for (int i = tid; i < 16384; i += 256) {
        int ci = i >> 8, px = i & 255;
        size_t gi = ((size_t)(n * 64 + ci) << 10) + pxb * 256 + px;
        float v = lrelu(res[gi] + fmaf(xin[gi], sga[ci], sbb[ci]));
        tt[px][ci] = f2bf(v);
    }
    __syncthreads();
    for (int o = tid; o < 4096; o += 256) {
        int px = o >> 4, c4 = o & 15;
        uint2 v = *(const uint2*)&tt[px][c4 * 4];
        *(uint2*)(outT + ((((size_t)n << 10) + pxb * 256 + px) << 6) + c4 * 4) = v;
    }
}

// ================= MFMA conv3x3 64->64 @32x32, bf16 (decoder) =================
template<int ACT, int STATS>
__global__ void __launch_bounds__(256) mfma_conv3x3_k(
    const unsigned short* __restrict__ inT, const float* __restrict__ w,
    const float* __restrict__ bias, float* __restrict__ out,
    float* __restrict__ psum, float* __restrict__ pss)
{
    __shared__ unsigned short lin[10][34][40];
    __shared__ unsigned short lwA[32][296];
    __shared__ float sS[4][32], sQ[4][32];
    int b = blockIdx.x;
    int cg = b & 1, pxb = (b >> 1) & 3, n = b >> 3;
    int tid = threadIdx.x;
    int wv = tid >> 6, l = tid & 63;
    int l15 = l & 15, lhi = l >> 4;

    f32x4 acc[2][4];
    #pragma unroll
    for (int ct = 0; ct < 2; ++ct)
        #pragma unroll
        for (int bt = 0; bt < 4; ++bt) {
            f32x4 z = {0.f, 0.f, 0.f, 0.f};
            acc[ct][bt] = z;
        }

    for (int c2 = 0; c2 < 2; ++c2) {
        __syncthreads();
        for (int i = tid; i < 1360; i += 256) {
            int pos = i >> 2, q = i & 3;
            int row = pos / 34, col = pos % 34;
            int iy = pxb * 8 - 1 + row, ix = col - 1;
            uint4 v = make_uint4(0u, 0u, 0u, 0u);
            if (iy >= 0 && iy < 32 && ix >= 0 && ix < 32)
                v = *(const uint4*)(inT + ((((size_t)n << 10) + iy * 32 + ix) << 6) + c2 * 32 + q * 8);
            *(uint4*)&lin[row][col][q * 8] = v;
        }
        for (int i = tid; i < 9216; i += 256) {
            int col = i / 288, k = i % 288;
            int tap = k >> 5, cc = k & 31;
            int co = cg * 32 + col;
            lwA[col][k] = f2bf(w[(co * 64 + c2 * 32 + cc) * 9 + tap]);
        }
        __syncthreads();
        #pragma unroll
        for (int tap = 0; tap < 9; ++tap) {
            const int dy = tap / 3, dx = tap % 3;
            short8 a[2], bb[4];
            #pragma unroll
            for (int ct = 0; ct < 2; ++ct)
                a[ct] = *(const short8*)&lwA[ct * 16 + l15][tap * 32 + lhi * 8];
            #pragma unroll
            for (int bt = 0; bt < 4; ++bt) {
                int rr = 2 * wv + (bt >> 1);
                int cc0 = (bt & 1) * 16;
                bb[bt] = *(const short8*)&lin[rr + dy][cc0 + l15 + dx][lhi * 8];
            }
            #pragma unroll
            for (int ct = 0; ct < 2; ++ct)
                #pragma unroll
                for (int bt = 0; bt < 4; ++bt)
                    acc[ct][bt] = __builtin_amdgcn_mfma_f32_16x16x32_bf16(a[ct], bb[bt], acc[ct][bt], 0, 0, 0);
        }
    }

    int orow0 = pxb * 8 + 2 * wv;
    #pragma unroll
    for (int ct = 0; ct < 2; ++ct) {
        #pragma unroll
        for (int j = 0; j < 4; ++j) {
            int co_l = ct * 16 + lhi * 4 + j;
            int co = cg * 32 + co_l;
            float bv = bias ? bias[co] : 0.f;
            float s = 0.f, q = 0.f;
            #pragma unroll
            for (int bt = 0; bt < 4; ++bt) {
                float v = acc[ct][bt][j] + bv;
                if (ACT == 1) v = lrelu(v);
                int row = orow0 + (bt >> 1);
                int col = (bt & 1) * 16 + l15;
                out[(((size_t)n * 64 + co) << 10) + row * 32 + col] = v;
                if (STATS) { s += v; q = fmaf(v, v, q); }
            }
            if (STATS) {
                #pragma unroll
                for (int m = 1; m < 16; m <<= 1) {
                    s += __shfl_xor(s, m);
                    q += __shfl_xor(q, m);
                }
                if (l15 == 0) { sS[wv][co_l] = s; sQ[wv][co_l] = q; }
            }
        }
    }
    if (STATS) {
        __syncthreads();
        if (tid < 32) {
            float s = sS[0][tid] + sS[1][tid] + sS[2][tid] + sS[3][tid];
            float q = sQ[0][tid] + sQ[1][tid] + sQ[2][tid] + sQ[3][tid];
            psum[(cg * 32 + tid) * 256 + n * 4 + pxb] = s;
            pss [(cg * 32 + tid) * 256 + n * 4 + pxb] = q;
        }
    }
}

// ================= MFMA conv1x1 64->64 @32x32, bf16 (decoder) =================
template<int ACT, int STATS>
__global__ void __launch_bounds__(256) mfma_conv1x1_k(
    const unsigned short* __restrict__ inT, const float* __restrict__ w,
    const float* __restrict__ bias, float* __restrict__ out,
    float* __restrict__ psum, float* __restrict__ pss)
{
    __shared__ unsigned short lin[256][72];
    __shared__ unsigned short lwA[32][72];
    __shared__ float sS[4][32], sQ[4][32];
    int b = blockIdx.x;
    int cg = b & 1, pxb = (b >> 1) & 3, n = b >> 3;
    int tid = threadIdx.x;
    int wv = tid >> 6, l = tid & 63;
    int l15 = l & 15, lhi = l >> 4;

    for (int i = tid; i < 2048; i += 256) {
        int px = i >> 3, q = i & 7;
        uint4 v = *(const uint4*)(inT + ((((size_t)n << 10) + pxb * 256 + px) << 6) + q * 8);
        *(uint4*)&lin[px][q * 8] = v;
    }
    for (int i = tid; i < 2048; i += 256) {
        int col = i >> 6, ci = i & 63;
        lwA[col][ci] = f2bf(w[(cg * 32 + col) * 64 + ci]);
    }
    __syncthreads();

    f32x4 acc[2][4];
    #pragma unroll
    for (int ct = 0; ct < 2; ++ct)
        #pragma unroll
        for (int bt = 0; bt < 4; ++bt) {
            f32x4 z = {0.f, 0.f, 0.f, 0.f};
            acc[ct][bt] = z;
        }

    #pragma unroll
    for (int ks = 0; ks < 2; ++ks) {
        short8 a[2], bb[4];
        #pragma unroll
        for (int ct = 0; ct < 2; ++ct)
            a[ct] = *(const short8*)&lwA[ct * 16 + l15][ks * 32 + lhi * 8];
        #pragma unroll
        for (int bt = 0; bt < 4; ++bt)
            bb[bt] = *(const short8*)&lin[wv * 64 + bt * 16 + l15][ks * 32 + lhi * 8];
        #pragma unroll
        for (int ct = 0; ct < 2; ++ct)
            #pragma unroll
            for (int bt = 0; bt < 4; ++bt)
                acc[ct][bt] = __builtin_amdgcn_mfma_f32_16x16x32_bf16(a[ct], bb[bt], acc[ct][bt], 0, 0, 0);
    }

    #pragma unroll
    for (int ct = 0; ct < 2; ++ct) {
        #pragma unroll
        for (int j = 0; j < 4; ++j) {
            int co_l = ct * 16 + lhi * 4 + j;
            int co = cg * 32 + co_l;
            float bv = bias ? bias[co] : 0.f;
            float s = 0.f, q = 0.f;
            #pragma unroll
            for (int bt = 0; bt < 4; ++bt) {
                float v = acc[ct][bt][j] + bv;
                if (ACT == 1) v = lrelu(v);
                int px = pxb * 256 + wv * 64 + bt * 16 + l15;
                out[(((size_t)n * 64 + co) << 10) + px] = v;
                if (STATS) { s += v; q = fmaf(v, v, q); }
            }
            if (STATS) {
                #pragma unroll
                for (int m = 1; m < 16; m <<= 1) {
                    s += __shfl_xor(s, m);
                    q += __shfl_xor(q, m);
                }
                if (l15 == 0) { sS[wv][co_l] = s; sQ[wv][co_l] = q; }
            }
        }
    }
    if (STATS) {
        __syncthreads();
        if (tid < 32) {
            float s = sS[0][tid] + sS[1][tid] + sS[2][tid] + sS[3][tid];
            float q = sQ[0][tid] + sQ[1][tid] + sQ[2][tid] + sQ[3][tid];
            psum[(cg * 32 + tid) * 256 + n * 4 + pxb] = s;
            pss [(cg * 32 + tid) * 256 + n * 4 + pxb] = q;
        }
    }
}

// ================= MFMA dt1: deconv 64->32, 32x32 -> 64x64, lrelu (bf16) =================
// quadrant GEMM: out(2u-1+py, 2v-1+px) = sum_{ty,tx,ci} in[u-ty][v-tx][ci] * w[ci][co][py+2ty][px+2tx]
// grid 1024: ublk = b&7 (4 u rows), p_y = (b>>3)&1, n = b>>4. wave: pq(px) = wv&1, j-half = wv>>1
__global__ void __launch_bounds__(256) mfma_dt1_k(
    const unsigned short* __restrict__ inT, const float* __restrict__ w,
    const float* __restrict__ bias, float* __restrict__ out)
{
    __shared__ unsigned short lin[5][34][40];    // 13.6 KB
    __shared__ unsigned short lwA[2][32][136];   // 17.4 KB
    int b = blockIdx.x;
    int ublk = b & 7, p_y = (b >> 3) & 1, n = b >> 4;
    int tid = threadIdx.x;
    int wv = tid >> 6, l = tid & 63;
    int l15 = l & 15, lhi = l >> 4;
    int pq = wv & 1;                 // p_x parity this wave computes
    int vbase = 1 - pq;
    int ubase = ublk * 4 + (p_y == 0 ? 1 : 0);

    f32x4 acc[2][4];
    #pragma unroll
    for (int ct = 0; ct < 2; ++ct)
        #pragma unroll
        for (int bt = 0; bt < 4; ++bt) {
            f32x4 z = {0.f, 0.f, 0.f, 0.f};
            acc[ct][bt] = z;
        }

    for (int ch = 0; ch < 2; ++ch) {     // 32-ci halves
        __syncthreads();
        // input: rows ubase-1..ubase+3, cols -1..32, 32 ci (short8 grains)
        for (int i = tid; i < 680; i += 256) {
            int rr = i / 136, rem = i % 136;
            int jc = rem >> 2, q = rem & 3;
            int gy = ubase - 1 + rr, gx = jc - 1;
            uint4 v = make_uint4(0u, 0u, 0u, 0u);
            if (gy >= 0 && gy < 32 && gx >= 0 && gx < 32)
                v = *(const uint4*)(inT + ((((size_t)n << 10) + gy * 32 + gx) << 6) + ch * 32 + q * 8);
            *(uint4*)&lin[rr][jc][q * 8] = v;
        }
        // weights: both px parities, 32 co, k = tap*32+cc
        for (int i = tid; i < 8192; i += 256) {
            int pqq = i >> 12, co = (i >> 7) & 31, k = i & 127;
            int tap = k >> 5, cc = k & 31;
            int ci = ch * 32 + cc;
            int ky = p_y + 2 * (tap >> 1), kx = pqq + 2 * (tap & 1);
            lwA[pqq][co][k] = f2bf(w[((ci * 32 + co) << 4) + ky * 4 + kx]);
        }
        __syncthreads();
        #pragma unroll
        for (int ks = 0; ks < 4; ++ks) {   // ks = tap
            int ty = ks >> 1, tx = ks & 1;
            short8 a[2], bb[4];
            #pragma unroll
            for (int ct = 0; ct < 2; ++ct)
                a[ct] = *(const short8*)&lwA[pq][ct * 16 + l15][ks * 32 + lhi * 8];
            #pragma unroll
            for (int bt = 0; bt < 4; ++bt) {
                int jloc = (wv >> 1) * 2 + (bt >> 1);
                int vloc = (bt & 1) * 16 + l15;
                bb[bt] = *(const short8*)&lin[jloc + 1 - ty][vloc + vbase + 1 - tx][lhi * 8];
            }
            #pragma unroll
            for (int ct = 0; ct < 2; ++ct)
                #pragma unroll
                for (int bt = 0; bt < 4; ++bt)
                    acc[ct][bt] = __builtin_amdgcn_mfma_f32_16x16x32_bf16(a[ct], bb[bt], acc[ct][bt], 0, 0, 0);
        }
    }

    // store: co = ct*16 + lhi*4 + j ; pixel (jloc, vloc) -> oy = 2(ubase+jloc)-1+p_y, ox = 2(vloc+vbase)-1+pq
    #pragma unroll
    for (int ct = 0; ct < 2; ++ct) {
        #pragma unroll
        for (int j = 0; j < 4; ++j) {
            int co = ct * 16 + lhi * 4 + j;
            float bv = bias[co];
            #pragma unroll
            for (int bt = 0; bt < 4; ++bt) {
                int jloc = (wv >> 1) * 2 + (bt >> 1);
                int vloc = (bt & 1) * 16 + l15;
                int oy = 2 * (ubase + jloc) - 1 + p_y;
                int ox = 2 * (vloc + vbase) - 1 + pq;
                out[((size_t)(n * 32 + co) << 12) + oy * 64 + ox] = lrelu(acc[ct][bt][j] + bv);
            }
        }
    }
}

// ================= VQ =================
__global__ void __launch_bounds__(256) vq_enorm_k(const float* __restrict__ emb, float* __restrict__ enorm)
{
    int k = blockIdx.x * 256 + threadIdx.x;
    if (k >= 512) return;
    const float4* e4 = (const float4*)(emb + (k << 6));
    float s = 0.f;
    #pragma unroll
    for (int j = 0; j < 16; ++j) {
        float4 e = e4[j];
        s = fmaf(e.x, e.x, s); s = fmaf(e.y, e.y, s);
        s = fmaf(e.z, e.z, s); s = fmaf(e.w, e.w, s);
    }
    enorm[k] = s;
}

__device__ __forceinline__ unsigned order_u32(float s) {
    unsigned u = __float_as_uint(s);
    return (s < 0.f) ? ~u : (u | 0x80000000u);
}

__global__ void __launch_bounds__(256) vq_dist_k(
    const float* __restrict__ z, const float* __restrict__ emb,
    const float* __restrict__ enorm, unsigned long long* __restrict__ best)
{
    __shared__ float se[64][64];
    __shared__ float sn[64];
    int b = blockIdx.x;
    int kb = b & 7, pg = b >> 3;
    int tid = threadIdx.x;
    for (int i = tid; i < 4096; i += 256)
        ((float*)se)[i] = emb[(kb << 12) + i];
    if (tid < 64) sn[tid] = enorm[(kb << 6) + tid];
    __syncthreads();

    int n = pg >> 1;
    int p0 = ((pg & 1) << 9) + tid;
    size_t base0 = (size_t)n * 65536 + p0;
    float z0[64], z1[64];
    #pragma unroll
    for (int d = 0; d < 64; ++d) z0[d] = z[base0 + (size_t)d * 1024];
    #pragma unroll
    for (int d = 0; d < 64; ++d) z1[d] = z[base0 + 256 + (size_t)d * 1024];

    unsigned long long b0 = ~0ULL, b1 = ~0ULL;
    for (int k = 0; k < 64; ++k) {
        const float4* e4 = (const float4*)se[k];
        float dot0 = 0.f, dot1 = 0.f;
        #pragma unroll
        for (int j = 0; j < 16; ++j) {
            float4 e = e4[j];
            dot0 = fmaf(z0[4*j],   e.x, dot0);
            dot0 = fmaf(z0[4*j+1], e.y, dot0);
            dot0 = fmaf(z0[4*j+2], e.z, dot0);
            dot0 = fmaf(z0[4*j+3], e.w, dot0);
            dot1 = fmaf(z1[4*j],   e.x, dot1);
            dot1 = fmaf(z1[4*j+1], e.y, dot1);
            dot1 = fmaf(z1[4*j+2], e.z, dot1);
            dot1 = fmaf(z1[4*j+3], e.w, dot1);
        }
        float s0 = fmaf(-2.f, dot0, sn[k]);
        float s1 = fmaf(-2.f, dot1, sn[k]);
        unsigned kk = (unsigned)((kb << 6) + k);
        unsigned long long p0k = ((unsigned long long)order_u32(s0) << 32) | kk;
        unsigned long long p1k = ((unsigned long long)order_u32(s1) << 32) | kk;
        b0 = p0k < b0 ? p0k : b0;
        b1 = p1k < b1 ? p1k : b1;
    }
    size_t m0 = ((size_t)pg << 9) + tid;
    best[((size_t)kb << 16) + m0]       = b0;
    best[((size_t)kb << 16) + m0 + 256] = b1;
}

__global__ void __launch_bounds__(256) vq_combine_k(
    const float* __restrict__ z, const float* __restrict__ emb,
    const unsigned long long* __restrict__ best,
    float* __restrict__ out_q, float* __restrict__ partials)
{
    int m = blockIdx.x * 256 + threadIdx.x;
    unsigned long long bb = best[m];
    #pragma unroll
    for (int kb = 1; kb < 8; ++kb) {
        unsigned long long v = best[((size_t)kb << 16) + m];
        bb = v < bb ? v : bb;
    }
    int bi = (int)(bb & 0x1ffu);
    int n = m >> 10, p = m & 1023;
    size_t base = (size_t)n * 65536 + p;
    const float* eb = emb + (bi << 6);
    float lsum = 0.f;
    #pragma unroll
    for (int d = 0; d < 64; ++d) {
        float zz = z[base + (size_t)d * 1024];
        float q = eb[d];
        out_q[base + (size_t)d * 1024] = q;
        float df = q - zz;
        lsum = fmaf(df, df, lsum);
    }
    __shared__ float sh[256];
    sh[threadIdx.x] = lsum;
    __syncthreads();
    for (int st = 128; st > 0; st >>= 1) {
        if (threadIdx.x < st) sh[threadIdx.x] += sh[threadIdx.x + st];
        __syncthreads();
    }
    if (threadIdx.x == 0) partials[blockIdx.x] = sh[0];
}

__global__ void vq_fin_k(const float* __restrict__ partials, float* __restrict__ out)
{
    __shared__ float sh[256];
    sh[threadIdx.x] = partials[threadIdx.x];
    __syncthreads();
    for (int st = 128; st > 0; st >>= 1) {
        if (threadIdx.x < st) sh[threadIdx.x] += sh[threadIdx.x + st];
        __syncthreads();
    }
    if (threadIdx.x == 0) out[0] = sh[0] * (0.25f / (65536.f * 64.f));
}

// ================= dt2: deconv 32->3, 64x64 -> 128x128, tanh (fp32) =================
__global__ void __launch_bounds__(256) deconv_dt2_t(
    const float* __restrict__ in, const float* __restrict__ w,
    const float* __restrict__ bias, float* __restrict__ out)
{
    __shared__ float lin[8][6][67];
    __shared__ float lw[8][3][16];
    int b = blockIdx.x;
    int n = b & 63, rt = b >> 6;
    int tid = threadIdx.x;
    int r8 = tid >> 5, g = tid & 31;
    int oy = rt * 8 + r8;
    const float* inp = in + (size_t)n * 32 * 4096;
    int iy0 = rt * 4 - 1;
    int ky0 = (oy + 1) & 1;
    int iyA = ((oy + 1 - ky0) >> 1) - iy0;
    int iyB = iyA - 1;
    int lx = 2 * g;

    float acc[3][4];
    #pragma unroll
    for (int co = 0; co < 3; ++co) { acc[co][0]=acc[co][1]=acc[co][2]=acc[co][3]=0.f; }

    for (int cic = 0; cic < 4; ++cic) {
        __syncthreads();
        for (int i = tid; i < 3168; i += 256) {
            int ci = i / 396, rr = i % 396;
            int y = rr / 66, xx = rr % 66;
            int gy = iy0 + y, gx = xx - 1;
            float v = 0.f;
            if (gy >= 0 && gy < 64 && gx >= 0 && gx < 64)
                v = inp[(cic * 8 + ci) * 4096 + gy * 64 + gx];
            lin[ci][y][xx] = v;
        }
        for (int i = tid; i < 384; i += 256) {
            int ci = i / 48, rr = i % 48;
            int co = rr >> 4, tt = rr & 15;
            lw[ci][co][tt] = w[((cic * 8 + ci) * 3 + co) * 16 + tt];
        }
        __syncthreads();
        #pragma unroll 2
        for (int ci = 0; ci < 8; ++ci) {
            float vA0 = lin[ci][iyA][lx],     vA1 = lin[ci][iyA][lx + 1];
            float vA2 = lin[ci][iyA][lx + 2], vA3 = lin[ci][iyA][lx + 3];
            float vB0 = lin[ci][iyB][lx],     vB1 = lin[ci][iyB][lx + 1];
            float vB2 = lin[ci][iyB][lx + 2], vB3 = lin[ci][iyB][lx + 3];
            #pragma unroll
            for (int co = 0; co < 3; ++co) {
                const float4* wp = (const float4*)lw[ci][co];
                float4 wA = wp[ky0];
                float4 wB = wp[ky0 + 2];
                acc[co][0] = fmaf(vA1, wA.y, fmaf(vA0, wA.w, fmaf(vB1, wB.y, fmaf(vB0, wB.w, acc[co][0]))));
                acc[co][1] = fmaf(vA2, wA.x, fmaf(vA1, wA.z, fmaf(vB2, wB.x, fmaf(vB1, wB.z, acc[co][1]))));
                acc[co][2] = fmaf(vA2, wA.y, fmaf(vA1, wA.w, fmaf(vB2, wB.y, fmaf(vB1, wB.w, acc[co][2]))));
                acc[co][3] = fmaf(vA3, wA.x, fmaf(vA2, wA.z, fmaf(vB3, wB.x, fmaf(vB2, wB.z, acc[co][3]))));
            }
        }
    }
    #pragma unroll
    for (int co = 0; co < 3; ++co) {
        float bv = bias[co];
        float4 v;
        v.x = fast_tanh(acc[co][0] + bv); v.y = fast_tanh(acc[co][1] + bv);
        v.z = fast_tanh(acc[co][2] + bv); v.w = fast_tanh(acc[co][3] + bv);
        *(float4*)(out + ((size_t)(n * 3 + co) * 16384) + oy * 128 + 4 * g) = v;
    }
}

extern "C" void kernel_launch(void* const* d_in, const int* in_sizes, int n_in,
                              void* d_out, int out_size, void* d_ws, size_t ws_size,
                              hipStream_t stream)
{
    const float* x    = (const float*)d_in[0];
    const float* e1w  = (const float*)d_in[1];
    const float* e1b  = (const float*)d_in[2];
    const float* e2w  = (const float*)d_in[3];
    const float* e2b  = (const float*)d_in[4];
    const float* e3w  = (const float*)d_in[5];
    const float* e3b  = (const float*)d_in[6];
    const float* er1w = (const float*)d_in[7];
    const float* er1g = (const float*)d_in[8];
    const float* er1b = (const float*)d_in[9];
    const float* er2w = (const float*)d_in[10];
    const float* er2g = (const float*)d_in[11];
    const float* er2b = (const float*)d_in[12];
    const float* e4w  = (const float*)d_in[13];
    const float* e4b  = (const float*)d_in[14];
    const float* emb  = (const float*)d_in[15];
    const float* d1w  = (const float*)d_in[16];
    const float* d1b  = (const float*)d_in[17];
    const float* dr1w = (const float*)d_in[18];
    const float* dr1g = (const float*)d_in[19];
    const float* dr1b = (const float*)d_in[20];
    const float* dr2w = (const float*)d_in[21];
    const float* dr2g = (const float*)d_in[22];
    const float* dr2b = (const float*)d_in[23];
    const float* dt1w = (const float*)d_in[24];
    const float* dt1b = (const float*)d_in[25];
    const float* dt2w = (const float*)d_in[26];
    const float* dt2b = (const float*)d_in[27];

    float* out = (float*)d_out;
    float* ws  = (float*)d_ws;

    // workspace layout (floats)
    float* B0 = ws;                   // 8,388,608
    float* B1 = ws + 8388608;         // 4,194,304 (fp32 in encoder; bf16 tbuf in decoder)
    float* B2 = B1 + 4194304;
    float* B3 = B2 + 4194304;
    float* B4 = B3 + 4194304;
    float* psum   = B4 + 4194304;     // 16384
    float* pss    = psum + 16384;     // 16384
    float* fin    = pss + 16384;      // 128
    float* vq_part = fin + 128;       // 256
    float* enorm   = vq_part + 256;   // 512
    unsigned long long* bestbuf = (unsigned long long*)(enorm + 512);  // 4MB

    unsigned short* tbuf = (unsigned short*)B1;  // 8.4MB bf16 NHWC

    float* out_recon = out;                 // 3,145,728
    float* out_q     = out + 3145728;       // 4,194,304
    float* out_e     = out + 7340032;       // 4,194,304
    float* out_loss  = out + 11534336;      // 1

    const float invM = 1.f / 65536.f;

    // ---------------- encoder (fp32 — protects VQ argmin) ----------------
    conv_e1_t<<<512, 256, 0, stream>>>(x, e1w, e1b, B0);
    conv_e2_t<<<512, 256, 0, stream>>>(B0, e2w, e2b, B1);
    conv3x3_t<1,0><<<512, 256, 0, stream>>>(B1, e3w, e3b, B2, nullptr, nullptr);

    conv3x3_t<0,1><<<512, 256, 0, stream>>>(B2, er1w, nullptr, B3, psum, pss);
    bn_fin2_k<<<1, 64, 0, stream>>>(psum, pss, fin, invM);
    conv1x1_t<1,0,1><<<512, 256, 0, stream>>>(B3, nullptr, er2w, nullptr, fin, er1g, er1b, B4, psum, pss);
    bn_fin2_k<<<1, 64, 0, stream>>>(psum, pss, fin, invM);
    conv1x1_t<2,1,0><<<512, 256, 0, stream>>>(B4, B2, e4w, e4b, fin, er2g, er2b, out_e, nullptr, nullptr);

    // VQ (fp32)
    vq_enorm_k<<<2, 256, 0, stream>>>(emb, enorm);
    vq_dist_k<<<1024, 256, 0, stream>>>(out_e, emb, enorm, bestbuf);
    vq_combine_k<<<256, 256, 0, stream>>>(out_e, emb, bestbuf, out_q, vq_part);
    vq_fin_k<<<1, 256, 0, stream>>>(vq_part, out_loss);

    // ---------------- decoder (bf16 MFMA) ----------------
    trans_k<0><<<256, 256, 0, stream>>>(out_q, nullptr, nullptr, nullptr, tbuf);
    mfma_conv3x3_k<1,0><<<512, 256, 0, stream>>>(tbuf, d1w, d1b, B2, nullptr, nullptr);

    trans_k<0><<<256, 256, 0, stream>>>(B2, nullptr, nullptr, nullptr, tbuf);
    mfma_conv3x3_k<0,1><<<512, 256, 0, stream>>>(tbuf, dr1w, nullptr, B3, psum, pss);
    bn_fin3_k<<<1, 64, 0, stream>>>(psum, pss, fin, invM);

    trans_k<1><<<256, 256, 0, stream>>>(B3, fin, dr1g, dr1b, tbuf);
    mfma_conv1x1_k<0,1><<<512, 256, 0, stream>>>(tbuf, dr2w, nullptr, B4, psum, pss);
    bn_fin3_k<<<1, 64, 0, stream>>>(psum, pss, fin, invM);

    // h = lrelu(res(B2) + bn(B4)) fused with NHWC bf16 transpose -> tbuf
    bnres_trans_k<<<256, 256, 0, stream>>>(B4, B2, fin, dr2g, dr2b, tbuf);

    // dt1 as MFMA quadrant GEMM -> B0 (fp32 NCHW)
    mfma_dt1_k<<<1024, 256, 0, stream>>>(tbuf, dt1w, dt1b, B0);

    // dt2 (fp32)
    deconv_dt2_t<<<1024, 256, 0, stream>>>(B0, dt2w, dt2b, out_recon);
}